// Round 8
// baseline (1066.978 us; speedup 1.0000x reference)
//
#include <hip/hip_runtime.h>

// Problem constants (match reference setup_inputs)
constexpr int ND   = 50000;
constexpr int NZ   = 20000;
constexpr int HID  = 128;
constexpr int OUTD = 64;
constexpr int E    = 1000000;

constexpr int SCAN_TILE = 1024;
constexpr int NB_D = (ND + SCAN_TILE - 1) / SCAN_TILE;   // 49
constexpr int NB_Z = (NZ + SCAN_TILE - 1) / SCAN_TILE;   // 20
constexpr int NXCD  = 8;     // XCD count; blockIdx % 8 assumed round-robin -> XCD
constexpr int HISTC = 64;    // chunks per edge list (hist)
constexpr int FILLC = 96;    // chunks per edge list (fill)
constexpr int VT    = 2 * ND + NZ;   // virtual node space for agg

static inline int ceil_div(int a, int b) { return (a + b - 1) / b; }

typedef __bf16 bf16x8 __attribute__((ext_vector_type(8)));
typedef float  f32x4  __attribute__((ext_vector_type(4)));

__device__ __forceinline__ float bf2f(unsigned short b) {
    return __uint_as_float(((unsigned int)b) << 16);
}
__device__ __forceinline__ unsigned short f2bf(float f) {
    unsigned int u = __float_as_uint(f);
    unsigned int r = (u + 0x7fffu + ((u >> 16) & 1u)) >> 16;
    return (unsigned short)r;
}

// ---------------------------------------------------------------------------
// Fused gather: rows [0,ND) from emb_drug[x_drug], rows [ND,ND+NZ) from emb_dis
// ---------------------------------------------------------------------------
__global__ __launch_bounds__(256) void gather_all(
    const float* __restrict__ emb_d, const int* __restrict__ idx_d,
    const float* __restrict__ emb_z, const int* __restrict__ idx_z,
    unsigned short* __restrict__ out_d, unsigned short* __restrict__ out_z)
{
    int t = blockIdx.x * blockDim.x + threadIdx.x;
    int row = t >> 5;
    int c = (t & 31) * 4;
    if (row >= ND + NZ) return;
    const float* src;
    unsigned short* dst;
    if (row < ND) {
        src = emb_d + (size_t)idx_d[row] * HID;
        dst = out_d + (size_t)row * HID;
    } else {
        int r2 = row - ND;
        src = emb_z + (size_t)idx_z[r2] * HID;
        dst = out_z + (size_t)r2 * HID;
    }
    float4 v = *reinterpret_cast<const float4*>(src + c);
    ushort4 o;
    o.x = f2bf(v.x); o.y = f2bf(v.y); o.z = f2bf(v.z); o.w = f2bf(v.w);
    *reinterpret_cast<ushort4*>(dst + c) = o;
}

// ---------------------------------------------------------------------------
// Fused weight prep: 6 weight pairs -> Wt[j][0:256] = bf16([Wl col j ; Wr col j])
// ---------------------------------------------------------------------------
struct PrepArgs {
    const float* wl[6];
    const float* wr[6];
    unsigned short* wt[6];
    int co[6];
    int boff[7];
};

__global__ __launch_bounds__(256) void prep_all(PrepArgs a)
{
    int sec = 0;
#pragma unroll
    for (int s = 0; s < 6; ++s)
        if ((int)blockIdx.x >= a.boff[s + 1]) sec = s + 1;
    int CO = a.co[sec];
    int idx = (blockIdx.x - a.boff[sec]) * 256 + threadIdx.x;  // CO*256 total
    int j = idx >> 8;
    int k = idx & 255;
    float v = (k < HID) ? a.wl[sec][k * CO + j] : a.wr[sec][(k - HID) * CO + j];
    a.wt[sec][(size_t)j * 256 + k] = f2bf(v);
}

// ---------------------------------------------------------------------------
// XCD-range-partitioned histogram: blockIdx%8 = destination range (-> XCD)
// ---------------------------------------------------------------------------
__global__ __launch_bounds__(256) void hist8(
    const int* __restrict__ d0, const int* __restrict__ d1, const int* __restrict__ d2,
    int* __restrict__ c0, int* __restrict__ c1, int* __restrict__ c2)
{
    const int range = blockIdx.x % NXCD;
    const int t = blockIdx.x / NXCD;
    const int list = t % 3;
    const int chunk = t / 3;                      // [0, HISTC)
    const int* dst = (list == 0) ? d0 : (list == 1) ? d1 : d2;
    int* cnt = (list == 0) ? c0 : (list == 1) ? c1 : c2;
    const int n = (list == 2) ? NZ : ND;
    const int rlo = range * (n / NXCD);
    const int rhi = (range == NXCD - 1) ? n : rlo + n / NXCD;
    const int elo = (int)((long long)chunk * E / HISTC);
    const int ehi = (int)((long long)(chunk + 1) * E / HISTC);
    for (int e = elo + threadIdx.x; e < ehi; e += 256) {
        int d = dst[e];
        if (d >= rlo && d < rhi) atomicAdd(&cnt[d], 1);
    }
}

// ---------------------------------------------------------------------------
// Fused 3-phase scan over the 3 count arrays
// ---------------------------------------------------------------------------
__device__ __forceinline__ void scan_map(int b, int& which, int& tile) {
    if (b < NB_D) { which = 0; tile = b; }
    else if (b < 2 * NB_D) { which = 1; tile = b - NB_D; }
    else { which = 2; tile = b - 2 * NB_D; }
}

__global__ __launch_bounds__(256) void scan_part3(
    const int* __restrict__ c0, const int* __restrict__ c1, const int* __restrict__ c2,
    int* __restrict__ part)
{
    __shared__ int red[256];
    int which, tile;
    scan_map(blockIdx.x, which, tile);
    const int* cnt = (which == 0) ? c0 : (which == 1) ? c1 : c2;
    int n = (which == 2) ? NZ : ND;
    int base = tile * SCAN_TILE;
    int s = 0;
    for (int i = threadIdx.x; i < SCAN_TILE; i += 256) {
        int idx = base + i;
        if (idx < n) s += cnt[idx];
    }
    red[threadIdx.x] = s;
    __syncthreads();
#pragma unroll
    for (int off = 128; off > 0; off >>= 1) {
        if (threadIdx.x < off) red[threadIdx.x] += red[threadIdx.x + off];
        __syncthreads();
    }
    if (threadIdx.x == 0) part[which * 64 + tile] = red[0];
}

__global__ __launch_bounds__(64) void scan_small3(
    int* __restrict__ part,
    int* __restrict__ o0, int* __restrict__ o1, int* __restrict__ o2)
{
    int w = blockIdx.x;
    int np = (w == 2) ? NB_Z : NB_D;
    int n = (w == 2) ? NZ : ND;
    int* offs = (w == 0) ? o0 : (w == 1) ? o1 : o2;
    int* pb = part + w * 64;
    int lane = threadIdx.x;
    int orig = (lane < np) ? pb[lane] : 0;
    int v = orig;
#pragma unroll
    for (int off = 1; off < 64; off <<= 1) {
        int t = __shfl_up(v, off, 64);
        if (lane >= off) v += t;
    }
    if (lane < np) pb[lane] = v - orig;   // exclusive
    if (lane == 63) offs[n] = v;          // total
}

__global__ __launch_bounds__(256) void scan_write3(
    const int* __restrict__ c0, const int* __restrict__ c1, const int* __restrict__ c2,
    const int* __restrict__ part,
    int* __restrict__ o0, int* __restrict__ o1, int* __restrict__ o2,
    int* __restrict__ u0, int* __restrict__ u1, int* __restrict__ u2)
{
    __shared__ int sc[256];
    int which, tile;
    scan_map(blockIdx.x, which, tile);
    const int* cnt = (which == 0) ? c0 : (which == 1) ? c1 : c2;
    int* offs = (which == 0) ? o0 : (which == 1) ? o1 : o2;
    int* cur  = (which == 0) ? u0 : (which == 1) ? u1 : u2;
    int n = (which == 2) ? NZ : ND;

    const int tid = threadIdx.x;
    const int tb = tile * SCAN_TILE + tid * 4;
    int v[4];
    int s = 0;
#pragma unroll
    for (int k = 0; k < 4; ++k) {
        v[k] = (tb + k < n) ? cnt[tb + k] : 0;
        s += v[k];
    }
    sc[tid] = s;
    __syncthreads();
#pragma unroll
    for (int off = 1; off < 256; off <<= 1) {
        int t = (tid >= off) ? sc[tid - off] : 0;
        __syncthreads();
        sc[tid] += t;
        __syncthreads();
    }
    int ex = part[which * 64 + tile] + (tid ? sc[tid - 1] : 0);
#pragma unroll
    for (int k = 0; k < 4; ++k) {
        if (tb + k < n) {
            offs[tb + k] = ex;
            cur[tb + k] = ex;
            ex += v[k];
        }
    }
}

// ---------------------------------------------------------------------------
// XCD-range-partitioned CSR fill
// ---------------------------------------------------------------------------
__global__ __launch_bounds__(256) void fill8(
    const int* __restrict__ s0, const int* __restrict__ d0,
    const int* __restrict__ s1, const int* __restrict__ d1,
    const int* __restrict__ s2, const int* __restrict__ d2,
    int* __restrict__ u0, int* __restrict__ u1, int* __restrict__ u2,
    int* __restrict__ l0, int* __restrict__ l1, int* __restrict__ l2)
{
    const int range = blockIdx.x % NXCD;
    const int t = blockIdx.x / NXCD;
    const int list = t % 3;
    const int chunk = t / 3;                      // [0, FILLC)
    const int* src = (list == 0) ? s0 : (list == 1) ? s1 : s2;
    const int* dst = (list == 0) ? d0 : (list == 1) ? d1 : d2;
    int* cur = (list == 0) ? u0 : (list == 1) ? u1 : u2;
    int* col = (list == 0) ? l0 : (list == 1) ? l1 : l2;
    const int n = (list == 2) ? NZ : ND;
    const int rlo = range * (n / NXCD);
    const int rhi = (range == NXCD - 1) ? n : rlo + n / NXCD;
    const int elo = (int)((long long)chunk * E / FILLC);
    const int ehi = (int)((long long)(chunk + 1) * E / FILLC);
    for (int e = elo + threadIdx.x; e < ehi; e += 256) {
        int d = dst[e];
        int s = src[e];                            // unconditional, coalesced
        if (d >= rlo && d < rhi) {
            int p = atomicAdd(&cur[d], 1);
            col[p] = s;
        }
    }
}

// ---------------------------------------------------------------------------
// Column-partitioned CSR mean-aggregation (agg8):
// blockIdx%8 -> XCD; column group g = (blockIdx%8)&3 covers cols [g*32,g*32+32)
// so each XCD's L2 only caches a 64B column slice of the feature tables
// (~4.5 MB working set -> L2-resident instead of L3).
// Wave: 4 edges in parallel (sub=lane>>4), 16 lanes x 4B = 64B slice per edge.
// Mean buffers use group-blocked layout [4][n][32] (ushort).
// ---------------------------------------------------------------------------
__global__ __launch_bounds__(256) void agg8(
    const int* __restrict__ o0, const int* __restrict__ c0,
    const unsigned short* __restrict__ X0, unsigned short* __restrict__ M0, int n0,
    const int* __restrict__ o1, const int* __restrict__ c1,
    const unsigned short* __restrict__ X1, unsigned short* __restrict__ M1, int n1,
    const int* __restrict__ o2, const int* __restrict__ c2,
    const unsigned short* __restrict__ X2, unsigned short* __restrict__ M2, int n2)
{
    const int xcd = blockIdx.x & 7;
    const int g   = xcd & 3;          // column group
    const int h   = xcd >> 2;         // which half of the node batch
    const int wave = threadIdx.x >> 6;
    const int lane = threadIdx.x & 63;
    const int sub = lane >> 4;        // edge slot 0..3
    const int cl  = lane & 15;        // 4B column lane within 64B slice

    int vnode = (blockIdx.x >> 3) * 8 + h * 4 + wave;
    const int* offs; const int* col;
    const unsigned short* X; unsigned short* M; int n;
    if (vnode < n0) { offs = o0; col = c0; X = X0; M = M0; n = n0; }
    else if (vnode < n0 + n1) { vnode -= n0; offs = o1; col = c1; X = X1; M = M1; n = n1; }
    else { vnode -= n0 + n1; if (vnode >= n2) return; offs = o2; col = c2; X = X2; M = M2; n = n2; }

    const int start = offs[vnode];
    const int end = offs[vnode + 1];
    const unsigned short* Xg = X + g * 32 + cl * 2;

    float a0 = 0.f, a1 = 0.f, b0 = 0.f, b1 = 0.f;
    for (int e = start; e < end; e += 8) {
        int e0 = e + sub;
        int e1 = e + 4 + sub;
        if (e0 < end) {
            unsigned v = *reinterpret_cast<const unsigned*>(Xg + (size_t)col[e0] * HID);
            a0 += bf2f((unsigned short)(v & 0xffffu));
            a1 += bf2f((unsigned short)(v >> 16));
        }
        if (e1 < end) {
            unsigned v = *reinterpret_cast<const unsigned*>(Xg + (size_t)col[e1] * HID);
            b0 += bf2f((unsigned short)(v & 0xffffu));
            b1 += bf2f((unsigned short)(v >> 16));
        }
    }
    a0 += b0; a1 += b1;
    a0 += __shfl_xor(a0, 16, 64); a1 += __shfl_xor(a1, 16, 64);
    a0 += __shfl_xor(a0, 32, 64); a1 += __shfl_xor(a1, 32, 64);

    if (sub == 0) {
        float inv = 1.0f / (float)max(end - start, 1);
        unsigned o = (unsigned)f2bf(a0 * inv) | ((unsigned)f2bf(a1 * inv) << 16);
        *reinterpret_cast<unsigned*>(M + ((size_t)g * n + vnode) * 32 + cl * 2) = o;
    }
}

// ---------------------------------------------------------------------------
// Single-edge-type MFMA SAGE (td): out = norm([mean|x]@Wt + bl), fp32 write.
// Mean buffer is group-blocked [4][n][32]; A-cols s*32+chunk*8 map to
// group s, offset chunk*8. C/D layout: col=lane&15, row=(lane>>4)*4+reg [m89]
// ---------------------------------------------------------------------------
template <int CO>
__global__ __launch_bounds__(256) void sage_mfma(
    const unsigned short* __restrict__ Mb,   // [4][n][32]
    const unsigned short* __restrict__ Xb,   // [n][128] row-major
    const unsigned short* __restrict__ Wt,
    const float* __restrict__ bl,
    float* __restrict__ H, int n)
{
    constexpr int NT = CO / 16;
    const int wave = threadIdx.x >> 6;
    const int lane = threadIdx.x & 63;
    const int r16 = lane & 15;
    const int chunk = lane >> 4;
    const int rowbase = blockIdx.x * 64 + wave * 16;
    if (rowbase >= n) return;

    const int arow = min(rowbase + r16, n - 1);
    const unsigned short* xrow = Xb + (size_t)arow * HID;

    bf16x8 a[8];
#pragma unroll
    for (int s = 0; s < 4; ++s) {
        a[s]     = *reinterpret_cast<const bf16x8*>(Mb + ((size_t)s * n + arow) * 32 + chunk * 8);
        a[4 + s] = *reinterpret_cast<const bf16x8*>(xrow + s * 32 + chunk * 8);
    }

    f32x4 acc[NT];
#pragma unroll
    for (int t = 0; t < NT; ++t) acc[t] = f32x4{0.f, 0.f, 0.f, 0.f};

#pragma unroll
    for (int t = 0; t < NT; ++t) {
        const unsigned short* wr_ = Wt + (size_t)(t * 16 + r16) * 256;
#pragma unroll
        for (int s = 0; s < 8; ++s) {
            bf16x8 b = *reinterpret_cast<const bf16x8*>(wr_ + s * 32 + chunk * 8);
            acc[t] = __builtin_amdgcn_mfma_f32_16x16x32_bf16(a[s], b, acc[t], 0, 0, 0);
        }
    }

    float ss[4] = {0.f, 0.f, 0.f, 0.f};
#pragma unroll
    for (int t = 0; t < NT; ++t) {
        float bias = bl[t * 16 + r16];
#pragma unroll
        for (int r = 0; r < 4; ++r) {
            acc[t][r] += bias;
            ss[r] += acc[t][r] * acc[t][r];
        }
    }
#pragma unroll
    for (int r = 0; r < 4; ++r)
#pragma unroll
        for (int m = 1; m < 16; m <<= 1)
            ss[r] += __shfl_xor(ss[r], m, 64);

#pragma unroll
    for (int r = 0; r < 4; ++r) {
        int node = rowbase + chunk * 4 + r;
        if (node < n) {
            float inv = 1.0f / fmaxf(sqrtf(ss[r]), 1e-12f);
#pragma unroll
            for (int t = 0; t < NT; ++t)
                H[(size_t)node * CO + t * 16 + r16] = acc[t][r] * inv;
        }
    }
}

// ---------------------------------------------------------------------------
// Dual-edge-type SAGE (dd + rd): H = norm(A-path) + norm(B-path), fp32 write.
// Mean buffers group-blocked [4][n][32].
// ---------------------------------------------------------------------------
template <int CO>
__global__ __launch_bounds__(256) void sage2_mfma(
    const unsigned short* __restrict__ MbA,
    const unsigned short* __restrict__ MbB,
    const unsigned short* __restrict__ Xb,
    const unsigned short* __restrict__ WtA,
    const unsigned short* __restrict__ WtB,
    const float* __restrict__ blA, const float* __restrict__ blB,
    float* __restrict__ H, int n)
{
    constexpr int NT = CO / 16;
    const int wave = threadIdx.x >> 6;
    const int lane = threadIdx.x & 63;
    const int r16 = lane & 15;
    const int chunk = lane >> 4;
    const int rowbase = blockIdx.x * 64 + wave * 16;
    if (rowbase >= n) return;

    const int arow = min(rowbase + r16, n - 1);
    const unsigned short* xrow  = Xb + (size_t)arow * HID;

    bf16x8 aA[4], aB[4], ax[4];
#pragma unroll
    for (int s = 0; s < 4; ++s) {
        aA[s] = *reinterpret_cast<const bf16x8*>(MbA + ((size_t)s * n + arow) * 32 + chunk * 8);
        aB[s] = *reinterpret_cast<const bf16x8*>(MbB + ((size_t)s * n + arow) * 32 + chunk * 8);
        ax[s] = *reinterpret_cast<const bf16x8*>(xrow + s * 32 + chunk * 8);
    }

    f32x4 accA[NT], accB[NT];
#pragma unroll
    for (int t = 0; t < NT; ++t) {
        accA[t] = f32x4{0.f, 0.f, 0.f, 0.f};
        accB[t] = f32x4{0.f, 0.f, 0.f, 0.f};
    }

#pragma unroll
    for (int t = 0; t < NT; ++t) {
        const unsigned short* wA = WtA + (size_t)(t * 16 + r16) * 256;
        const unsigned short* wB = WtB + (size_t)(t * 16 + r16) * 256;
#pragma unroll
        for (int s = 0; s < 4; ++s) {
            bf16x8 b0 = *reinterpret_cast<const bf16x8*>(wA + s * 32 + chunk * 8);
            accA[t] = __builtin_amdgcn_mfma_f32_16x16x32_bf16(aA[s], b0, accA[t], 0, 0, 0);
            bf16x8 b1 = *reinterpret_cast<const bf16x8*>(wA + HID + s * 32 + chunk * 8);
            accA[t] = __builtin_amdgcn_mfma_f32_16x16x32_bf16(ax[s], b1, accA[t], 0, 0, 0);
            bf16x8 b2 = *reinterpret_cast<const bf16x8*>(wB + s * 32 + chunk * 8);
            accB[t] = __builtin_amdgcn_mfma_f32_16x16x32_bf16(aB[s], b2, accB[t], 0, 0, 0);
            bf16x8 b3 = *reinterpret_cast<const bf16x8*>(wB + HID + s * 32 + chunk * 8);
            accB[t] = __builtin_amdgcn_mfma_f32_16x16x32_bf16(ax[s], b3, accB[t], 0, 0, 0);
        }
    }

    float ssA[4] = {0.f, 0.f, 0.f, 0.f};
    float ssB[4] = {0.f, 0.f, 0.f, 0.f};
#pragma unroll
    for (int t = 0; t < NT; ++t) {
        float biasA = blA[t * 16 + r16];
        float biasB = blB[t * 16 + r16];
#pragma unroll
        for (int r = 0; r < 4; ++r) {
            accA[t][r] += biasA;
            ssA[r] += accA[t][r] * accA[t][r];
            accB[t][r] += biasB;
            ssB[r] += accB[t][r] * accB[t][r];
        }
    }
#pragma unroll
    for (int r = 0; r < 4; ++r)
#pragma unroll
        for (int m = 1; m < 16; m <<= 1) {
            ssA[r] += __shfl_xor(ssA[r], m, 64);
            ssB[r] += __shfl_xor(ssB[r], m, 64);
        }

#pragma unroll
    for (int r = 0; r < 4; ++r) {
        int node = rowbase + chunk * 4 + r;
        if (node < n) {
            float invA = 1.0f / fmaxf(sqrtf(ssA[r]), 1e-12f);
            float invB = 1.0f / fmaxf(sqrtf(ssB[r]), 1e-12f);
#pragma unroll
            for (int t = 0; t < NT; ++t)
                H[(size_t)node * CO + t * 16 + r16] =
                    accA[t][r] * invA + accB[t][r] * invB;
        }
    }
}

// ---------------------------------------------------------------------------
// LayerNorm (+optional ReLU), one wave per row; fp32 in; bf16 or fp32 out.
// ---------------------------------------------------------------------------
template <int D, bool RELU, bool OUTBF>
__global__ __launch_bounds__(256) void ln_kernel(
    const float* __restrict__ X, const float* __restrict__ gg,
    const float* __restrict__ bb, void* __restrict__ outp, int n)
{
    constexpr int VPL = D / 64;
    int wid = (blockIdx.x * blockDim.x + threadIdx.x) >> 6;
    int lane = threadIdx.x & 63;
    if (wid >= n) return;

    float v[VPL], gv[VPL], bv[VPL];
    const float* xp = X + (size_t)wid * D + lane * VPL;
#pragma unroll
    for (int k = 0; k < VPL; ++k) {
        v[k] = xp[k];
        gv[k] = gg[lane * VPL + k];
        bv[k] = bb[lane * VPL + k];
    }
    float s = 0.f;
#pragma unroll
    for (int k = 0; k < VPL; ++k) s += v[k];
#pragma unroll
    for (int off = 32; off > 0; off >>= 1) s += __shfl_xor(s, off, 64);
    float m = s / D;
    float ss = 0.f;
#pragma unroll
    for (int k = 0; k < VPL; ++k) { float d = v[k] - m; ss += d * d; }
#pragma unroll
    for (int off = 32; off > 0; off >>= 1) ss += __shfl_xor(ss, off, 64);
    float rstd = rsqrtf(ss / D + 1e-5f);

    float y[VPL];
#pragma unroll
    for (int k = 0; k < VPL; ++k) {
        y[k] = gv[k] * (v[k] - m) * rstd + bv[k];
        if (RELU) y[k] = fmaxf(y[k], 0.f);
    }
    if (OUTBF) {
        unsigned short* op = (unsigned short*)outp + (size_t)wid * D + lane * VPL;
#pragma unroll
        for (int k = 0; k < VPL; ++k) op[k] = f2bf(y[k]);
    } else {
        float* op = (float*)outp + (size_t)wid * D + lane * VPL;
#pragma unroll
        for (int k = 0; k < VPL; ++k) op[k] = y[k];
    }
}

// ---------------------------------------------------------------------------
extern "C" void kernel_launch(void* const* d_in, const int* in_sizes, int n_in,
                              void* d_out, int out_size, void* d_ws, size_t ws_size,
                              hipStream_t stream)
{
    const int*   x_drug   = (const int*)d_in[0];
    const int*   x_dis    = (const int*)d_in[1];
    const float* emb_drug = (const float*)d_in[2];
    const float* emb_dis  = (const float*)d_in[3];
    const int*   src_dd   = (const int*)d_in[4];
    const int*   dst_dd   = (const int*)d_in[5];
    const int*   src_td   = (const int*)d_in[6];
    const int*   dst_td   = (const int*)d_in[7];
    const int*   src_rd   = (const int*)d_in[8];
    const int*   dst_rd   = (const int*)d_in[9];
    const float* Wl0_dd = (const float*)d_in[10];
    const float* bl0_dd = (const float*)d_in[11];
    const float* Wr0_dd = (const float*)d_in[12];
    const float* Wl0_td = (const float*)d_in[13];
    const float* bl0_td = (const float*)d_in[14];
    const float* Wr0_td = (const float*)d_in[15];
    const float* Wl0_rd = (const float*)d_in[16];
    const float* bl0_rd = (const float*)d_in[17];
    const float* Wr0_rd = (const float*)d_in[18];
    const float* Wl1_dd = (const float*)d_in[19];
    const float* bl1_dd = (const float*)d_in[20];
    const float* Wr1_dd = (const float*)d_in[21];
    const float* Wl1_td = (const float*)d_in[22];
    const float* bl1_td = (const float*)d_in[23];
    const float* Wr1_td = (const float*)d_in[24];
    const float* Wl1_rd = (const float*)d_in[25];
    const float* bl1_rd = (const float*)d_in[26];
    const float* Wr1_rd = (const float*)d_in[27];
    const float* g0_drug = (const float*)d_in[28];
    const float* b0_drug = (const float*)d_in[29];
    const float* g0_dis  = (const float*)d_in[30];
    const float* b0_dis  = (const float*)d_in[31];
    const float* g1_drug = (const float*)d_in[32];
    const float* b1_drug = (const float*)d_in[33];
    const float* g1_dis  = (const float*)d_in[34];
    const float* b1_dis  = (const float*)d_in[35];

    // ---------------- workspace layout ----------------
    char* wp = (char*)d_ws;
    auto alloc = [&](size_t bytes) { char* p = wp; wp += (bytes + 255) & ~size_t(255); return p; };

    unsigned short* hd0  = (unsigned short*)alloc((size_t)ND * HID * 2);
    unsigned short* hz0  = (unsigned short*)alloc((size_t)NZ * HID * 2);
    unsigned short* hd1b = (unsigned short*)alloc((size_t)ND * HID * 2);
    unsigned short* hz1b = (unsigned short*)alloc((size_t)NZ * HID * 2);
    unsigned short* meanA= (unsigned short*)alloc((size_t)ND * HID * 2);   // [4][ND][32]
    unsigned short* meanB= (unsigned short*)alloc((size_t)ND * HID * 2);   // [4][ND][32]
    unsigned short* meanC= (unsigned short*)alloc((size_t)NZ * HID * 2);   // [4][NZ][32]
    float* hd1f = (float*)alloc((size_t)ND * HID * 4);
    float* hz1f = (float*)alloc((size_t)NZ * HID * 4);
    unsigned short* Wt0_dd = (unsigned short*)alloc((size_t)HID * 256 * 2);
    unsigned short* Wt0_rd = (unsigned short*)alloc((size_t)HID * 256 * 2);
    unsigned short* Wt0_td = (unsigned short*)alloc((size_t)HID * 256 * 2);
    unsigned short* Wt1_dd = (unsigned short*)alloc((size_t)OUTD * 256 * 2);
    unsigned short* Wt1_rd = (unsigned short*)alloc((size_t)OUTD * 256 * 2);
    unsigned short* Wt1_td = (unsigned short*)alloc((size_t)OUTD * 256 * 2);
    int* offs_dd = (int*)alloc((ND + 1) * 4);
    int* offs_rd = (int*)alloc((ND + 1) * 4);
    int* offs_td = (int*)alloc((NZ + 1) * 4);
    int* col_dd  = (int*)alloc((size_t)E * 4);
    int* col_rd  = (int*)alloc((size_t)E * 4);
    int* col_td  = (int*)alloc((size_t)E * 4);
    // contiguous count region (one memset covers all three)
    int* cnt_dd  = (int*)alloc(((size_t)(ND + 1) + (ND + 1) + (NZ + 1)) * 4);
    int* cnt_rd  = cnt_dd + (ND + 1);
    int* cnt_td  = cnt_rd + (ND + 1);
    int* cur_dd  = (int*)alloc((ND + 1) * 4);
    int* cur_rd  = (int*)alloc((ND + 1) * 4);
    int* cur_td  = (int*)alloc((NZ + 1) * 4);
    int* part    = (int*)alloc(3 * 64 * 4);

    float* outD = (float*)d_out;
    float* outZ = outD + (size_t)ND * OUTD;

    // ---------------- independent prep ----------------
    hipMemsetAsync(cnt_dd, 0, ((size_t)(ND + 1) + (ND + 1) + (NZ + 1)) * 4, stream);

    gather_all<<<ceil_div((ND + NZ) * 32, 256), 256, 0, stream>>>(
        emb_drug, x_drug, emb_dis, x_dis, hd0, hz0);

    PrepArgs pa;
    pa.wl[0] = Wl0_dd; pa.wr[0] = Wr0_dd; pa.wt[0] = Wt0_dd; pa.co[0] = HID;
    pa.wl[1] = Wl0_rd; pa.wr[1] = Wr0_rd; pa.wt[1] = Wt0_rd; pa.co[1] = HID;
    pa.wl[2] = Wl0_td; pa.wr[2] = Wr0_td; pa.wt[2] = Wt0_td; pa.co[2] = HID;
    pa.wl[3] = Wl1_dd; pa.wr[3] = Wr1_dd; pa.wt[3] = Wt1_dd; pa.co[3] = OUTD;
    pa.wl[4] = Wl1_rd; pa.wr[4] = Wr1_rd; pa.wt[4] = Wt1_rd; pa.co[4] = OUTD;
    pa.wl[5] = Wl1_td; pa.wr[5] = Wr1_td; pa.wt[5] = Wt1_td; pa.co[5] = OUTD;
    pa.boff[0] = 0;
    for (int s = 0; s < 6; ++s) pa.boff[s + 1] = pa.boff[s] + pa.co[s];
    prep_all<<<pa.boff[6], 256, 0, stream>>>(pa);

    // ---------------- CSR build (XCD-range-partitioned) ----------------
    hist8<<<3 * NXCD * HISTC, 256, 0, stream>>>(
        dst_dd, dst_rd, dst_td, cnt_dd, cnt_rd, cnt_td);
    scan_part3<<<2 * NB_D + NB_Z, 256, 0, stream>>>(cnt_dd, cnt_rd, cnt_td, part);
    scan_small3<<<3, 64, 0, stream>>>(part, offs_dd, offs_rd, offs_td);
    scan_write3<<<2 * NB_D + NB_Z, 256, 0, stream>>>(
        cnt_dd, cnt_rd, cnt_td, part, offs_dd, offs_rd, offs_td, cur_dd, cur_rd, cur_td);
    fill8<<<3 * NXCD * FILLC, 256, 0, stream>>>(
        src_dd, dst_dd, src_rd, dst_rd, src_td, dst_td,
        cur_dd, cur_rd, cur_td, col_dd, col_rd, col_td);

    const int AGG_GRID = ceil_div(VT, 8) * 8;

    // ---------------- layer 0 ----------------
    agg8<<<AGG_GRID, 256, 0, stream>>>(
        offs_dd, col_dd, hd0, meanA, ND,
        offs_rd, col_rd, hz0, meanB, ND,
        offs_td, col_td, hd0, meanC, NZ);
    sage2_mfma<HID><<<ceil_div(ND, 64), 256, 0, stream>>>(
        meanA, meanB, hd0, Wt0_dd, Wt0_rd, bl0_dd, bl0_rd, hd1f, ND);
    sage_mfma<HID><<<ceil_div(NZ, 64), 256, 0, stream>>>(
        meanC, hz0, Wt0_td, bl0_td, hz1f, NZ);

    ln_kernel<HID, true, true><<<ceil_div(ND, 4), 256, 0, stream>>>(hd1f, g0_drug, b0_drug, hd1b, ND);
    ln_kernel<HID, true, true><<<ceil_div(NZ, 4), 256, 0, stream>>>(hz1f, g0_dis, b0_dis, hz1b, NZ);

    // ---------------- layer 1 ----------------
    agg8<<<AGG_GRID, 256, 0, stream>>>(
        offs_dd, col_dd, hd1b, meanA, ND,
        offs_rd, col_rd, hz1b, meanB, ND,
        offs_td, col_td, hd1b, meanC, NZ);
    sage2_mfma<OUTD><<<ceil_div(ND, 64), 256, 0, stream>>>(
        meanA, meanB, hd1b, Wt1_dd, Wt1_rd, bl1_dd, bl1_rd, outD, ND);
    sage_mfma<OUTD><<<ceil_div(NZ, 64), 256, 0, stream>>>(
        meanC, hz1b, Wt1_td, bl1_td, outZ, NZ);

    ln_kernel<OUTD, false, false><<<ceil_div(ND, 4), 256, 0, stream>>>(outD, g1_drug, b1_drug, outD, ND);
    ln_kernel<OUTD, false, false><<<ceil_div(NZ, 4), 256, 0, stream>>>(outZ, g1_dis, b1_dis, outZ, NZ);
}

// Round 9
// 753.131 us; speedup vs baseline: 1.4167x; 1.4167x over previous
//
#include <hip/hip_runtime.h>

// Problem constants (match reference setup_inputs)
constexpr int ND   = 50000;
constexpr int NZ   = 20000;
constexpr int HID  = 128;
constexpr int OUTD = 64;
constexpr int E    = 1000000;

constexpr int SCAN_TILE = 1024;
constexpr int NB_D = (ND + SCAN_TILE - 1) / SCAN_TILE;   // 49
constexpr int NB_Z = (NZ + SCAN_TILE - 1) / SCAN_TILE;   // 20
constexpr int NXCD  = 8;     // XCD count; blockIdx % 8 assumed round-robin -> XCD
constexpr int HISTC = 64;    // chunks per edge list (hist)
constexpr int FILLC = 96;    // chunks per edge list (fill)

static inline int ceil_div(int a, int b) { return (a + b - 1) / b; }

typedef __bf16 bf16x8 __attribute__((ext_vector_type(8)));
typedef float  f32x4  __attribute__((ext_vector_type(4)));

__device__ __forceinline__ float bf2f(unsigned short b) {
    return __uint_as_float(((unsigned int)b) << 16);
}
__device__ __forceinline__ unsigned short f2bf(float f) {
    unsigned int u = __float_as_uint(f);
    unsigned int r = (u + 0x7fffu + ((u >> 16) & 1u)) >> 16;
    return (unsigned short)r;
}

// ---------------------------------------------------------------------------
// Fused gather: rows [0,ND) from emb_drug[x_drug], rows [ND,ND+NZ) from emb_dis
// ---------------------------------------------------------------------------
__global__ __launch_bounds__(256) void gather_all(
    const float* __restrict__ emb_d, const int* __restrict__ idx_d,
    const float* __restrict__ emb_z, const int* __restrict__ idx_z,
    unsigned short* __restrict__ out_d, unsigned short* __restrict__ out_z)
{
    int t = blockIdx.x * blockDim.x + threadIdx.x;
    int row = t >> 5;
    int c = (t & 31) * 4;
    if (row >= ND + NZ) return;
    const float* src;
    unsigned short* dst;
    if (row < ND) {
        src = emb_d + (size_t)idx_d[row] * HID;
        dst = out_d + (size_t)row * HID;
    } else {
        int r2 = row - ND;
        src = emb_z + (size_t)idx_z[r2] * HID;
        dst = out_z + (size_t)r2 * HID;
    }
    float4 v = *reinterpret_cast<const float4*>(src + c);
    ushort4 o;
    o.x = f2bf(v.x); o.y = f2bf(v.y); o.z = f2bf(v.z); o.w = f2bf(v.w);
    *reinterpret_cast<ushort4*>(dst + c) = o;
}

// ---------------------------------------------------------------------------
// Fused weight prep: 6 weight pairs -> Wt[j][0:256] = bf16([Wl col j ; Wr col j])
// ---------------------------------------------------------------------------
struct PrepArgs {
    const float* wl[6];
    const float* wr[6];
    unsigned short* wt[6];
    int co[6];
    int boff[7];
};

__global__ __launch_bounds__(256) void prep_all(PrepArgs a)
{
    int sec = 0;
#pragma unroll
    for (int s = 0; s < 6; ++s)
        if ((int)blockIdx.x >= a.boff[s + 1]) sec = s + 1;
    int CO = a.co[sec];
    int idx = (blockIdx.x - a.boff[sec]) * 256 + threadIdx.x;  // CO*256 total
    int j = idx >> 8;
    int k = idx & 255;
    float v = (k < HID) ? a.wl[sec][k * CO + j] : a.wr[sec][(k - HID) * CO + j];
    a.wt[sec][(size_t)j * 256 + k] = f2bf(v);
}

// ---------------------------------------------------------------------------
// XCD-range-partitioned histogram: blockIdx%8 = destination range (-> XCD).
// dst reads are streaming/read-once -> nontemporal to avoid L2 pollution.
// ---------------------------------------------------------------------------
__global__ __launch_bounds__(256) void hist8(
    const int* __restrict__ d0, const int* __restrict__ d1, const int* __restrict__ d2,
    int* __restrict__ c0, int* __restrict__ c1, int* __restrict__ c2)
{
    const int range = blockIdx.x % NXCD;
    const int t = blockIdx.x / NXCD;
    const int list = t % 3;
    const int chunk = t / 3;                      // [0, HISTC)
    const int* dst = (list == 0) ? d0 : (list == 1) ? d1 : d2;
    int* cnt = (list == 0) ? c0 : (list == 1) ? c1 : c2;
    const int n = (list == 2) ? NZ : ND;
    const int rlo = range * (n / NXCD);
    const int rhi = (range == NXCD - 1) ? n : rlo + n / NXCD;
    const int elo = (int)((long long)chunk * E / HISTC);
    const int ehi = (int)((long long)(chunk + 1) * E / HISTC);
    for (int e = elo + threadIdx.x; e < ehi; e += 256) {
        int d = __builtin_nontemporal_load(dst + e);
        if (d >= rlo && d < rhi) atomicAdd(&cnt[d], 1);
    }
}

// ---------------------------------------------------------------------------
// Fused 3-phase scan over the 3 count arrays
// ---------------------------------------------------------------------------
__device__ __forceinline__ void scan_map(int b, int& which, int& tile) {
    if (b < NB_D) { which = 0; tile = b; }
    else if (b < 2 * NB_D) { which = 1; tile = b - NB_D; }
    else { which = 2; tile = b - 2 * NB_D; }
}

__global__ __launch_bounds__(256) void scan_part3(
    const int* __restrict__ c0, const int* __restrict__ c1, const int* __restrict__ c2,
    int* __restrict__ part)
{
    __shared__ int red[256];
    int which, tile;
    scan_map(blockIdx.x, which, tile);
    const int* cnt = (which == 0) ? c0 : (which == 1) ? c1 : c2;
    int n = (which == 2) ? NZ : ND;
    int base = tile * SCAN_TILE;
    int s = 0;
    for (int i = threadIdx.x; i < SCAN_TILE; i += 256) {
        int idx = base + i;
        if (idx < n) s += cnt[idx];
    }
    red[threadIdx.x] = s;
    __syncthreads();
#pragma unroll
    for (int off = 128; off > 0; off >>= 1) {
        if (threadIdx.x < off) red[threadIdx.x] += red[threadIdx.x + off];
        __syncthreads();
    }
    if (threadIdx.x == 0) part[which * 64 + tile] = red[0];
}

__global__ __launch_bounds__(64) void scan_small3(
    int* __restrict__ part,
    int* __restrict__ o0, int* __restrict__ o1, int* __restrict__ o2)
{
    int w = blockIdx.x;
    int np = (w == 2) ? NB_Z : NB_D;
    int n = (w == 2) ? NZ : ND;
    int* offs = (w == 0) ? o0 : (w == 1) ? o1 : o2;
    int* pb = part + w * 64;
    int lane = threadIdx.x;
    int orig = (lane < np) ? pb[lane] : 0;
    int v = orig;
#pragma unroll
    for (int off = 1; off < 64; off <<= 1) {
        int t = __shfl_up(v, off, 64);
        if (lane >= off) v += t;
    }
    if (lane < np) pb[lane] = v - orig;   // exclusive
    if (lane == 63) offs[n] = v;          // total
}

__global__ __launch_bounds__(256) void scan_write3(
    const int* __restrict__ c0, const int* __restrict__ c1, const int* __restrict__ c2,
    const int* __restrict__ part,
    int* __restrict__ o0, int* __restrict__ o1, int* __restrict__ o2,
    int* __restrict__ u0, int* __restrict__ u1, int* __restrict__ u2)
{
    __shared__ int sc[256];
    int which, tile;
    scan_map(blockIdx.x, which, tile);
    const int* cnt = (which == 0) ? c0 : (which == 1) ? c1 : c2;
    int* offs = (which == 0) ? o0 : (which == 1) ? o1 : o2;
    int* cur  = (which == 0) ? u0 : (which == 1) ? u1 : u2;
    int n = (which == 2) ? NZ : ND;

    const int tid = threadIdx.x;
    const int tb = tile * SCAN_TILE + tid * 4;
    int v[4];
    int s = 0;
#pragma unroll
    for (int k = 0; k < 4; ++k) {
        v[k] = (tb + k < n) ? cnt[tb + k] : 0;
        s += v[k];
    }
    sc[tid] = s;
    __syncthreads();
#pragma unroll
    for (int off = 1; off < 256; off <<= 1) {
        int t = (tid >= off) ? sc[tid - off] : 0;
        __syncthreads();
        sc[tid] += t;
        __syncthreads();
    }
    int ex = part[which * 64 + tile] + (tid ? sc[tid - 1] : 0);
#pragma unroll
    for (int k = 0; k < 4; ++k) {
        if (tb + k < n) {
            offs[tb + k] = ex;
            cur[tb + k] = ex;
            ex += v[k];
        }
    }
}

// ---------------------------------------------------------------------------
// XCD-range-partitioned CSR fill. Streaming dst/src reads are nontemporal so
// they don't evict the partially-written col lines from this XCD's L2.
// ---------------------------------------------------------------------------
__global__ __launch_bounds__(256) void fill8(
    const int* __restrict__ s0, const int* __restrict__ d0,
    const int* __restrict__ s1, const int* __restrict__ d1,
    const int* __restrict__ s2, const int* __restrict__ d2,
    int* __restrict__ u0, int* __restrict__ u1, int* __restrict__ u2,
    int* __restrict__ l0, int* __restrict__ l1, int* __restrict__ l2)
{
    const int range = blockIdx.x % NXCD;
    const int t = blockIdx.x / NXCD;
    const int list = t % 3;
    const int chunk = t / 3;                      // [0, FILLC)
    const int* src = (list == 0) ? s0 : (list == 1) ? s1 : s2;
    const int* dst = (list == 0) ? d0 : (list == 1) ? d1 : d2;
    int* cur = (list == 0) ? u0 : (list == 1) ? u1 : u2;
    int* col = (list == 0) ? l0 : (list == 1) ? l1 : l2;
    const int n = (list == 2) ? NZ : ND;
    const int rlo = range * (n / NXCD);
    const int rhi = (range == NXCD - 1) ? n : rlo + n / NXCD;
    const int elo = (int)((long long)chunk * E / FILLC);
    const int ehi = (int)((long long)(chunk + 1) * E / FILLC);
    for (int e = elo + threadIdx.x; e < ehi; e += 256) {
        int d = __builtin_nontemporal_load(dst + e);
        int s = __builtin_nontemporal_load(src + e);   // unconditional, coalesced
        if (d >= rlo && d < rhi) {
            int p = atomicAdd(&cur[d], 1);
            col[p] = s;
        }
    }
}

// ---------------------------------------------------------------------------
// Fused CSR mean-aggregation over 3 (offs,col,X,M) sets; one wave per node.
// Wave halves process alternate edges; 4-edge unroll (2 per half) for MLP.
// col[] is read-once -> nontemporal, so X rows keep L2 residency.
// ---------------------------------------------------------------------------
__global__ __launch_bounds__(256) void agg3(
    const int* __restrict__ o0, const int* __restrict__ c0,
    const unsigned short* __restrict__ X0, unsigned short* __restrict__ M0, int n0,
    const int* __restrict__ o1, const int* __restrict__ c1,
    const unsigned short* __restrict__ X1, unsigned short* __restrict__ M1, int n1,
    const int* __restrict__ o2, const int* __restrict__ c2,
    const unsigned short* __restrict__ X2, unsigned short* __restrict__ M2, int n2)
{
    int wid = (blockIdx.x * blockDim.x + threadIdx.x) >> 6;
    const int lane = threadIdx.x & 63;
    const int half = lane >> 5;
    const int l32 = lane & 31;

    const int* offs; const int* col;
    const unsigned short* X; unsigned short* M;
    if (wid < n0) { offs = o0; col = c0; X = X0; M = M0; }
    else if (wid < n0 + n1) { wid -= n0; offs = o1; col = c1; X = X1; M = M1; }
    else { wid -= n0 + n1; if (wid >= n2) return; offs = o2; col = c2; X = X2; M = M2; }

    const int start = offs[wid];
    const int end = offs[wid + 1];
    const unsigned short* Xl = X + l32 * 4;

    float a0 = 0.f, a1 = 0.f, a2 = 0.f, a3 = 0.f;
    float b0 = 0.f, b1 = 0.f, b2 = 0.f, b3 = 0.f;
    int e = start;
    for (; e + 3 < end; e += 4) {
        int sA = __builtin_nontemporal_load(col + e + 2 * half);
        int sB = __builtin_nontemporal_load(col + e + 2 * half + 1);
        uint2 vA = *reinterpret_cast<const uint2*>(Xl + (size_t)sA * HID);
        uint2 vB = *reinterpret_cast<const uint2*>(Xl + (size_t)sB * HID);
        a0 += bf2f((unsigned short)(vA.x & 0xffffu));
        a1 += bf2f((unsigned short)(vA.x >> 16));
        a2 += bf2f((unsigned short)(vA.y & 0xffffu));
        a3 += bf2f((unsigned short)(vA.y >> 16));
        b0 += bf2f((unsigned short)(vB.x & 0xffffu));
        b1 += bf2f((unsigned short)(vB.x >> 16));
        b2 += bf2f((unsigned short)(vB.y & 0xffffu));
        b3 += bf2f((unsigned short)(vB.y >> 16));
    }
    if (e + 1 < end) {
        int sA = col[e + half];
        uint2 vA = *reinterpret_cast<const uint2*>(Xl + (size_t)sA * HID);
        a0 += bf2f((unsigned short)(vA.x & 0xffffu));
        a1 += bf2f((unsigned short)(vA.x >> 16));
        a2 += bf2f((unsigned short)(vA.y & 0xffffu));
        a3 += bf2f((unsigned short)(vA.y >> 16));
        e += 2;
    }
    if (e < end && half == 0) {
        int sA = col[e];
        uint2 vA = *reinterpret_cast<const uint2*>(Xl + (size_t)sA * HID);
        a0 += bf2f((unsigned short)(vA.x & 0xffffu));
        a1 += bf2f((unsigned short)(vA.x >> 16));
        a2 += bf2f((unsigned short)(vA.y & 0xffffu));
        a3 += bf2f((unsigned short)(vA.y >> 16));
    }
    a0 += b0; a1 += b1; a2 += b2; a3 += b3;
    a0 += __shfl_xor(a0, 32, 64);
    a1 += __shfl_xor(a1, 32, 64);
    a2 += __shfl_xor(a2, 32, 64);
    a3 += __shfl_xor(a3, 32, 64);

    if (half == 0) {
        float inv = 1.0f / (float)max(end - start, 1);
        uint2 o;
        o.x = (unsigned int)f2bf(a0 * inv) | ((unsigned int)f2bf(a1 * inv) << 16);
        o.y = (unsigned int)f2bf(a2 * inv) | ((unsigned int)f2bf(a3 * inv) << 16);
        *reinterpret_cast<uint2*>(M + (size_t)wid * HID + l32 * 4) = o;
    }
}

// ---------------------------------------------------------------------------
// Single-edge-type MFMA SAGE (td): out = norm([mean|x]@Wt + bl), fp32 write.
// C/D layout: col = lane&15, row = (lane>>4)*4 + reg   [verified m89]
// ---------------------------------------------------------------------------
template <int CO>
__global__ __launch_bounds__(256) void sage_mfma(
    const unsigned short* __restrict__ Mb,
    const unsigned short* __restrict__ Xb,
    const unsigned short* __restrict__ Wt,
    const float* __restrict__ bl,
    float* __restrict__ H, int n)
{
    constexpr int NT = CO / 16;
    const int wave = threadIdx.x >> 6;
    const int lane = threadIdx.x & 63;
    const int r16 = lane & 15;
    const int chunk = lane >> 4;
    const int rowbase = blockIdx.x * 64 + wave * 16;
    if (rowbase >= n) return;

    const int arow = min(rowbase + r16, n - 1);
    const unsigned short* mrow = Mb + (size_t)arow * HID;
    const unsigned short* xrow = Xb + (size_t)arow * HID;

    bf16x8 a[8];
#pragma unroll
    for (int s = 0; s < 4; ++s) {
        a[s]     = *reinterpret_cast<const bf16x8*>(mrow + s * 32 + chunk * 8);
        a[4 + s] = *reinterpret_cast<const bf16x8*>(xrow + s * 32 + chunk * 8);
    }

    f32x4 acc[NT];
#pragma unroll
    for (int t = 0; t < NT; ++t) acc[t] = f32x4{0.f, 0.f, 0.f, 0.f};

#pragma unroll
    for (int t = 0; t < NT; ++t) {
        const unsigned short* wr_ = Wt + (size_t)(t * 16 + r16) * 256;
#pragma unroll
        for (int s = 0; s < 8; ++s) {
            bf16x8 b = *reinterpret_cast<const bf16x8*>(wr_ + s * 32 + chunk * 8);
            acc[t] = __builtin_amdgcn_mfma_f32_16x16x32_bf16(a[s], b, acc[t], 0, 0, 0);
        }
    }

    float ss[4] = {0.f, 0.f, 0.f, 0.f};
#pragma unroll
    for (int t = 0; t < NT; ++t) {
        float bias = bl[t * 16 + r16];
#pragma unroll
        for (int r = 0; r < 4; ++r) {
            acc[t][r] += bias;
            ss[r] += acc[t][r] * acc[t][r];
        }
    }
#pragma unroll
    for (int r = 0; r < 4; ++r)
#pragma unroll
        for (int m = 1; m < 16; m <<= 1)
            ss[r] += __shfl_xor(ss[r], m, 64);

#pragma unroll
    for (int r = 0; r < 4; ++r) {
        int node = rowbase + chunk * 4 + r;
        if (node < n) {
            float inv = 1.0f / fmaxf(sqrtf(ss[r]), 1e-12f);
#pragma unroll
            for (int t = 0; t < NT; ++t)
                H[(size_t)node * CO + t * 16 + r16] = acc[t][r] * inv;
        }
    }
}

// ---------------------------------------------------------------------------
// Dual-edge-type SAGE (dd + rd): H = norm(A-path) + norm(B-path), fp32 write.
// ---------------------------------------------------------------------------
template <int CO>
__global__ __launch_bounds__(256) void sage2_mfma(
    const unsigned short* __restrict__ MbA,
    const unsigned short* __restrict__ MbB,
    const unsigned short* __restrict__ Xb,
    const unsigned short* __restrict__ WtA,
    const unsigned short* __restrict__ WtB,
    const float* __restrict__ blA, const float* __restrict__ blB,
    float* __restrict__ H, int n)
{
    constexpr int NT = CO / 16;
    const int wave = threadIdx.x >> 6;
    const int lane = threadIdx.x & 63;
    const int r16 = lane & 15;
    const int chunk = lane >> 4;
    const int rowbase = blockIdx.x * 64 + wave * 16;
    if (rowbase >= n) return;

    const int arow = min(rowbase + r16, n - 1);
    const unsigned short* marow = MbA + (size_t)arow * HID;
    const unsigned short* mbrow = MbB + (size_t)arow * HID;
    const unsigned short* xrow  = Xb  + (size_t)arow * HID;

    bf16x8 aA[4], aB[4], ax[4];
#pragma unroll
    for (int s = 0; s < 4; ++s) {
        aA[s] = *reinterpret_cast<const bf16x8*>(marow + s * 32 + chunk * 8);
        aB[s] = *reinterpret_cast<const bf16x8*>(mbrow + s * 32 + chunk * 8);
        ax[s] = *reinterpret_cast<const bf16x8*>(xrow  + s * 32 + chunk * 8);
    }

    f32x4 accA[NT], accB[NT];
#pragma unroll
    for (int t = 0; t < NT; ++t) {
        accA[t] = f32x4{0.f, 0.f, 0.f, 0.f};
        accB[t] = f32x4{0.f, 0.f, 0.f, 0.f};
    }

#pragma unroll
    for (int t = 0; t < NT; ++t) {
        const unsigned short* wA = WtA + (size_t)(t * 16 + r16) * 256;
        const unsigned short* wB = WtB + (size_t)(t * 16 + r16) * 256;
#pragma unroll
        for (int s = 0; s < 4; ++s) {
            bf16x8 b0 = *reinterpret_cast<const bf16x8*>(wA + s * 32 + chunk * 8);
            accA[t] = __builtin_amdgcn_mfma_f32_16x16x32_bf16(aA[s], b0, accA[t], 0, 0, 0);
            bf16x8 b1 = *reinterpret_cast<const bf16x8*>(wA + HID + s * 32 + chunk * 8);
            accA[t] = __builtin_amdgcn_mfma_f32_16x16x32_bf16(ax[s], b1, accA[t], 0, 0, 0);
            bf16x8 b2 = *reinterpret_cast<const bf16x8*>(wB + s * 32 + chunk * 8);
            accB[t] = __builtin_amdgcn_mfma_f32_16x16x32_bf16(aB[s], b2, accB[t], 0, 0, 0);
            bf16x8 b3 = *reinterpret_cast<const bf16x8*>(wB + HID + s * 32 + chunk * 8);
            accB[t] = __builtin_amdgcn_mfma_f32_16x16x32_bf16(ax[s], b3, accB[t], 0, 0, 0);
        }
    }

    float ssA[4] = {0.f, 0.f, 0.f, 0.f};
    float ssB[4] = {0.f, 0.f, 0.f, 0.f};
#pragma unroll
    for (int t = 0; t < NT; ++t) {
        float biasA = blA[t * 16 + r16];
        float biasB = blB[t * 16 + r16];
#pragma unroll
        for (int r = 0; r < 4; ++r) {
            accA[t][r] += biasA;
            ssA[r] += accA[t][r] * accA[t][r];
            accB[t][r] += biasB;
            ssB[r] += accB[t][r] * accB[t][r];
        }
    }
#pragma unroll
    for (int r = 0; r < 4; ++r)
#pragma unroll
        for (int m = 1; m < 16; m <<= 1) {
            ssA[r] += __shfl_xor(ssA[r], m, 64);
            ssB[r] += __shfl_xor(ssB[r], m, 64);
        }

#pragma unroll
    for (int r = 0; r < 4; ++r) {
        int node = rowbase + chunk * 4 + r;
        if (node < n) {
            float invA = 1.0f / fmaxf(sqrtf(ssA[r]), 1e-12f);
            float invB = 1.0f / fmaxf(sqrtf(ssB[r]), 1e-12f);
#pragma unroll
            for (int t = 0; t < NT; ++t)
                H[(size_t)node * CO + t * 16 + r16] =
                    accA[t][r] * invA + accB[t][r] * invB;
        }
    }
}

// ---------------------------------------------------------------------------
// LayerNorm (+optional ReLU), one wave per row; fp32 in; bf16 or fp32 out.
// ---------------------------------------------------------------------------
template <int D, bool RELU, bool OUTBF>
__global__ __launch_bounds__(256) void ln_kernel(
    const float* __restrict__ X, const float* __restrict__ gg,
    const float* __restrict__ bb, void* __restrict__ outp, int n)
{
    constexpr int VPL = D / 64;
    int wid = (blockIdx.x * blockDim.x + threadIdx.x) >> 6;
    int lane = threadIdx.x & 63;
    if (wid >= n) return;

    float v[VPL], gv[VPL], bv[VPL];
    const float* xp = X + (size_t)wid * D + lane * VPL;
#pragma unroll
    for (int k = 0; k < VPL; ++k) {
        v[k] = xp[k];
        gv[k] = gg[lane * VPL + k];
        bv[k] = bb[lane * VPL + k];
    }
    float s = 0.f;
#pragma unroll
    for (int k = 0; k < VPL; ++k) s += v[k];
#pragma unroll
    for (int off = 32; off > 0; off >>= 1) s += __shfl_xor(s, off, 64);
    float m = s / D;
    float ss = 0.f;
#pragma unroll
    for (int k = 0; k < VPL; ++k) { float d = v[k] - m; ss += d * d; }
#pragma unroll
    for (int off = 32; off > 0; off >>= 1) ss += __shfl_xor(ss, off, 64);
    float rstd = rsqrtf(ss / D + 1e-5f);

    float y[VPL];
#pragma unroll
    for (int k = 0; k < VPL; ++k) {
        y[k] = gv[k] * (v[k] - m) * rstd + bv[k];
        if (RELU) y[k] = fmaxf(y[k], 0.f);
    }
    if (OUTBF) {
        unsigned short* op = (unsigned short*)outp + (size_t)wid * D + lane * VPL;
#pragma unroll
        for (int k = 0; k < VPL; ++k) op[k] = f2bf(y[k]);
    } else {
        float* op = (float*)outp + (size_t)wid * D + lane * VPL;
#pragma unroll
        for (int k = 0; k < VPL; ++k) op[k] = y[k];
    }
}

// ---------------------------------------------------------------------------
extern "C" void kernel_launch(void* const* d_in, const int* in_sizes, int n_in,
                              void* d_out, int out_size, void* d_ws, size_t ws_size,
                              hipStream_t stream)
{
    const int*   x_drug   = (const int*)d_in[0];
    const int*   x_dis    = (const int*)d_in[1];
    const float* emb_drug = (const float*)d_in[2];
    const float* emb_dis  = (const float*)d_in[3];
    const int*   src_dd   = (const int*)d_in[4];
    const int*   dst_dd   = (const int*)d_in[5];
    const int*   src_td   = (const int*)d_in[6];
    const int*   dst_td   = (const int*)d_in[7];
    const int*   src_rd   = (const int*)d_in[8];
    const int*   dst_rd   = (const int*)d_in[9];
    const float* Wl0_dd = (const float*)d_in[10];
    const float* bl0_dd = (const float*)d_in[11];
    const float* Wr0_dd = (const float*)d_in[12];
    const float* Wl0_td = (const float*)d_in[13];
    const float* bl0_td = (const float*)d_in[14];
    const float* Wr0_td = (const float*)d_in[15];
    const float* Wl0_rd = (const float*)d_in[16];
    const float* bl0_rd = (const float*)d_in[17];
    const float* Wr0_rd = (const float*)d_in[18];
    const float* Wl1_dd = (const float*)d_in[19];
    const float* bl1_dd = (const float*)d_in[20];
    const float* Wr1_dd = (const float*)d_in[21];
    const float* Wl1_td = (const float*)d_in[22];
    const float* bl1_td = (const float*)d_in[23];
    const float* Wr1_td = (const float*)d_in[24];
    const float* Wl1_rd = (const float*)d_in[25];
    const float* bl1_rd = (const float*)d_in[26];
    const float* Wr1_rd = (const float*)d_in[27];
    const float* g0_drug = (const float*)d_in[28];
    const float* b0_drug = (const float*)d_in[29];
    const float* g0_dis  = (const float*)d_in[30];
    const float* b0_dis  = (const float*)d_in[31];
    const float* g1_drug = (const float*)d_in[32];
    const float* b1_drug = (const float*)d_in[33];
    const float* g1_dis  = (const float*)d_in[34];
    const float* b1_dis  = (const float*)d_in[35];

    // ---------------- workspace layout ----------------
    char* wp = (char*)d_ws;
    auto alloc = [&](size_t bytes) { char* p = wp; wp += (bytes + 255) & ~size_t(255); return p; };

    unsigned short* hd0  = (unsigned short*)alloc((size_t)ND * HID * 2);
    unsigned short* hz0  = (unsigned short*)alloc((size_t)NZ * HID * 2);
    unsigned short* hd1b = (unsigned short*)alloc((size_t)ND * HID * 2);
    unsigned short* hz1b = (unsigned short*)alloc((size_t)NZ * HID * 2);
    unsigned short* meanA= (unsigned short*)alloc((size_t)ND * HID * 2);
    unsigned short* meanB= (unsigned short*)alloc((size_t)ND * HID * 2);
    unsigned short* meanC= (unsigned short*)alloc((size_t)NZ * HID * 2);
    float* hd1f = (float*)alloc((size_t)ND * HID * 4);
    float* hz1f = (float*)alloc((size_t)NZ * HID * 4);
    unsigned short* Wt0_dd = (unsigned short*)alloc((size_t)HID * 256 * 2);
    unsigned short* Wt0_rd = (unsigned short*)alloc((size_t)HID * 256 * 2);
    unsigned short* Wt0_td = (unsigned short*)alloc((size_t)HID * 256 * 2);
    unsigned short* Wt1_dd = (unsigned short*)alloc((size_t)OUTD * 256 * 2);
    unsigned short* Wt1_rd = (unsigned short*)alloc((size_t)OUTD * 256 * 2);
    unsigned short* Wt1_td = (unsigned short*)alloc((size_t)OUTD * 256 * 2);
    int* offs_dd = (int*)alloc((ND + 1) * 4);
    int* offs_rd = (int*)alloc((ND + 1) * 4);
    int* offs_td = (int*)alloc((NZ + 1) * 4);
    int* col_dd  = (int*)alloc((size_t)E * 4);
    int* col_rd  = (int*)alloc((size_t)E * 4);
    int* col_td  = (int*)alloc((size_t)E * 4);
    // contiguous count region (one memset covers all three)
    int* cnt_dd  = (int*)alloc(((size_t)(ND + 1) + (ND + 1) + (NZ + 1)) * 4);
    int* cnt_rd  = cnt_dd + (ND + 1);
    int* cnt_td  = cnt_rd + (ND + 1);
    int* cur_dd  = (int*)alloc((ND + 1) * 4);
    int* cur_rd  = (int*)alloc((ND + 1) * 4);
    int* cur_td  = (int*)alloc((NZ + 1) * 4);
    int* part    = (int*)alloc(3 * 64 * 4);

    float* outD = (float*)d_out;
    float* outZ = outD + (size_t)ND * OUTD;

    // ---------------- independent prep ----------------
    hipMemsetAsync(cnt_dd, 0, ((size_t)(ND + 1) + (ND + 1) + (NZ + 1)) * 4, stream);

    gather_all<<<ceil_div((ND + NZ) * 32, 256), 256, 0, stream>>>(
        emb_drug, x_drug, emb_dis, x_dis, hd0, hz0);

    PrepArgs pa;
    pa.wl[0] = Wl0_dd; pa.wr[0] = Wr0_dd; pa.wt[0] = Wt0_dd; pa.co[0] = HID;
    pa.wl[1] = Wl0_rd; pa.wr[1] = Wr0_rd; pa.wt[1] = Wt0_rd; pa.co[1] = HID;
    pa.wl[2] = Wl0_td; pa.wr[2] = Wr0_td; pa.wt[2] = Wt0_td; pa.co[2] = HID;
    pa.wl[3] = Wl1_dd; pa.wr[3] = Wr1_dd; pa.wt[3] = Wt1_dd; pa.co[3] = OUTD;
    pa.wl[4] = Wl1_rd; pa.wr[4] = Wr1_rd; pa.wt[4] = Wt1_rd; pa.co[4] = OUTD;
    pa.wl[5] = Wl1_td; pa.wr[5] = Wr1_td; pa.wt[5] = Wt1_td; pa.co[5] = OUTD;
    pa.boff[0] = 0;
    for (int s = 0; s < 6; ++s) pa.boff[s + 1] = pa.boff[s] + pa.co[s];
    prep_all<<<pa.boff[6], 256, 0, stream>>>(pa);

    // ---------------- CSR build (XCD-range-partitioned) ----------------
    hist8<<<3 * NXCD * HISTC, 256, 0, stream>>>(
        dst_dd, dst_rd, dst_td, cnt_dd, cnt_rd, cnt_td);
    scan_part3<<<2 * NB_D + NB_Z, 256, 0, stream>>>(cnt_dd, cnt_rd, cnt_td, part);
    scan_small3<<<3, 64, 0, stream>>>(part, offs_dd, offs_rd, offs_td);
    scan_write3<<<2 * NB_D + NB_Z, 256, 0, stream>>>(
        cnt_dd, cnt_rd, cnt_td, part, offs_dd, offs_rd, offs_td, cur_dd, cur_rd, cur_td);
    fill8<<<3 * NXCD * FILLC, 256, 0, stream>>>(
        src_dd, dst_dd, src_rd, dst_rd, src_td, dst_td,
        cur_dd, cur_rd, cur_td, col_dd, col_rd, col_td);

    // ---------------- layer 0 ----------------
    agg3<<<ceil_div((2 * ND + NZ) * 64, 256), 256, 0, stream>>>(
        offs_dd, col_dd, hd0, meanA, ND,
        offs_rd, col_rd, hz0, meanB, ND,
        offs_td, col_td, hd0, meanC, NZ);
    sage2_mfma<HID><<<ceil_div(ND, 64), 256, 0, stream>>>(
        meanA, meanB, hd0, Wt0_dd, Wt0_rd, bl0_dd, bl0_rd, hd1f, ND);
    sage_mfma<HID><<<ceil_div(NZ, 64), 256, 0, stream>>>(
        meanC, hz0, Wt0_td, bl0_td, hz1f, NZ);

    ln_kernel<HID, true, true><<<ceil_div(ND, 4), 256, 0, stream>>>(hd1f, g0_drug, b0_drug, hd1b, ND);
    ln_kernel<HID, true, true><<<ceil_div(NZ, 4), 256, 0, stream>>>(hz1f, g0_dis, b0_dis, hz1b, NZ);

    // ---------------- layer 1 ----------------
    agg3<<<ceil_div((2 * ND + NZ) * 64, 256), 256, 0, stream>>>(
        offs_dd, col_dd, hd1b, meanA, ND,
        offs_rd, col_rd, hz1b, meanB, ND,
        offs_td, col_td, hd1b, meanC, NZ);
    sage2_mfma<OUTD><<<ceil_div(ND, 64), 256, 0, stream>>>(
        meanA, meanB, hd1b, Wt1_dd, Wt1_rd, bl1_dd, bl1_rd, outD, ND);
    sage_mfma<OUTD><<<ceil_div(NZ, 64), 256, 0, stream>>>(
        meanC, hz1b, Wt1_td, bl1_td, outZ, NZ);

    ln_kernel<OUTD, false, false><<<ceil_div(ND, 4), 256, 0, stream>>>(outD, g1_drug, b1_drug, outD, ND);
    ln_kernel<OUTD, false, false><<<ceil_div(NZ, 4), 256, 0, stream>>>(outZ, g1_dis, b1_dis, outZ, NZ);
}

// Round 10
// 673.633 us; speedup vs baseline: 1.5839x; 1.1180x over previous
//
#include <hip/hip_runtime.h>

// Problem constants (match reference setup_inputs)
constexpr int ND   = 50000;
constexpr int NZ   = 20000;
constexpr int HID  = 128;
constexpr int OUTD = 64;
constexpr int E    = 1000000;

constexpr int SCAN_TILE = 1024;
constexpr int NB_D = (ND + SCAN_TILE - 1) / SCAN_TILE;   // 49
constexpr int NB_Z = (NZ + SCAN_TILE - 1) / SCAN_TILE;   // 20
constexpr int NXCD  = 8;     // XCD count; blockIdx % 8 assumed round-robin -> XCD
constexpr int HISTC = 64;    // chunks per edge list (hist)
constexpr int FILLC = 96;    // chunks per edge list (fill)

static inline int ceil_div(int a, int b) { return (a + b - 1) / b; }

typedef __bf16 bf16x8 __attribute__((ext_vector_type(8)));
typedef float  f32x4  __attribute__((ext_vector_type(4)));

__device__ __forceinline__ float bf2f(unsigned short b) {
    return __uint_as_float(((unsigned int)b) << 16);
}
__device__ __forceinline__ unsigned short f2bf(float f) {
    unsigned int u = __float_as_uint(f);
    unsigned int r = (u + 0x7fffu + ((u >> 16) & 1u)) >> 16;
    return (unsigned short)r;
}

// ---------------------------------------------------------------------------
// Fused gather: rows [0,ND) from emb_drug[x_drug], rows [ND,ND+NZ) from emb_dis
// ---------------------------------------------------------------------------
__global__ __launch_bounds__(256) void gather_all(
    const float* __restrict__ emb_d, const int* __restrict__ idx_d,
    const float* __restrict__ emb_z, const int* __restrict__ idx_z,
    unsigned short* __restrict__ out_d, unsigned short* __restrict__ out_z)
{
    int t = blockIdx.x * blockDim.x + threadIdx.x;
    int row = t >> 5;
    int c = (t & 31) * 4;
    if (row >= ND + NZ) return;
    const float* src;
    unsigned short* dst;
    if (row < ND) {
        src = emb_d + (size_t)idx_d[row] * HID;
        dst = out_d + (size_t)row * HID;
    } else {
        int r2 = row - ND;
        src = emb_z + (size_t)idx_z[r2] * HID;
        dst = out_z + (size_t)r2 * HID;
    }
    float4 v = *reinterpret_cast<const float4*>(src + c);
    ushort4 o;
    o.x = f2bf(v.x); o.y = f2bf(v.y); o.z = f2bf(v.z); o.w = f2bf(v.w);
    *reinterpret_cast<ushort4*>(dst + c) = o;
}

// ---------------------------------------------------------------------------
// Fused weight prep: 6 weight pairs -> Wt[j][0:256] = bf16([Wl col j ; Wr col j])
// ---------------------------------------------------------------------------
struct PrepArgs {
    const float* wl[6];
    const float* wr[6];
    unsigned short* wt[6];
    int co[6];
    int boff[7];
};

__global__ __launch_bounds__(256) void prep_all(PrepArgs a)
{
    int sec = 0;
#pragma unroll
    for (int s = 0; s < 6; ++s)
        if ((int)blockIdx.x >= a.boff[s + 1]) sec = s + 1;
    int CO = a.co[sec];
    int idx = (blockIdx.x - a.boff[sec]) * 256 + threadIdx.x;  // CO*256 total
    int j = idx >> 8;
    int k = idx & 255;
    float v = (k < HID) ? a.wl[sec][k * CO + j] : a.wr[sec][(k - HID) * CO + j];
    a.wt[sec][(size_t)j * 256 + k] = f2bf(v);
}

// ---------------------------------------------------------------------------
// XCD-range-partitioned histogram: blockIdx%8 = destination range (-> XCD)
// ---------------------------------------------------------------------------
__global__ __launch_bounds__(256) void hist8(
    const int* __restrict__ d0, const int* __restrict__ d1, const int* __restrict__ d2,
    int* __restrict__ c0, int* __restrict__ c1, int* __restrict__ c2)
{
    const int range = blockIdx.x % NXCD;
    const int t = blockIdx.x / NXCD;
    const int list = t % 3;
    const int chunk = t / 3;                      // [0, HISTC)
    const int* dst = (list == 0) ? d0 : (list == 1) ? d1 : d2;
    int* cnt = (list == 0) ? c0 : (list == 1) ? c1 : c2;
    const int n = (list == 2) ? NZ : ND;
    const int rlo = range * (n / NXCD);
    const int rhi = (range == NXCD - 1) ? n : rlo + n / NXCD;
    const int elo = (int)((long long)chunk * E / HISTC);
    const int ehi = (int)((long long)(chunk + 1) * E / HISTC);
    for (int e = elo + threadIdx.x; e < ehi; e += 256) {
        int d = dst[e];
        if (d >= rlo && d < rhi) atomicAdd(&cnt[d], 1);
    }
}

// ---------------------------------------------------------------------------
// Fused 3-phase scan over the 3 count arrays
// ---------------------------------------------------------------------------
__device__ __forceinline__ void scan_map(int b, int& which, int& tile) {
    if (b < NB_D) { which = 0; tile = b; }
    else if (b < 2 * NB_D) { which = 1; tile = b - NB_D; }
    else { which = 2; tile = b - 2 * NB_D; }
}

__global__ __launch_bounds__(256) void scan_part3(
    const int* __restrict__ c0, const int* __restrict__ c1, const int* __restrict__ c2,
    int* __restrict__ part)
{
    __shared__ int red[256];
    int which, tile;
    scan_map(blockIdx.x, which, tile);
    const int* cnt = (which == 0) ? c0 : (which == 1) ? c1 : c2;
    int n = (which == 2) ? NZ : ND;
    int base = tile * SCAN_TILE;
    int s = 0;
    for (int i = threadIdx.x; i < SCAN_TILE; i += 256) {
        int idx = base + i;
        if (idx < n) s += cnt[idx];
    }
    red[threadIdx.x] = s;
    __syncthreads();
#pragma unroll
    for (int off = 128; off > 0; off >>= 1) {
        if (threadIdx.x < off) red[threadIdx.x] += red[threadIdx.x + off];
        __syncthreads();
    }
    if (threadIdx.x == 0) part[which * 64 + tile] = red[0];
}

__global__ __launch_bounds__(64) void scan_small3(
    int* __restrict__ part,
    int* __restrict__ o0, int* __restrict__ o1, int* __restrict__ o2)
{
    int w = blockIdx.x;
    int np = (w == 2) ? NB_Z : NB_D;
    int n = (w == 2) ? NZ : ND;
    int* offs = (w == 0) ? o0 : (w == 1) ? o1 : o2;
    int* pb = part + w * 64;
    int lane = threadIdx.x;
    int orig = (lane < np) ? pb[lane] : 0;
    int v = orig;
#pragma unroll
    for (int off = 1; off < 64; off <<= 1) {
        int t = __shfl_up(v, off, 64);
        if (lane >= off) v += t;
    }
    if (lane < np) pb[lane] = v - orig;   // exclusive
    if (lane == 63) offs[n] = v;          // total
}

__global__ __launch_bounds__(256) void scan_write3(
    const int* __restrict__ c0, const int* __restrict__ c1, const int* __restrict__ c2,
    const int* __restrict__ part,
    int* __restrict__ o0, int* __restrict__ o1, int* __restrict__ o2,
    int* __restrict__ u0, int* __restrict__ u1, int* __restrict__ u2)
{
    __shared__ int sc[256];
    int which, tile;
    scan_map(blockIdx.x, which, tile);
    const int* cnt = (which == 0) ? c0 : (which == 1) ? c1 : c2;
    int* offs = (which == 0) ? o0 : (which == 1) ? o1 : o2;
    int* cur  = (which == 0) ? u0 : (which == 1) ? u1 : u2;
    int n = (which == 2) ? NZ : ND;

    const int tid = threadIdx.x;
    const int tb = tile * SCAN_TILE + tid * 4;
    int v[4];
    int s = 0;
#pragma unroll
    for (int k = 0; k < 4; ++k) {
        v[k] = (tb + k < n) ? cnt[tb + k] : 0;
        s += v[k];
    }
    sc[tid] = s;
    __syncthreads();
#pragma unroll
    for (int off = 1; off < 256; off <<= 1) {
        int t = (tid >= off) ? sc[tid - off] : 0;
        __syncthreads();
        sc[tid] += t;
        __syncthreads();
    }
    int ex = part[which * 64 + tile] + (tid ? sc[tid - 1] : 0);
#pragma unroll
    for (int k = 0; k < 4; ++k) {
        if (tb + k < n) {
            offs[tb + k] = ex;
            cur[tb + k] = ex;
            ex += v[k];
        }
    }
}

// ---------------------------------------------------------------------------
// XCD-range-partitioned CSR fill
// ---------------------------------------------------------------------------
__global__ __launch_bounds__(256) void fill8(
    const int* __restrict__ s0, const int* __restrict__ d0,
    const int* __restrict__ s1, const int* __restrict__ d1,
    const int* __restrict__ s2, const int* __restrict__ d2,
    int* __restrict__ u0, int* __restrict__ u1, int* __restrict__ u2,
    int* __restrict__ l0, int* __restrict__ l1, int* __restrict__ l2)
{
    const int range = blockIdx.x % NXCD;
    const int t = blockIdx.x / NXCD;
    const int list = t % 3;
    const int chunk = t / 3;                      // [0, FILLC)
    const int* src = (list == 0) ? s0 : (list == 1) ? s1 : s2;
    const int* dst = (list == 0) ? d0 : (list == 1) ? d1 : d2;
    int* cur = (list == 0) ? u0 : (list == 1) ? u1 : u2;
    int* col = (list == 0) ? l0 : (list == 1) ? l1 : l2;
    const int n = (list == 2) ? NZ : ND;
    const int rlo = range * (n / NXCD);
    const int rhi = (range == NXCD - 1) ? n : rlo + n / NXCD;
    const int elo = (int)((long long)chunk * E / FILLC);
    const int ehi = (int)((long long)(chunk + 1) * E / FILLC);
    for (int e = elo + threadIdx.x; e < ehi; e += 256) {
        int d = dst[e];
        int s = src[e];                            // unconditional, coalesced
        if (d >= rlo && d < rhi) {
            int p = atomicAdd(&cur[d], 1);
            col[p] = s;
        }
    }
}

// ---------------------------------------------------------------------------
// Fused CSR mean-aggregation, 128-col rows; one wave per node, 4-edge unroll.
// ---------------------------------------------------------------------------
__global__ __launch_bounds__(256) void agg3_128(
    const int* __restrict__ o0, const int* __restrict__ c0,
    const unsigned short* __restrict__ X0, unsigned short* __restrict__ M0, int n0,
    const int* __restrict__ o1, const int* __restrict__ c1,
    const unsigned short* __restrict__ X1, unsigned short* __restrict__ M1, int n1,
    const int* __restrict__ o2, const int* __restrict__ c2,
    const unsigned short* __restrict__ X2, unsigned short* __restrict__ M2, int n2)
{
    int wid = (blockIdx.x * blockDim.x + threadIdx.x) >> 6;
    const int lane = threadIdx.x & 63;
    const int half = lane >> 5;
    const int l32 = lane & 31;

    const int* offs; const int* col;
    const unsigned short* X; unsigned short* M;
    if (wid < n0) { offs = o0; col = c0; X = X0; M = M0; }
    else if (wid < n0 + n1) { wid -= n0; offs = o1; col = c1; X = X1; M = M1; }
    else { wid -= n0 + n1; if (wid >= n2) return; offs = o2; col = c2; X = X2; M = M2; }

    const int start = offs[wid];
    const int end = offs[wid + 1];
    const unsigned short* Xl = X + l32 * 4;

    float a0 = 0.f, a1 = 0.f, a2 = 0.f, a3 = 0.f;
    float b0 = 0.f, b1 = 0.f, b2 = 0.f, b3 = 0.f;
    int e = start;
    for (; e + 3 < end; e += 4) {
        int sA = col[e + 2 * half];
        int sB = col[e + 2 * half + 1];
        uint2 vA = *reinterpret_cast<const uint2*>(Xl + (size_t)sA * HID);
        uint2 vB = *reinterpret_cast<const uint2*>(Xl + (size_t)sB * HID);
        a0 += bf2f((unsigned short)(vA.x & 0xffffu));
        a1 += bf2f((unsigned short)(vA.x >> 16));
        a2 += bf2f((unsigned short)(vA.y & 0xffffu));
        a3 += bf2f((unsigned short)(vA.y >> 16));
        b0 += bf2f((unsigned short)(vB.x & 0xffffu));
        b1 += bf2f((unsigned short)(vB.x >> 16));
        b2 += bf2f((unsigned short)(vB.y & 0xffffu));
        b3 += bf2f((unsigned short)(vB.y >> 16));
    }
    if (e + 1 < end) {
        int sA = col[e + half];
        uint2 vA = *reinterpret_cast<const uint2*>(Xl + (size_t)sA * HID);
        a0 += bf2f((unsigned short)(vA.x & 0xffffu));
        a1 += bf2f((unsigned short)(vA.x >> 16));
        a2 += bf2f((unsigned short)(vA.y & 0xffffu));
        a3 += bf2f((unsigned short)(vA.y >> 16));
        e += 2;
    }
    if (e < end && half == 0) {
        int sA = col[e];
        uint2 vA = *reinterpret_cast<const uint2*>(Xl + (size_t)sA * HID);
        a0 += bf2f((unsigned short)(vA.x & 0xffffu));
        a1 += bf2f((unsigned short)(vA.x >> 16));
        a2 += bf2f((unsigned short)(vA.y & 0xffffu));
        a3 += bf2f((unsigned short)(vA.y >> 16));
    }
    a0 += b0; a1 += b1; a2 += b2; a3 += b3;
    a0 += __shfl_xor(a0, 32, 64);
    a1 += __shfl_xor(a1, 32, 64);
    a2 += __shfl_xor(a2, 32, 64);
    a3 += __shfl_xor(a3, 32, 64);

    if (half == 0) {
        float inv = 1.0f / (float)max(end - start, 1);
        uint2 o;
        o.x = (unsigned int)f2bf(a0 * inv) | ((unsigned int)f2bf(a1 * inv) << 16);
        o.y = (unsigned int)f2bf(a2 * inv) | ((unsigned int)f2bf(a3 * inv) << 16);
        *reinterpret_cast<uint2*>(M + (size_t)wid * HID + l32 * 4) = o;
    }
}

// ---------------------------------------------------------------------------
// Fused CSR mean-aggregation, 64-col rows (pre-transformed Z). 128 B/edge.
// ---------------------------------------------------------------------------
__global__ __launch_bounds__(256) void agg3_64(
    const int* __restrict__ o0, const int* __restrict__ c0,
    const unsigned short* __restrict__ X0, unsigned short* __restrict__ M0, int n0,
    const int* __restrict__ o1, const int* __restrict__ c1,
    const unsigned short* __restrict__ X1, unsigned short* __restrict__ M1, int n1,
    const int* __restrict__ o2, const int* __restrict__ c2,
    const unsigned short* __restrict__ X2, unsigned short* __restrict__ M2, int n2)
{
    int wid = (blockIdx.x * blockDim.x + threadIdx.x) >> 6;
    const int lane = threadIdx.x & 63;
    const int half = lane >> 5;
    const int l32 = lane & 31;

    const int* offs; const int* col;
    const unsigned short* X; unsigned short* M;
    if (wid < n0) { offs = o0; col = c0; X = X0; M = M0; }
    else if (wid < n0 + n1) { wid -= n0; offs = o1; col = c1; X = X1; M = M1; }
    else { wid -= n0 + n1; if (wid >= n2) return; offs = o2; col = c2; X = X2; M = M2; }

    const int start = offs[wid];
    const int end = offs[wid + 1];
    const unsigned short* Xl = X + l32 * 2;

    float a0 = 0.f, a1 = 0.f, b0 = 0.f, b1 = 0.f;
    int e = start;
    for (; e + 3 < end; e += 4) {
        int sA = col[e + 2 * half];
        int sB = col[e + 2 * half + 1];
        unsigned vA = *reinterpret_cast<const unsigned*>(Xl + (size_t)sA * OUTD);
        unsigned vB = *reinterpret_cast<const unsigned*>(Xl + (size_t)sB * OUTD);
        a0 += bf2f((unsigned short)(vA & 0xffffu));
        a1 += bf2f((unsigned short)(vA >> 16));
        b0 += bf2f((unsigned short)(vB & 0xffffu));
        b1 += bf2f((unsigned short)(vB >> 16));
    }
    if (e + 1 < end) {
        int sA = col[e + half];
        unsigned vA = *reinterpret_cast<const unsigned*>(Xl + (size_t)sA * OUTD);
        a0 += bf2f((unsigned short)(vA & 0xffffu));
        a1 += bf2f((unsigned short)(vA >> 16));
        e += 2;
    }
    if (e < end && half == 0) {
        int sA = col[e];
        unsigned vA = *reinterpret_cast<const unsigned*>(Xl + (size_t)sA * OUTD);
        a0 += bf2f((unsigned short)(vA & 0xffffu));
        a1 += bf2f((unsigned short)(vA >> 16));
    }
    a0 += b0; a1 += b1;
    a0 += __shfl_xor(a0, 32, 64);
    a1 += __shfl_xor(a1, 32, 64);

    if (half == 0) {
        float inv = 1.0f / (float)max(end - start, 1);
        unsigned o = (unsigned)f2bf(a0 * inv) | ((unsigned)f2bf(a1 * inv) << 16);
        *reinterpret_cast<unsigned*>(M + (size_t)wid * OUTD + l32 * 2) = o;
    }
}

// ---------------------------------------------------------------------------
// Fused transform: Z = H @ Wl (first half of Wt), CO=64, K=128. 3 sections.
// ---------------------------------------------------------------------------
__global__ __launch_bounds__(256) void xform3(
    const unsigned short* __restrict__ H0, const unsigned short* __restrict__ W0,
    unsigned short* __restrict__ Z0, int n0,
    const unsigned short* __restrict__ H1, const unsigned short* __restrict__ W1,
    unsigned short* __restrict__ Z1, int n1,
    const unsigned short* __restrict__ H2, const unsigned short* __restrict__ W2,
    unsigned short* __restrict__ Z2, int n2)
{
    const int b0 = (n0 + 63) / 64, b1 = (n1 + 63) / 64;
    int b = blockIdx.x;
    const unsigned short *H, *W; unsigned short* Z; int n;
    if (b < b0) { H = H0; W = W0; Z = Z0; n = n0; }
    else if (b < b0 + b1) { b -= b0; H = H1; W = W1; Z = Z1; n = n1; }
    else { b -= b0 + b1; H = H2; W = W2; Z = Z2; n = n2; }

    constexpr int NT = OUTD / 16;   // 4
    const int wave = threadIdx.x >> 6;
    const int lane = threadIdx.x & 63;
    const int r16 = lane & 15;
    const int chunk = lane >> 4;
    const int rowbase = b * 64 + wave * 16;
    if (rowbase >= n) return;

    const int arow = min(rowbase + r16, n - 1);
    const unsigned short* hrow = H + (size_t)arow * HID;

    bf16x8 a[4];
#pragma unroll
    for (int s = 0; s < 4; ++s)
        a[s] = *reinterpret_cast<const bf16x8*>(hrow + s * 32 + chunk * 8);

    f32x4 acc[NT];
#pragma unroll
    for (int t = 0; t < NT; ++t) acc[t] = f32x4{0.f, 0.f, 0.f, 0.f};

#pragma unroll
    for (int t = 0; t < NT; ++t) {
        const unsigned short* w_ = W + (size_t)(t * 16 + r16) * 256;   // Wl half
#pragma unroll
        for (int s = 0; s < 4; ++s) {
            bf16x8 bfrag = *reinterpret_cast<const bf16x8*>(w_ + s * 32 + chunk * 8);
            acc[t] = __builtin_amdgcn_mfma_f32_16x16x32_bf16(a[s], bfrag, acc[t], 0, 0, 0);
        }
    }

#pragma unroll
    for (int r = 0; r < 4; ++r) {
        int node = rowbase + chunk * 4 + r;
        if (node < n) {
#pragma unroll
            for (int t = 0; t < NT; ++t)
                Z[(size_t)node * OUTD + t * 16 + r16] = f2bf(acc[t][r]);
        }
    }
}

// ---------------------------------------------------------------------------
// Layer-0 SAGE kernels (K=256 over [mean|x]), unchanged from round 7.
// C/D layout: col = lane&15, row = (lane>>4)*4 + reg   [verified m89]
// ---------------------------------------------------------------------------
template <int CO>
__global__ __launch_bounds__(256) void sage_mfma(
    const unsigned short* __restrict__ Mb,
    const unsigned short* __restrict__ Xb,
    const unsigned short* __restrict__ Wt,
    const float* __restrict__ bl,
    float* __restrict__ H, int n)
{
    constexpr int NT = CO / 16;
    const int wave = threadIdx.x >> 6;
    const int lane = threadIdx.x & 63;
    const int r16 = lane & 15;
    const int chunk = lane >> 4;
    const int rowbase = blockIdx.x * 64 + wave * 16;
    if (rowbase >= n) return;

    const int arow = min(rowbase + r16, n - 1);
    const unsigned short* mrow = Mb + (size_t)arow * HID;
    const unsigned short* xrow = Xb + (size_t)arow * HID;

    bf16x8 a[8];
#pragma unroll
    for (int s = 0; s < 4; ++s) {
        a[s]     = *reinterpret_cast<const bf16x8*>(mrow + s * 32 + chunk * 8);
        a[4 + s] = *reinterpret_cast<const bf16x8*>(xrow + s * 32 + chunk * 8);
    }

    f32x4 acc[NT];
#pragma unroll
    for (int t = 0; t < NT; ++t) acc[t] = f32x4{0.f, 0.f, 0.f, 0.f};

#pragma unroll
    for (int t = 0; t < NT; ++t) {
        const unsigned short* wr_ = Wt + (size_t)(t * 16 + r16) * 256;
#pragma unroll
        for (int s = 0; s < 8; ++s) {
            bf16x8 b = *reinterpret_cast<const bf16x8*>(wr_ + s * 32 + chunk * 8);
            acc[t] = __builtin_amdgcn_mfma_f32_16x16x32_bf16(a[s], b, acc[t], 0, 0, 0);
        }
    }

    float ss[4] = {0.f, 0.f, 0.f, 0.f};
#pragma unroll
    for (int t = 0; t < NT; ++t) {
        float bias = bl[t * 16 + r16];
#pragma unroll
        for (int r = 0; r < 4; ++r) {
            acc[t][r] += bias;
            ss[r] += acc[t][r] * acc[t][r];
        }
    }
#pragma unroll
    for (int r = 0; r < 4; ++r)
#pragma unroll
        for (int m = 1; m < 16; m <<= 1)
            ss[r] += __shfl_xor(ss[r], m, 64);

#pragma unroll
    for (int r = 0; r < 4; ++r) {
        int node = rowbase + chunk * 4 + r;
        if (node < n) {
            float inv = 1.0f / fmaxf(sqrtf(ss[r]), 1e-12f);
#pragma unroll
            for (int t = 0; t < NT; ++t)
                H[(size_t)node * CO + t * 16 + r16] = acc[t][r] * inv;
        }
    }
}

template <int CO>
__global__ __launch_bounds__(256) void sage2_mfma(
    const unsigned short* __restrict__ MbA,
    const unsigned short* __restrict__ MbB,
    const unsigned short* __restrict__ Xb,
    const unsigned short* __restrict__ WtA,
    const unsigned short* __restrict__ WtB,
    const float* __restrict__ blA, const float* __restrict__ blB,
    float* __restrict__ H, int n)
{
    constexpr int NT = CO / 16;
    const int wave = threadIdx.x >> 6;
    const int lane = threadIdx.x & 63;
    const int r16 = lane & 15;
    const int chunk = lane >> 4;
    const int rowbase = blockIdx.x * 64 + wave * 16;
    if (rowbase >= n) return;

    const int arow = min(rowbase + r16, n - 1);
    const unsigned short* marow = MbA + (size_t)arow * HID;
    const unsigned short* mbrow = MbB + (size_t)arow * HID;
    const unsigned short* xrow  = Xb  + (size_t)arow * HID;

    bf16x8 aA[4], aB[4], ax[4];
#pragma unroll
    for (int s = 0; s < 4; ++s) {
        aA[s] = *reinterpret_cast<const bf16x8*>(marow + s * 32 + chunk * 8);
        aB[s] = *reinterpret_cast<const bf16x8*>(mbrow + s * 32 + chunk * 8);
        ax[s] = *reinterpret_cast<const bf16x8*>(xrow  + s * 32 + chunk * 8);
    }

    f32x4 accA[NT], accB[NT];
#pragma unroll
    for (int t = 0; t < NT; ++t) {
        accA[t] = f32x4{0.f, 0.f, 0.f, 0.f};
        accB[t] = f32x4{0.f, 0.f, 0.f, 0.f};
    }

#pragma unroll
    for (int t = 0; t < NT; ++t) {
        const unsigned short* wA = WtA + (size_t)(t * 16 + r16) * 256;
        const unsigned short* wB = WtB + (size_t)(t * 16 + r16) * 256;
#pragma unroll
        for (int s = 0; s < 4; ++s) {
            bf16x8 b0 = *reinterpret_cast<const bf16x8*>(wA + s * 32 + chunk * 8);
            accA[t] = __builtin_amdgcn_mfma_f32_16x16x32_bf16(aA[s], b0, accA[t], 0, 0, 0);
            bf16x8 b1 = *reinterpret_cast<const bf16x8*>(wA + HID + s * 32 + chunk * 8);
            accA[t] = __builtin_amdgcn_mfma_f32_16x16x32_bf16(ax[s], b1, accA[t], 0, 0, 0);
            bf16x8 b2 = *reinterpret_cast<const bf16x8*>(wB + s * 32 + chunk * 8);
            accB[t] = __builtin_amdgcn_mfma_f32_16x16x32_bf16(aB[s], b2, accB[t], 0, 0, 0);
            bf16x8 b3 = *reinterpret_cast<const bf16x8*>(wB + HID + s * 32 + chunk * 8);
            accB[t] = __builtin_amdgcn_mfma_f32_16x16x32_bf16(ax[s], b3, accB[t], 0, 0, 0);
        }
    }

    float ssA[4] = {0.f, 0.f, 0.f, 0.f};
    float ssB[4] = {0.f, 0.f, 0.f, 0.f};
#pragma unroll
    for (int t = 0; t < NT; ++t) {
        float biasA = blA[t * 16 + r16];
        float biasB = blB[t * 16 + r16];
#pragma unroll
        for (int r = 0; r < 4; ++r) {
            accA[t][r] += biasA;
            ssA[r] += accA[t][r] * accA[t][r];
            accB[t][r] += biasB;
            ssB[r] += accB[t][r] * accB[t][r];
        }
    }
#pragma unroll
    for (int r = 0; r < 4; ++r)
#pragma unroll
        for (int m = 1; m < 16; m <<= 1) {
            ssA[r] += __shfl_xor(ssA[r], m, 64);
            ssB[r] += __shfl_xor(ssB[r], m, 64);
        }

#pragma unroll
    for (int r = 0; r < 4; ++r) {
        int node = rowbase + chunk * 4 + r;
        if (node < n) {
            float invA = 1.0f / fmaxf(sqrtf(ssA[r]), 1e-12f);
            float invB = 1.0f / fmaxf(sqrtf(ssB[r]), 1e-12f);
#pragma unroll
            for (int t = 0; t < NT; ++t)
                H[(size_t)node * CO + t * 16 + r16] =
                    accA[t][r] * invA + accB[t][r] * invB;
        }
    }
}

// ---------------------------------------------------------------------------
// Layer-1 SAGE with pre-aggregated meanZ (= mean@Wl): only x@Wr via MFMA.
//   path = meanZ + bl + x@Wr; out = norm(pathA) [+ norm(pathB)]
// ---------------------------------------------------------------------------
__global__ __launch_bounds__(256) void sage2z(
    const unsigned short* __restrict__ MZa,   // [n][64]
    const unsigned short* __restrict__ MZb,   // [n][64]
    const unsigned short* __restrict__ Xb,    // [n][128]
    const unsigned short* __restrict__ WtA,   // [64][256] (Wr at +HID)
    const unsigned short* __restrict__ WtB,
    const float* __restrict__ blA, const float* __restrict__ blB,
    float* __restrict__ H, int n)
{
    constexpr int NT = OUTD / 16;
    const int wave = threadIdx.x >> 6;
    const int lane = threadIdx.x & 63;
    const int r16 = lane & 15;
    const int chunk = lane >> 4;
    const int rowbase = blockIdx.x * 64 + wave * 16;
    if (rowbase >= n) return;

    const int arow = min(rowbase + r16, n - 1);
    const unsigned short* xrow = Xb + (size_t)arow * HID;

    bf16x8 ax[4];
#pragma unroll
    for (int s = 0; s < 4; ++s)
        ax[s] = *reinterpret_cast<const bf16x8*>(xrow + s * 32 + chunk * 8);

    f32x4 accA[NT], accB[NT];
#pragma unroll
    for (int t = 0; t < NT; ++t) {
        accA[t] = f32x4{0.f, 0.f, 0.f, 0.f};
        accB[t] = f32x4{0.f, 0.f, 0.f, 0.f};
    }

#pragma unroll
    for (int t = 0; t < NT; ++t) {
        const unsigned short* wA = WtA + (size_t)(t * 16 + r16) * 256 + HID;
        const unsigned short* wB = WtB + (size_t)(t * 16 + r16) * 256 + HID;
#pragma unroll
        for (int s = 0; s < 4; ++s) {
            bf16x8 b0 = *reinterpret_cast<const bf16x8*>(wA + s * 32 + chunk * 8);
            accA[t] = __builtin_amdgcn_mfma_f32_16x16x32_bf16(ax[s], b0, accA[t], 0, 0, 0);
            bf16x8 b1 = *reinterpret_cast<const bf16x8*>(wB + s * 32 + chunk * 8);
            accB[t] = __builtin_amdgcn_mfma_f32_16x16x32_bf16(ax[s], b1, accB[t], 0, 0, 0);
        }
    }

    float ssA[4] = {0.f, 0.f, 0.f, 0.f};
    float ssB[4] = {0.f, 0.f, 0.f, 0.f};
#pragma unroll
    for (int r = 0; r < 4; ++r) {
        int cl = min(rowbase + chunk * 4 + r, n - 1);
#pragma unroll
        for (int t = 0; t < NT; ++t) {
            int j = t * 16 + r16;
            float vA = accA[t][r] + blA[j] + bf2f(MZa[(size_t)cl * OUTD + j]);
            accA[t][r] = vA;
            ssA[r] += vA * vA;
            float vB = accB[t][r] + blB[j] + bf2f(MZb[(size_t)cl * OUTD + j]);
            accB[t][r] = vB;
            ssB[r] += vB * vB;
        }
    }
#pragma unroll
    for (int r = 0; r < 4; ++r)
#pragma unroll
        for (int m = 1; m < 16; m <<= 1) {
            ssA[r] += __shfl_xor(ssA[r], m, 64);
            ssB[r] += __shfl_xor(ssB[r], m, 64);
        }

#pragma unroll
    for (int r = 0; r < 4; ++r) {
        int node = rowbase + chunk * 4 + r;
        if (node < n) {
            float invA = 1.0f / fmaxf(sqrtf(ssA[r]), 1e-12f);
            float invB = 1.0f / fmaxf(sqrtf(ssB[r]), 1e-12f);
#pragma unroll
            for (int t = 0; t < NT; ++t)
                H[(size_t)node * OUTD + t * 16 + r16] =
                    accA[t][r] * invA + accB[t][r] * invB;
        }
    }
}

__global__ __launch_bounds__(256) void sagez(
    const unsigned short* __restrict__ MZ,    // [n][64]
    const unsigned short* __restrict__ Xb,    // [n][128]
    const unsigned short* __restrict__ Wt,    // [64][256] (Wr at +HID)
    const float* __restrict__ bl,
    float* __restrict__ H, int n)
{
    constexpr int NT = OUTD / 16;
    const int wave = threadIdx.x >> 6;
    const int lane = threadIdx.x & 63;
    const int r16 = lane & 15;
    const int chunk = lane >> 4;
    const int rowbase = blockIdx.x * 64 + wave * 16;
    if (rowbase >= n) return;

    const int arow = min(rowbase + r16, n - 1);
    const unsigned short* xrow = Xb + (size_t)arow * HID;

    bf16x8 ax[4];
#pragma unroll
    for (int s = 0; s < 4; ++s)
        ax[s] = *reinterpret_cast<const bf16x8*>(xrow + s * 32 + chunk * 8);

    f32x4 acc[NT];
#pragma unroll
    for (int t = 0; t < NT; ++t) acc[t] = f32x4{0.f, 0.f, 0.f, 0.f};

#pragma unroll
    for (int t = 0; t < NT; ++t) {
        const unsigned short* w_ = Wt + (size_t)(t * 16 + r16) * 256 + HID;
#pragma unroll
        for (int s = 0; s < 4; ++s) {
            bf16x8 b = *reinterpret_cast<const bf16x8*>(w_ + s * 32 + chunk * 8);
            acc[t] = __builtin_amdgcn_mfma_f32_16x16x32_bf16(ax[s], b, acc[t], 0, 0, 0);
        }
    }

    float ss[4] = {0.f, 0.f, 0.f, 0.f};
#pragma unroll
    for (int r = 0; r < 4; ++r) {
        int cl = min(rowbase + chunk * 4 + r, n - 1);
#pragma unroll
        for (int t = 0; t < NT; ++t) {
            int j = t * 16 + r16;
            float v = acc[t][r] + bl[j] + bf2f(MZ[(size_t)cl * OUTD + j]);
            acc[t][r] = v;
            ss[r] += v * v;
        }
    }
#pragma unroll
    for (int r = 0; r < 4; ++r)
#pragma unroll
        for (int m = 1; m < 16; m <<= 1)
            ss[r] += __shfl_xor(ss[r], m, 64);

#pragma unroll
    for (int r = 0; r < 4; ++r) {
        int node = rowbase + chunk * 4 + r;
        if (node < n) {
            float inv = 1.0f / fmaxf(sqrtf(ss[r]), 1e-12f);
#pragma unroll
            for (int t = 0; t < NT; ++t)
                H[(size_t)node * OUTD + t * 16 + r16] = acc[t][r] * inv;
        }
    }
}

// ---------------------------------------------------------------------------
// LayerNorm (+optional ReLU), one wave per row; fp32 in; bf16 or fp32 out.
// ---------------------------------------------------------------------------
template <int D, bool RELU, bool OUTBF>
__global__ __launch_bounds__(256) void ln_kernel(
    const float* __restrict__ X, const float* __restrict__ gg,
    const float* __restrict__ bb, void* __restrict__ outp, int n)
{
    constexpr int VPL = D / 64;
    int wid = (blockIdx.x * blockDim.x + threadIdx.x) >> 6;
    int lane = threadIdx.x & 63;
    if (wid >= n) return;

    float v[VPL], gv[VPL], bv[VPL];
    const float* xp = X + (size_t)wid * D + lane * VPL;
#pragma unroll
    for (int k = 0; k < VPL; ++k) {
        v[k] = xp[k];
        gv[k] = gg[lane * VPL + k];
        bv[k] = bb[lane * VPL + k];
    }
    float s = 0.f;
#pragma unroll
    for (int k = 0; k < VPL; ++k) s += v[k];
#pragma unroll
    for (int off = 32; off > 0; off >>= 1) s += __shfl_xor(s, off, 64);
    float m = s / D;
    float ss = 0.f;
#pragma unroll
    for (int k = 0; k < VPL; ++k) { float d = v[k] - m; ss += d * d; }
#pragma unroll
    for (int off = 32; off > 0; off >>= 1) ss += __shfl_xor(ss, off, 64);
    float rstd = rsqrtf(ss / D + 1e-5f);

    float y[VPL];
#pragma unroll
    for (int k = 0; k < VPL; ++k) {
        y[k] = gv[k] * (v[k] - m) * rstd + bv[k];
        if (RELU) y[k] = fmaxf(y[k], 0.f);
    }
    if (OUTBF) {
        unsigned short* op = (unsigned short*)outp + (size_t)wid * D + lane * VPL;
#pragma unroll
        for (int k = 0; k < VPL; ++k) op[k] = f2bf(y[k]);
    } else {
        float* op = (float*)outp + (size_t)wid * D + lane * VPL;
#pragma unroll
        for (int k = 0; k < VPL; ++k) op[k] = y[k];
    }
}

// ---------------------------------------------------------------------------
extern "C" void kernel_launch(void* const* d_in, const int* in_sizes, int n_in,
                              void* d_out, int out_size, void* d_ws, size_t ws_size,
                              hipStream_t stream)
{
    const int*   x_drug   = (const int*)d_in[0];
    const int*   x_dis    = (const int*)d_in[1];
    const float* emb_drug = (const float*)d_in[2];
    const float* emb_dis  = (const float*)d_in[3];
    const int*   src_dd   = (const int*)d_in[4];
    const int*   dst_dd   = (const int*)d_in[5];
    const int*   src_td   = (const int*)d_in[6];
    const int*   dst_td   = (const int*)d_in[7];
    const int*   src_rd   = (const int*)d_in[8];
    const int*   dst_rd   = (const int*)d_in[9];
    const float* Wl0_dd = (const float*)d_in[10];
    const float* bl0_dd = (const float*)d_in[11];
    const float* Wr0_dd = (const float*)d_in[12];
    const float* Wl0_td = (const float*)d_in[13];
    const float* bl0_td = (const float*)d_in[14];
    const float* Wr0_td = (const float*)d_in[15];
    const float* Wl0_rd = (const float*)d_in[16];
    const float* bl0_rd = (const float*)d_in[17];
    const float* Wr0_rd = (const float*)d_in[18];
    const float* Wl1_dd = (const float*)d_in[19];
    const float* bl1_dd = (const float*)d_in[20];
    const float* Wr1_dd = (const float*)d_in[21];
    const float* Wl1_td = (const float*)d_in[22];
    const float* bl1_td = (const float*)d_in[23];
    const float* Wr1_td = (const float*)d_in[24];
    const float* Wl1_rd = (const float*)d_in[25];
    const float* bl1_rd = (const float*)d_in[26];
    const float* Wr1_rd = (const float*)d_in[27];
    const float* g0_drug = (const float*)d_in[28];
    const float* b0_drug = (const float*)d_in[29];
    const float* g0_dis  = (const float*)d_in[30];
    const float* b0_dis  = (const float*)d_in[31];
    const float* g1_drug = (const float*)d_in[32];
    const float* b1_drug = (const float*)d_in[33];
    const float* g1_dis  = (const float*)d_in[34];
    const float* b1_dis  = (const float*)d_in[35];

    // ---------------- workspace layout ----------------
    char* wp = (char*)d_ws;
    auto alloc = [&](size_t bytes) { char* p = wp; wp += (bytes + 255) & ~size_t(255); return p; };

    unsigned short* hd0  = (unsigned short*)alloc((size_t)ND * HID * 2);
    unsigned short* hz0  = (unsigned short*)alloc((size_t)NZ * HID * 2);
    unsigned short* hd1b = (unsigned short*)alloc((size_t)ND * HID * 2);
    unsigned short* hz1b = (unsigned short*)alloc((size_t)NZ * HID * 2);
    unsigned short* meanA= (unsigned short*)alloc((size_t)ND * HID * 2);
    unsigned short* meanB= (unsigned short*)alloc((size_t)ND * HID * 2);
    unsigned short* meanC= (unsigned short*)alloc((size_t)NZ * HID * 2);
    unsigned short* Zdd  = (unsigned short*)alloc((size_t)ND * OUTD * 2);
    unsigned short* Zrd  = (unsigned short*)alloc((size_t)NZ * OUTD * 2);
    unsigned short* Ztd  = (unsigned short*)alloc((size_t)ND * OUTD * 2);
    float* hd1f = (float*)alloc((size_t)ND * HID * 4);
    float* hz1f = (float*)alloc((size_t)NZ * HID * 4);
    unsigned short* Wt0_dd = (unsigned short*)alloc((size_t)HID * 256 * 2);
    unsigned short* Wt0_rd = (unsigned short*)alloc((size_t)HID * 256 * 2);
    unsigned short* Wt0_td = (unsigned short*)alloc((size_t)HID * 256 * 2);
    unsigned short* Wt1_dd = (unsigned short*)alloc((size_t)OUTD * 256 * 2);
    unsigned short* Wt1_rd = (unsigned short*)alloc((size_t)OUTD * 256 * 2);
    unsigned short* Wt1_td = (unsigned short*)alloc((size_t)OUTD * 256 * 2);
    int* offs_dd = (int*)alloc((ND + 1) * 4);
    int* offs_rd = (int*)alloc((ND + 1) * 4);
    int* offs_td = (int*)alloc((NZ + 1) * 4);
    int* col_dd  = (int*)alloc((size_t)E * 4);
    int* col_rd  = (int*)alloc((size_t)E * 4);
    int* col_td  = (int*)alloc((size_t)E * 4);
    // contiguous count region (one memset covers all three)
    int* cnt_dd  = (int*)alloc(((size_t)(ND + 1) + (ND + 1) + (NZ + 1)) * 4);
    int* cnt_rd  = cnt_dd + (ND + 1);
    int* cnt_td  = cnt_rd + (ND + 1);
    int* cur_dd  = (int*)alloc((ND + 1) * 4);
    int* cur_rd  = (int*)alloc((ND + 1) * 4);
    int* cur_td  = (int*)alloc((NZ + 1) * 4);
    int* part    = (int*)alloc(3 * 64 * 4);

    float* outD = (float*)d_out;
    float* outZ = outD + (size_t)ND * OUTD;

    // ---------------- independent prep ----------------
    hipMemsetAsync(cnt_dd, 0, ((size_t)(ND + 1) + (ND + 1) + (NZ + 1)) * 4, stream);

    gather_all<<<ceil_div((ND + NZ) * 32, 256), 256, 0, stream>>>(
        emb_drug, x_drug, emb_dis, x_dis, hd0, hz0);

    PrepArgs pa;
    pa.wl[0] = Wl0_dd; pa.wr[0] = Wr0_dd; pa.wt[0] = Wt0_dd; pa.co[0] = HID;
    pa.wl[1] = Wl0_rd; pa.wr[1] = Wr0_rd; pa.wt[1] = Wt0_rd; pa.co[1] = HID;
    pa.wl[2] = Wl0_td; pa.wr[2] = Wr0_td; pa.wt[2] = Wt0_td; pa.co[2] = HID;
    pa.wl[3] = Wl1_dd; pa.wr[3] = Wr1_dd; pa.wt[3] = Wt1_dd; pa.co[3] = OUTD;
    pa.wl[4] = Wl1_rd; pa.wr[4] = Wr1_rd; pa.wt[4] = Wt1_rd; pa.co[4] = OUTD;
    pa.wl[5] = Wl1_td; pa.wr[5] = Wr1_td; pa.wt[5] = Wt1_td; pa.co[5] = OUTD;
    pa.boff[0] = 0;
    for (int s = 0; s < 6; ++s) pa.boff[s + 1] = pa.boff[s] + pa.co[s];
    prep_all<<<pa.boff[6], 256, 0, stream>>>(pa);

    // ---------------- CSR build (XCD-range-partitioned) ----------------
    hist8<<<3 * NXCD * HISTC, 256, 0, stream>>>(
        dst_dd, dst_rd, dst_td, cnt_dd, cnt_rd, cnt_td);
    scan_part3<<<2 * NB_D + NB_Z, 256, 0, stream>>>(cnt_dd, cnt_rd, cnt_td, part);
    scan_small3<<<3, 64, 0, stream>>>(part, offs_dd, offs_rd, offs_td);
    scan_write3<<<2 * NB_D + NB_Z, 256, 0, stream>>>(
        cnt_dd, cnt_rd, cnt_td, part, offs_dd, offs_rd, offs_td, cur_dd, cur_rd, cur_td);
    fill8<<<3 * NXCD * FILLC, 256, 0, stream>>>(
        src_dd, dst_dd, src_rd, dst_rd, src_td, dst_td,
        cur_dd, cur_rd, cur_td, col_dd, col_rd, col_td);

    // ---------------- layer 0 ----------------
    agg3_128<<<ceil_div((2 * ND + NZ) * 64, 256), 256, 0, stream>>>(
        offs_dd, col_dd, hd0, meanA, ND,
        offs_rd, col_rd, hz0, meanB, ND,
        offs_td, col_td, hd0, meanC, NZ);
    sage2_mfma<HID><<<ceil_div(ND, 64), 256, 0, stream>>>(
        meanA, meanB, hd0, Wt0_dd, Wt0_rd, bl0_dd, bl0_rd, hd1f, ND);
    sage_mfma<HID><<<ceil_div(NZ, 64), 256, 0, stream>>>(
        meanC, hz0, Wt0_td, bl0_td, hz1f, NZ);

    ln_kernel<HID, true, true><<<ceil_div(ND, 4), 256, 0, stream>>>(hd1f, g0_drug, b0_drug, hd1b, ND);
    ln_kernel<HID, true, true><<<ceil_div(NZ, 4), 256, 0, stream>>>(hz1f, g0_dis, b0_dis, hz1b, NZ);

    // ---------------- layer 1 (transform-then-aggregate) ----------------
    // Z = H @ Wl for each edge type (linearity: mean(H)@Wl == mean(H@Wl))
    xform3<<<ceil_div(ND, 64) * 2 + ceil_div(NZ, 64), 256, 0, stream>>>(
        hd1b, Wt1_dd, Zdd, ND,
        hz1b, Wt1_rd, Zrd, NZ,
        hd1b, Wt1_td, Ztd, ND);

    // aggregate 64-col Z rows (half the gather traffic of 128-col H rows)
    agg3_64<<<ceil_div((2 * ND + NZ) * 64, 256), 256, 0, stream>>>(
        offs_dd, col_dd, Zdd, meanA, ND,
        offs_rd, col_rd, Zrd, meanB, ND,
        offs_td, col_td, Ztd, meanC, NZ);

    sage2z<<<ceil_div(ND, 64), 256, 0, stream>>>(
        meanA, meanB, hd1b, Wt1_dd, Wt1_rd, bl1_dd, bl1_rd, outD, ND);
    sagez<<<ceil_div(NZ, 64), 256, 0, stream>>>(
        meanC, hz1b, Wt1_td, bl1_td, outZ, NZ);

    ln_kernel<OUTD, false, false><<<ceil_div(ND, 4), 256, 0, stream>>>(outD, g1_drug, b1_drug, outD, ND);
    ln_kernel<OUTD, false, false><<<ceil_div(NZ, 4), 256, 0, stream>>>(outZ, g1_dis, b1_dis, outZ, NZ);
}

// Round 11
// 665.945 us; speedup vs baseline: 1.6022x; 1.0115x over previous
//
#include <hip/hip_runtime.h>

// Problem constants (match reference setup_inputs)
constexpr int ND   = 50000;
constexpr int NZ   = 20000;
constexpr int HID  = 128;
constexpr int OUTD = 64;
constexpr int E    = 1000000;

constexpr int SCAN_TILE = 1024;
constexpr int NB_D = (ND + SCAN_TILE - 1) / SCAN_TILE;   // 49
constexpr int NB_Z = (NZ + SCAN_TILE - 1) / SCAN_TILE;   // 20
constexpr int NXCD = 8;      // XCD count; blockIdx % 8 assumed round-robin -> XCD
constexpr int CHK  = 96;     // edge chunks per list (bucket build)
constexpr int HB2  = 32;     // blocks per (list,range) in bhist/bfill

static inline int ceil_div(int a, int b) { return (a + b - 1) / b; }

typedef __bf16 bf16x8 __attribute__((ext_vector_type(8)));
typedef float  f32x4  __attribute__((ext_vector_type(4)));

__device__ __forceinline__ float bf2f(unsigned short b) {
    return __uint_as_float(((unsigned int)b) << 16);
}
__device__ __forceinline__ unsigned short f2bf(float f) {
    unsigned int u = __float_as_uint(f);
    unsigned int r = (u + 0x7fffu + ((u >> 16) & 1u)) >> 16;
    return (unsigned short)r;
}

// ---------------------------------------------------------------------------
// Fused gather: rows [0,ND) from emb_drug[x_drug], rows [ND,ND+NZ) from emb_dis
// ---------------------------------------------------------------------------
__global__ __launch_bounds__(256) void gather_all(
    const float* __restrict__ emb_d, const int* __restrict__ idx_d,
    const float* __restrict__ emb_z, const int* __restrict__ idx_z,
    unsigned short* __restrict__ out_d, unsigned short* __restrict__ out_z)
{
    int t = blockIdx.x * blockDim.x + threadIdx.x;
    int row = t >> 5;
    int c = (t & 31) * 4;
    if (row >= ND + NZ) return;
    const float* src;
    unsigned short* dst;
    if (row < ND) {
        src = emb_d + (size_t)idx_d[row] * HID;
        dst = out_d + (size_t)row * HID;
    } else {
        int r2 = row - ND;
        src = emb_z + (size_t)idx_z[r2] * HID;
        dst = out_z + (size_t)r2 * HID;
    }
    float4 v = *reinterpret_cast<const float4*>(src + c);
    ushort4 o;
    o.x = f2bf(v.x); o.y = f2bf(v.y); o.z = f2bf(v.z); o.w = f2bf(v.w);
    *reinterpret_cast<ushort4*>(dst + c) = o;
}

// ---------------------------------------------------------------------------
// Fused weight prep: 6 weight pairs -> Wt[j][0:256] = bf16([Wl col j ; Wr col j])
// ---------------------------------------------------------------------------
struct PrepArgs {
    const float* wl[6];
    const float* wr[6];
    unsigned short* wt[6];
    int co[6];
    int boff[7];
};

__global__ __launch_bounds__(256) void prep_all(PrepArgs a)
{
    int sec = 0;
#pragma unroll
    for (int s = 0; s < 6; ++s)
        if ((int)blockIdx.x >= a.boff[s + 1]) sec = s + 1;
    int CO = a.co[sec];
    int idx = (blockIdx.x - a.boff[sec]) * 256 + threadIdx.x;  // CO*256 total
    int j = idx >> 8;
    int k = idx & 255;
    float v = (k < HID) ? a.wl[sec][k * CO + j] : a.wr[sec][(k - HID) * CO + j];
    a.wt[sec][(size_t)j * 256 + k] = f2bf(v);
}

// ---------------------------------------------------------------------------
// Bucketed CSR build, phase 1: per-(list,chunk) range histogram (LDS)
// rc[(list*CHK + chunk)*8 + r] = #edges in chunk with dst in range r
// ---------------------------------------------------------------------------
__global__ __launch_bounds__(256) void bcount(
    const int* __restrict__ d0, const int* __restrict__ d1, const int* __restrict__ d2,
    int* __restrict__ rc)
{
    __shared__ int lc[8];
    const int list = blockIdx.x / CHK;
    const int chunk = blockIdx.x % CHK;
    if (threadIdx.x < 8) lc[threadIdx.x] = 0;
    __syncthreads();
    const int* dst = (list == 0) ? d0 : (list == 1) ? d1 : d2;
    const int elo = (int)((long long)chunk * E / CHK);
    const int ehi = (int)((long long)(chunk + 1) * E / CHK);
    for (int e = elo + threadIdx.x; e < ehi; e += 256) {
        int d = dst[e];
        int r = (list == 2) ? min(d / (NZ / NXCD), 7) : min(d / (ND / NXCD), 7);
        atomicAdd(&lc[r], 1);
    }
    __syncthreads();
    if (threadIdx.x < 8) rc[(list * CHK + chunk) * 8 + threadIdx.x] = lc[threadIdx.x];
}

// ---------------------------------------------------------------------------
// Phase 2: exclusive scan of rc in order (list, range, chunk); per-list reset.
// wpos = write base per (list,chunk,range); rbase[list][r] = bucket segment base
// (rbase[list][8] = E).  Single block, 256 threads x 9 elements.
// ---------------------------------------------------------------------------
__global__ __launch_bounds__(256) void bscan(
    const int* __restrict__ rc, int* __restrict__ wpos, int* __restrict__ rbase)
{
    __shared__ int sc[256];
    const int tid = threadIdx.x;
    const int lo = tid * 9;                      // 2304 = 256*9 total
    int v[9];
    int s = 0;
#pragma unroll
    for (int k = 0; k < 9; ++k) {
        int i = lo + k;
        int list = i / (8 * CHK), rem = i % (8 * CHK);
        int r = rem / CHK, c = rem % CHK;
        v[k] = rc[(list * CHK + c) * 8 + r];
        s += v[k];
    }
    sc[tid] = s;
    __syncthreads();
    for (int off = 1; off < 256; off <<= 1) {
        int t = (tid >= off) ? sc[tid - off] : 0;
        __syncthreads();
        sc[tid] += t;
        __syncthreads();
    }
    int run = tid ? sc[tid - 1] : 0;
#pragma unroll
    for (int k = 0; k < 9; ++k) {
        int i = lo + k;
        int list = i / (8 * CHK), rem = i % (8 * CHK);
        int r = rem / CHK, c = rem % CHK;
        int base = run - list * E;               // per-list reset (each list sums to E)
        wpos[(list * CHK + c) * 8 + r] = base;
        if (c == 0) rbase[list * 9 + r] = base;
        run += v[k];
    }
    if (tid < 3) rbase[tid * 9 + 8] = E;
}

// ---------------------------------------------------------------------------
// Phase 3: scatter edges (d,s) into per-range buckets at pre-scanned positions.
// Block-local LDS running counters; blocks own disjoint slot sets -> no races.
// ---------------------------------------------------------------------------
__global__ __launch_bounds__(256) void bscatter(
    const int* __restrict__ s0, const int* __restrict__ d0,
    const int* __restrict__ s1, const int* __restrict__ d1,
    const int* __restrict__ s2, const int* __restrict__ d2,
    const int* __restrict__ wpos,
    int2* __restrict__ b0, int2* __restrict__ b1, int2* __restrict__ b2)
{
    __shared__ int lc[8];
    const int list = blockIdx.x / CHK;
    const int chunk = blockIdx.x % CHK;
    if (threadIdx.x < 8) lc[threadIdx.x] = wpos[(list * CHK + chunk) * 8 + threadIdx.x];
    __syncthreads();
    const int* src = (list == 0) ? s0 : (list == 1) ? s1 : s2;
    const int* dst = (list == 0) ? d0 : (list == 1) ? d1 : d2;
    int2* bkt = (list == 0) ? b0 : (list == 1) ? b1 : b2;
    const int elo = (int)((long long)chunk * E / CHK);
    const int ehi = (int)((long long)(chunk + 1) * E / CHK);
    for (int e = elo + threadIdx.x; e < ehi; e += 256) {
        int d = dst[e];
        int s = src[e];
        int r = (list == 2) ? min(d / (NZ / NXCD), 7) : min(d / (ND / NXCD), 7);
        int p = atomicAdd(&lc[r], 1);
        bkt[p] = make_int2(d, s);
    }
}

// ---------------------------------------------------------------------------
// Phase 4: per-node histogram from buckets; blockIdx%8 = range -> XCD-local cnt
// ---------------------------------------------------------------------------
__global__ __launch_bounds__(256) void bhist(
    const int2* __restrict__ b0, const int2* __restrict__ b1, const int2* __restrict__ b2,
    const int* __restrict__ rbase,
    int* __restrict__ c0, int* __restrict__ c1, int* __restrict__ c2)
{
    const int range = blockIdx.x & 7;
    const int t = blockIdx.x >> 3;
    const int list = t % 3;
    const int sub = t / 3;                       // [0, HB2)
    const int2* bkt = (list == 0) ? b0 : (list == 1) ? b1 : b2;
    int* cnt = (list == 0) ? c0 : (list == 1) ? c1 : c2;
    const int s0 = rbase[list * 9 + range];
    const int s1 = rbase[list * 9 + range + 1];
    const int len = s1 - s0;
    const int lo = s0 + (int)((long long)sub * len / HB2);
    const int hi = s0 + (int)((long long)(sub + 1) * len / HB2);
    for (int i = lo + threadIdx.x; i < hi; i += 256)
        atomicAdd(&cnt[bkt[i].x], 1);
}

// ---------------------------------------------------------------------------
// Fused 3-phase scan over the 3 count arrays (unchanged)
// ---------------------------------------------------------------------------
__device__ __forceinline__ void scan_map(int b, int& which, int& tile) {
    if (b < NB_D) { which = 0; tile = b; }
    else if (b < 2 * NB_D) { which = 1; tile = b - NB_D; }
    else { which = 2; tile = b - 2 * NB_D; }
}

__global__ __launch_bounds__(256) void scan_part3(
    const int* __restrict__ c0, const int* __restrict__ c1, const int* __restrict__ c2,
    int* __restrict__ part)
{
    __shared__ int red[256];
    int which, tile;
    scan_map(blockIdx.x, which, tile);
    const int* cnt = (which == 0) ? c0 : (which == 1) ? c1 : c2;
    int n = (which == 2) ? NZ : ND;
    int base = tile * SCAN_TILE;
    int s = 0;
    for (int i = threadIdx.x; i < SCAN_TILE; i += 256) {
        int idx = base + i;
        if (idx < n) s += cnt[idx];
    }
    red[threadIdx.x] = s;
    __syncthreads();
#pragma unroll
    for (int off = 128; off > 0; off >>= 1) {
        if (threadIdx.x < off) red[threadIdx.x] += red[threadIdx.x + off];
        __syncthreads();
    }
    if (threadIdx.x == 0) part[which * 64 + tile] = red[0];
}

__global__ __launch_bounds__(64) void scan_small3(
    int* __restrict__ part,
    int* __restrict__ o0, int* __restrict__ o1, int* __restrict__ o2)
{
    int w = blockIdx.x;
    int np = (w == 2) ? NB_Z : NB_D;
    int n = (w == 2) ? NZ : ND;
    int* offs = (w == 0) ? o0 : (w == 1) ? o1 : o2;
    int* pb = part + w * 64;
    int lane = threadIdx.x;
    int orig = (lane < np) ? pb[lane] : 0;
    int v = orig;
#pragma unroll
    for (int off = 1; off < 64; off <<= 1) {
        int t = __shfl_up(v, off, 64);
        if (lane >= off) v += t;
    }
    if (lane < np) pb[lane] = v - orig;   // exclusive
    if (lane == 63) offs[n] = v;          // total
}

__global__ __launch_bounds__(256) void scan_write3(
    const int* __restrict__ c0, const int* __restrict__ c1, const int* __restrict__ c2,
    const int* __restrict__ part,
    int* __restrict__ o0, int* __restrict__ o1, int* __restrict__ o2,
    int* __restrict__ u0, int* __restrict__ u1, int* __restrict__ u2)
{
    __shared__ int sc[256];
    int which, tile;
    scan_map(blockIdx.x, which, tile);
    const int* cnt = (which == 0) ? c0 : (which == 1) ? c1 : c2;
    int* offs = (which == 0) ? o0 : (which == 1) ? o1 : o2;
    int* cur  = (which == 0) ? u0 : (which == 1) ? u1 : u2;
    int n = (which == 2) ? NZ : ND;

    const int tid = threadIdx.x;
    const int tb = tile * SCAN_TILE + tid * 4;
    int v[4];
    int s = 0;
#pragma unroll
    for (int k = 0; k < 4; ++k) {
        v[k] = (tb + k < n) ? cnt[tb + k] : 0;
        s += v[k];
    }
    sc[tid] = s;
    __syncthreads();
#pragma unroll
    for (int off = 1; off < 256; off <<= 1) {
        int t = (tid >= off) ? sc[tid - off] : 0;
        __syncthreads();
        sc[tid] += t;
        __syncthreads();
    }
    int ex = part[which * 64 + tile] + (tid ? sc[tid - 1] : 0);
#pragma unroll
    for (int k = 0; k < 4; ++k) {
        if (tb + k < n) {
            offs[tb + k] = ex;
            cur[tb + k] = ex;
            ex += v[k];
        }
    }
}

// ---------------------------------------------------------------------------
// Phase 5: CSR fill from buckets; blockIdx%8 = range -> XCD-local cur and col
// ---------------------------------------------------------------------------
__global__ __launch_bounds__(256) void bfill(
    const int2* __restrict__ b0, const int2* __restrict__ b1, const int2* __restrict__ b2,
    const int* __restrict__ rbase,
    int* __restrict__ u0, int* __restrict__ u1, int* __restrict__ u2,
    int* __restrict__ l0, int* __restrict__ l1, int* __restrict__ l2)
{
    const int range = blockIdx.x & 7;
    const int t = blockIdx.x >> 3;
    const int list = t % 3;
    const int sub = t / 3;
    const int2* bkt = (list == 0) ? b0 : (list == 1) ? b1 : b2;
    int* cur = (list == 0) ? u0 : (list == 1) ? u1 : u2;
    int* col = (list == 0) ? l0 : (list == 1) ? l1 : l2;
    const int s0 = rbase[list * 9 + range];
    const int s1 = rbase[list * 9 + range + 1];
    const int len = s1 - s0;
    const int lo = s0 + (int)((long long)sub * len / HB2);
    const int hi = s0 + (int)((long long)(sub + 1) * len / HB2);
    for (int i = lo + threadIdx.x; i < hi; i += 256) {
        int2 e = bkt[i];
        int p = atomicAdd(&cur[e.x], 1);
        col[p] = e.y;
    }
}

// ---------------------------------------------------------------------------
// Fused CSR mean-aggregation, 128-col rows; one wave per node, 4-edge unroll.
// ---------------------------------------------------------------------------
__global__ __launch_bounds__(256) void agg3_128(
    const int* __restrict__ o0, const int* __restrict__ c0,
    const unsigned short* __restrict__ X0, unsigned short* __restrict__ M0, int n0,
    const int* __restrict__ o1, const int* __restrict__ c1,
    const unsigned short* __restrict__ X1, unsigned short* __restrict__ M1, int n1,
    const int* __restrict__ o2, const int* __restrict__ c2,
    const unsigned short* __restrict__ X2, unsigned short* __restrict__ M2, int n2)
{
    int wid = (blockIdx.x * blockDim.x + threadIdx.x) >> 6;
    const int lane = threadIdx.x & 63;
    const int half = lane >> 5;
    const int l32 = lane & 31;

    const int* offs; const int* col;
    const unsigned short* X; unsigned short* M;
    if (wid < n0) { offs = o0; col = c0; X = X0; M = M0; }
    else if (wid < n0 + n1) { wid -= n0; offs = o1; col = c1; X = X1; M = M1; }
    else { wid -= n0 + n1; if (wid >= n2) return; offs = o2; col = c2; X = X2; M = M2; }

    const int start = offs[wid];
    const int end = offs[wid + 1];
    const unsigned short* Xl = X + l32 * 4;

    float a0 = 0.f, a1 = 0.f, a2 = 0.f, a3 = 0.f;
    float b0 = 0.f, b1 = 0.f, b2 = 0.f, b3 = 0.f;
    int e = start;
    for (; e + 3 < end; e += 4) {
        int sA = col[e + 2 * half];
        int sB = col[e + 2 * half + 1];
        uint2 vA = *reinterpret_cast<const uint2*>(Xl + (size_t)sA * HID);
        uint2 vB = *reinterpret_cast<const uint2*>(Xl + (size_t)sB * HID);
        a0 += bf2f((unsigned short)(vA.x & 0xffffu));
        a1 += bf2f((unsigned short)(vA.x >> 16));
        a2 += bf2f((unsigned short)(vA.y & 0xffffu));
        a3 += bf2f((unsigned short)(vA.y >> 16));
        b0 += bf2f((unsigned short)(vB.x & 0xffffu));
        b1 += bf2f((unsigned short)(vB.x >> 16));
        b2 += bf2f((unsigned short)(vB.y & 0xffffu));
        b3 += bf2f((unsigned short)(vB.y >> 16));
    }
    if (e + 1 < end) {
        int sA = col[e + half];
        uint2 vA = *reinterpret_cast<const uint2*>(Xl + (size_t)sA * HID);
        a0 += bf2f((unsigned short)(vA.x & 0xffffu));
        a1 += bf2f((unsigned short)(vA.x >> 16));
        a2 += bf2f((unsigned short)(vA.y & 0xffffu));
        a3 += bf2f((unsigned short)(vA.y >> 16));
        e += 2;
    }
    if (e < end && half == 0) {
        int sA = col[e];
        uint2 vA = *reinterpret_cast<const uint2*>(Xl + (size_t)sA * HID);
        a0 += bf2f((unsigned short)(vA.x & 0xffffu));
        a1 += bf2f((unsigned short)(vA.x >> 16));
        a2 += bf2f((unsigned short)(vA.y & 0xffffu));
        a3 += bf2f((unsigned short)(vA.y >> 16));
    }
    a0 += b0; a1 += b1; a2 += b2; a3 += b3;
    a0 += __shfl_xor(a0, 32, 64);
    a1 += __shfl_xor(a1, 32, 64);
    a2 += __shfl_xor(a2, 32, 64);
    a3 += __shfl_xor(a3, 32, 64);

    if (half == 0) {
        float inv = 1.0f / (float)max(end - start, 1);
        uint2 o;
        o.x = (unsigned int)f2bf(a0 * inv) | ((unsigned int)f2bf(a1 * inv) << 16);
        o.y = (unsigned int)f2bf(a2 * inv) | ((unsigned int)f2bf(a3 * inv) << 16);
        *reinterpret_cast<uint2*>(M + (size_t)wid * HID + l32 * 4) = o;
    }
}

// ---------------------------------------------------------------------------
// Fused CSR mean-aggregation, 64-col rows (pre-transformed Z). 128 B/edge.
// ---------------------------------------------------------------------------
__global__ __launch_bounds__(256) void agg3_64(
    const int* __restrict__ o0, const int* __restrict__ c0,
    const unsigned short* __restrict__ X0, unsigned short* __restrict__ M0, int n0,
    const int* __restrict__ o1, const int* __restrict__ c1,
    const unsigned short* __restrict__ X1, unsigned short* __restrict__ M1, int n1,
    const int* __restrict__ o2, const int* __restrict__ c2,
    const unsigned short* __restrict__ X2, unsigned short* __restrict__ M2, int n2)
{
    int wid = (blockIdx.x * blockDim.x + threadIdx.x) >> 6;
    const int lane = threadIdx.x & 63;
    const int half = lane >> 5;
    const int l32 = lane & 31;

    const int* offs; const int* col;
    const unsigned short* X; unsigned short* M;
    if (wid < n0) { offs = o0; col = c0; X = X0; M = M0; }
    else if (wid < n0 + n1) { wid -= n0; offs = o1; col = c1; X = X1; M = M1; }
    else { wid -= n0 + n1; if (wid >= n2) return; offs = o2; col = c2; X = X2; M = M2; }

    const int start = offs[wid];
    const int end = offs[wid + 1];
    const unsigned short* Xl = X + l32 * 2;

    float a0 = 0.f, a1 = 0.f, b0 = 0.f, b1 = 0.f;
    int e = start;
    for (; e + 3 < end; e += 4) {
        int sA = col[e + 2 * half];
        int sB = col[e + 2 * half + 1];
        unsigned vA = *reinterpret_cast<const unsigned*>(Xl + (size_t)sA * OUTD);
        unsigned vB = *reinterpret_cast<const unsigned*>(Xl + (size_t)sB * OUTD);
        a0 += bf2f((unsigned short)(vA & 0xffffu));
        a1 += bf2f((unsigned short)(vA >> 16));
        b0 += bf2f((unsigned short)(vB & 0xffffu));
        b1 += bf2f((unsigned short)(vB >> 16));
    }
    if (e + 1 < end) {
        int sA = col[e + half];
        unsigned vA = *reinterpret_cast<const unsigned*>(Xl + (size_t)sA * OUTD);
        a0 += bf2f((unsigned short)(vA & 0xffffu));
        a1 += bf2f((unsigned short)(vA >> 16));
        e += 2;
    }
    if (e < end && half == 0) {
        int sA = col[e];
        unsigned vA = *reinterpret_cast<const unsigned*>(Xl + (size_t)sA * OUTD);
        a0 += bf2f((unsigned short)(vA & 0xffffu));
        a1 += bf2f((unsigned short)(vA >> 16));
    }
    a0 += b0; a1 += b1;
    a0 += __shfl_xor(a0, 32, 64);
    a1 += __shfl_xor(a1, 32, 64);

    if (half == 0) {
        float inv = 1.0f / (float)max(end - start, 1);
        unsigned o = (unsigned)f2bf(a0 * inv) | ((unsigned)f2bf(a1 * inv) << 16);
        *reinterpret_cast<unsigned*>(M + (size_t)wid * OUTD + l32 * 2) = o;
    }
}

// ---------------------------------------------------------------------------
// Fused transform: Z = H @ Wl (first half of Wt), CO=64, K=128. 3 sections.
// ---------------------------------------------------------------------------
__global__ __launch_bounds__(256) void xform3(
    const unsigned short* __restrict__ H0, const unsigned short* __restrict__ W0,
    unsigned short* __restrict__ Z0, int n0,
    const unsigned short* __restrict__ H1, const unsigned short* __restrict__ W1,
    unsigned short* __restrict__ Z1, int n1,
    const unsigned short* __restrict__ H2, const unsigned short* __restrict__ W2,
    unsigned short* __restrict__ Z2, int n2)
{
    const int b0 = (n0 + 63) / 64, b1 = (n1 + 63) / 64;
    int b = blockIdx.x;
    const unsigned short *H, *W; unsigned short* Z; int n;
    if (b < b0) { H = H0; W = W0; Z = Z0; n = n0; }
    else if (b < b0 + b1) { b -= b0; H = H1; W = W1; Z = Z1; n = n1; }
    else { b -= b0 + b1; H = H2; W = W2; Z = Z2; n = n2; }

    constexpr int NT = OUTD / 16;   // 4
    const int wave = threadIdx.x >> 6;
    const int lane = threadIdx.x & 63;
    const int r16 = lane & 15;
    const int chunk = lane >> 4;
    const int rowbase = b * 64 + wave * 16;
    if (rowbase >= n) return;

    const int arow = min(rowbase + r16, n - 1);
    const unsigned short* hrow = H + (size_t)arow * HID;

    bf16x8 a[4];
#pragma unroll
    for (int s = 0; s < 4; ++s)
        a[s] = *reinterpret_cast<const bf16x8*>(hrow + s * 32 + chunk * 8);

    f32x4 acc[NT];
#pragma unroll
    for (int t = 0; t < NT; ++t) acc[t] = f32x4{0.f, 0.f, 0.f, 0.f};

#pragma unroll
    for (int t = 0; t < NT; ++t) {
        const unsigned short* w_ = W + (size_t)(t * 16 + r16) * 256;   // Wl half
#pragma unroll
        for (int s = 0; s < 4; ++s) {
            bf16x8 bfrag = *reinterpret_cast<const bf16x8*>(w_ + s * 32 + chunk * 8);
            acc[t] = __builtin_amdgcn_mfma_f32_16x16x32_bf16(a[s], bfrag, acc[t], 0, 0, 0);
        }
    }

#pragma unroll
    for (int r = 0; r < 4; ++r) {
        int node = rowbase + chunk * 4 + r;
        if (node < n) {
#pragma unroll
            for (int t = 0; t < NT; ++t)
                Z[(size_t)node * OUTD + t * 16 + r16] = f2bf(acc[t][r]);
        }
    }
}

// ---------------------------------------------------------------------------
// Layer-0 SAGE kernels (K=256 over [mean|x]).
// C/D layout: col = lane&15, row = (lane>>4)*4 + reg   [verified m89]
// ---------------------------------------------------------------------------
template <int CO>
__global__ __launch_bounds__(256) void sage_mfma(
    const unsigned short* __restrict__ Mb,
    const unsigned short* __restrict__ Xb,
    const unsigned short* __restrict__ Wt,
    const float* __restrict__ bl,
    float* __restrict__ H, int n)
{
    constexpr int NT = CO / 16;
    const int wave = threadIdx.x >> 6;
    const int lane = threadIdx.x & 63;
    const int r16 = lane & 15;
    const int chunk = lane >> 4;
    const int rowbase = blockIdx.x * 64 + wave * 16;
    if (rowbase >= n) return;

    const int arow = min(rowbase + r16, n - 1);
    const unsigned short* mrow = Mb + (size_t)arow * HID;
    const unsigned short* xrow = Xb + (size_t)arow * HID;

    bf16x8 a[8];
#pragma unroll
    for (int s = 0; s < 4; ++s) {
        a[s]     = *reinterpret_cast<const bf16x8*>(mrow + s * 32 + chunk * 8);
        a[4 + s] = *reinterpret_cast<const bf16x8*>(xrow + s * 32 + chunk * 8);
    }

    f32x4 acc[NT];
#pragma unroll
    for (int t = 0; t < NT; ++t) acc[t] = f32x4{0.f, 0.f, 0.f, 0.f};

#pragma unroll
    for (int t = 0; t < NT; ++t) {
        const unsigned short* wr_ = Wt + (size_t)(t * 16 + r16) * 256;
#pragma unroll
        for (int s = 0; s < 8; ++s) {
            bf16x8 b = *reinterpret_cast<const bf16x8*>(wr_ + s * 32 + chunk * 8);
            acc[t] = __builtin_amdgcn_mfma_f32_16x16x32_bf16(a[s], b, acc[t], 0, 0, 0);
        }
    }

    float ss[4] = {0.f, 0.f, 0.f, 0.f};
#pragma unroll
    for (int t = 0; t < NT; ++t) {
        float bias = bl[t * 16 + r16];
#pragma unroll
        for (int r = 0; r < 4; ++r) {
            acc[t][r] += bias;
            ss[r] += acc[t][r] * acc[t][r];
        }
    }
#pragma unroll
    for (int r = 0; r < 4; ++r)
#pragma unroll
        for (int m = 1; m < 16; m <<= 1)
            ss[r] += __shfl_xor(ss[r], m, 64);

#pragma unroll
    for (int r = 0; r < 4; ++r) {
        int node = rowbase + chunk * 4 + r;
        if (node < n) {
            float inv = 1.0f / fmaxf(sqrtf(ss[r]), 1e-12f);
#pragma unroll
            for (int t = 0; t < NT; ++t)
                H[(size_t)node * CO + t * 16 + r16] = acc[t][r] * inv;
        }
    }
}

template <int CO>
__global__ __launch_bounds__(256) void sage2_mfma(
    const unsigned short* __restrict__ MbA,
    const unsigned short* __restrict__ MbB,
    const unsigned short* __restrict__ Xb,
    const unsigned short* __restrict__ WtA,
    const unsigned short* __restrict__ WtB,
    const float* __restrict__ blA, const float* __restrict__ blB,
    float* __restrict__ H, int n)
{
    constexpr int NT = CO / 16;
    const int wave = threadIdx.x >> 6;
    const int lane = threadIdx.x & 63;
    const int r16 = lane & 15;
    const int chunk = lane >> 4;
    const int rowbase = blockIdx.x * 64 + wave * 16;
    if (rowbase >= n) return;

    const int arow = min(rowbase + r16, n - 1);
    const unsigned short* marow = MbA + (size_t)arow * HID;
    const unsigned short* mbrow = MbB + (size_t)arow * HID;
    const unsigned short* xrow  = Xb  + (size_t)arow * HID;

    bf16x8 aA[4], aB[4], ax[4];
#pragma unroll
    for (int s = 0; s < 4; ++s) {
        aA[s] = *reinterpret_cast<const bf16x8*>(marow + s * 32 + chunk * 8);
        aB[s] = *reinterpret_cast<const bf16x8*>(mbrow + s * 32 + chunk * 8);
        ax[s] = *reinterpret_cast<const bf16x8*>(xrow  + s * 32 + chunk * 8);
    }

    f32x4 accA[NT], accB[NT];
#pragma unroll
    for (int t = 0; t < NT; ++t) {
        accA[t] = f32x4{0.f, 0.f, 0.f, 0.f};
        accB[t] = f32x4{0.f, 0.f, 0.f, 0.f};
    }

#pragma unroll
    for (int t = 0; t < NT; ++t) {
        const unsigned short* wA = WtA + (size_t)(t * 16 + r16) * 256;
        const unsigned short* wB = WtB + (size_t)(t * 16 + r16) * 256;
#pragma unroll
        for (int s = 0; s < 4; ++s) {
            bf16x8 b0 = *reinterpret_cast<const bf16x8*>(wA + s * 32 + chunk * 8);
            accA[t] = __builtin_amdgcn_mfma_f32_16x16x32_bf16(aA[s], b0, accA[t], 0, 0, 0);
            bf16x8 b1 = *reinterpret_cast<const bf16x8*>(wA + HID + s * 32 + chunk * 8);
            accA[t] = __builtin_amdgcn_mfma_f32_16x16x32_bf16(ax[s], b1, accA[t], 0, 0, 0);
            bf16x8 b2 = *reinterpret_cast<const bf16x8*>(wB + s * 32 + chunk * 8);
            accB[t] = __builtin_amdgcn_mfma_f32_16x16x32_bf16(aB[s], b2, accB[t], 0, 0, 0);
            bf16x8 b3 = *reinterpret_cast<const bf16x8*>(wB + HID + s * 32 + chunk * 8);
            accB[t] = __builtin_amdgcn_mfma_f32_16x16x32_bf16(ax[s], b3, accB[t], 0, 0, 0);
        }
    }

    float ssA[4] = {0.f, 0.f, 0.f, 0.f};
    float ssB[4] = {0.f, 0.f, 0.f, 0.f};
#pragma unroll
    for (int t = 0; t < NT; ++t) {
        float biasA = blA[t * 16 + r16];
        float biasB = blB[t * 16 + r16];
#pragma unroll
        for (int r = 0; r < 4; ++r) {
            accA[t][r] += biasA;
            ssA[r] += accA[t][r] * accA[t][r];
            accB[t][r] += biasB;
            ssB[r] += accB[t][r] * accB[t][r];
        }
    }
#pragma unroll
    for (int r = 0; r < 4; ++r)
#pragma unroll
        for (int m = 1; m < 16; m <<= 1) {
            ssA[r] += __shfl_xor(ssA[r], m, 64);
            ssB[r] += __shfl_xor(ssB[r], m, 64);
        }

#pragma unroll
    for (int r = 0; r < 4; ++r) {
        int node = rowbase + chunk * 4 + r;
        if (node < n) {
            float invA = 1.0f / fmaxf(sqrtf(ssA[r]), 1e-12f);
            float invB = 1.0f / fmaxf(sqrtf(ssB[r]), 1e-12f);
#pragma unroll
            for (int t = 0; t < NT; ++t)
                H[(size_t)node * CO + t * 16 + r16] =
                    accA[t][r] * invA + accB[t][r] * invB;
        }
    }
}

// ---------------------------------------------------------------------------
// Layer-1 SAGE with pre-aggregated meanZ (= mean@Wl): only x@Wr via MFMA.
// ---------------------------------------------------------------------------
__global__ __launch_bounds__(256) void sage2z(
    const unsigned short* __restrict__ MZa,   // [n][64]
    const unsigned short* __restrict__ MZb,   // [n][64]
    const unsigned short* __restrict__ Xb,    // [n][128]
    const unsigned short* __restrict__ WtA,   // [64][256] (Wr at +HID)
    const unsigned short* __restrict__ WtB,
    const float* __restrict__ blA, const float* __restrict__ blB,
    float* __restrict__ H, int n)
{
    constexpr int NT = OUTD / 16;
    const int wave = threadIdx.x >> 6;
    const int lane = threadIdx.x & 63;
    const int r16 = lane & 15;
    const int chunk = lane >> 4;
    const int rowbase = blockIdx.x * 64 + wave * 16;
    if (rowbase >= n) return;

    const int arow = min(rowbase + r16, n - 1);
    const unsigned short* xrow = Xb + (size_t)arow * HID;

    bf16x8 ax[4];
#pragma unroll
    for (int s = 0; s < 4; ++s)
        ax[s] = *reinterpret_cast<const bf16x8*>(xrow + s * 32 + chunk * 8);

    f32x4 accA[NT], accB[NT];
#pragma unroll
    for (int t = 0; t < NT; ++t) {
        accA[t] = f32x4{0.f, 0.f, 0.f, 0.f};
        accB[t] = f32x4{0.f, 0.f, 0.f, 0.f};
    }

#pragma unroll
    for (int t = 0; t < NT; ++t) {
        const unsigned short* wA = WtA + (size_t)(t * 16 + r16) * 256 + HID;
        const unsigned short* wB = WtB + (size_t)(t * 16 + r16) * 256 + HID;
#pragma unroll
        for (int s = 0; s < 4; ++s) {
            bf16x8 b0 = *reinterpret_cast<const bf16x8*>(wA + s * 32 + chunk * 8);
            accA[t] = __builtin_amdgcn_mfma_f32_16x16x32_bf16(ax[s], b0, accA[t], 0, 0, 0);
            bf16x8 b1 = *reinterpret_cast<const bf16x8*>(wB + s * 32 + chunk * 8);
            accB[t] = __builtin_amdgcn_mfma_f32_16x16x32_bf16(ax[s], b1, accB[t], 0, 0, 0);
        }
    }

    float ssA[4] = {0.f, 0.f, 0.f, 0.f};
    float ssB[4] = {0.f, 0.f, 0.f, 0.f};
#pragma unroll
    for (int r = 0; r < 4; ++r) {
        int cl = min(rowbase + chunk * 4 + r, n - 1);
#pragma unroll
        for (int t = 0; t < NT; ++t) {
            int j = t * 16 + r16;
            float vA = accA[t][r] + blA[j] + bf2f(MZa[(size_t)cl * OUTD + j]);
            accA[t][r] = vA;
            ssA[r] += vA * vA;
            float vB = accB[t][r] + blB[j] + bf2f(MZb[(size_t)cl * OUTD + j]);
            accB[t][r] = vB;
            ssB[r] += vB * vB;
        }
    }
#pragma unroll
    for (int r = 0; r < 4; ++r)
#pragma unroll
        for (int m = 1; m < 16; m <<= 1) {
            ssA[r] += __shfl_xor(ssA[r], m, 64);
            ssB[r] += __shfl_xor(ssB[r], m, 64);
        }

#pragma unroll
    for (int r = 0; r < 4; ++r) {
        int node = rowbase + chunk * 4 + r;
        if (node < n) {
            float invA = 1.0f / fmaxf(sqrtf(ssA[r]), 1e-12f);
            float invB = 1.0f / fmaxf(sqrtf(ssB[r]), 1e-12f);
#pragma unroll
            for (int t = 0; t < NT; ++t)
                H[(size_t)node * OUTD + t * 16 + r16] =
                    accA[t][r] * invA + accB[t][r] * invB;
        }
    }
}

__global__ __launch_bounds__(256) void sagez(
    const unsigned short* __restrict__ MZ,    // [n][64]
    const unsigned short* __restrict__ Xb,    // [n][128]
    const unsigned short* __restrict__ Wt,    // [64][256] (Wr at +HID)
    const float* __restrict__ bl,
    float* __restrict__ H, int n)
{
    constexpr int NT = OUTD / 16;
    const int wave = threadIdx.x >> 6;
    const int lane = threadIdx.x & 63;
    const int r16 = lane & 15;
    const int chunk = lane >> 4;
    const int rowbase = blockIdx.x * 64 + wave * 16;
    if (rowbase >= n) return;

    const int arow = min(rowbase + r16, n - 1);
    const unsigned short* xrow = Xb + (size_t)arow * HID;

    bf16x8 ax[4];
#pragma unroll
    for (int s = 0; s < 4; ++s)
        ax[s] = *reinterpret_cast<const bf16x8*>(xrow + s * 32 + chunk * 8);

    f32x4 acc[NT];
#pragma unroll
    for (int t = 0; t < NT; ++t) acc[t] = f32x4{0.f, 0.f, 0.f, 0.f};

#pragma unroll
    for (int t = 0; t < NT; ++t) {
        const unsigned short* w_ = Wt + (size_t)(t * 16 + r16) * 256 + HID;
#pragma unroll
        for (int s = 0; s < 4; ++s) {
            bf16x8 b = *reinterpret_cast<const bf16x8*>(w_ + s * 32 + chunk * 8);
            acc[t] = __builtin_amdgcn_mfma_f32_16x16x32_bf16(ax[s], b, acc[t], 0, 0, 0);
        }
    }

    float ss[4] = {0.f, 0.f, 0.f, 0.f};
#pragma unroll
    for (int r = 0; r < 4; ++r) {
        int cl = min(rowbase + chunk * 4 + r, n - 1);
#pragma unroll
        for (int t = 0; t < NT; ++t) {
            int j = t * 16 + r16;
            float v = acc[t][r] + bl[j] + bf2f(MZ[(size_t)cl * OUTD + j]);
            acc[t][r] = v;
            ss[r] += v * v;
        }
    }
#pragma unroll
    for (int r = 0; r < 4; ++r)
#pragma unroll
        for (int m = 1; m < 16; m <<= 1)
            ss[r] += __shfl_xor(ss[r], m, 64);

#pragma unroll
    for (int r = 0; r < 4; ++r) {
        int node = rowbase + chunk * 4 + r;
        if (node < n) {
            float inv = 1.0f / fmaxf(sqrtf(ss[r]), 1e-12f);
#pragma unroll
            for (int t = 0; t < NT; ++t)
                H[(size_t)node * OUTD + t * 16 + r16] = acc[t][r] * inv;
        }
    }
}

// ---------------------------------------------------------------------------
// LayerNorm (+optional ReLU), one wave per row; fp32 in; bf16 or fp32 out.
// ---------------------------------------------------------------------------
template <int D, bool RELU, bool OUTBF>
__global__ __launch_bounds__(256) void ln_kernel(
    const float* __restrict__ X, const float* __restrict__ gg,
    const float* __restrict__ bb, void* __restrict__ outp, int n)
{
    constexpr int VPL = D / 64;
    int wid = (blockIdx.x * blockDim.x + threadIdx.x) >> 6;
    int lane = threadIdx.x & 63;
    if (wid >= n) return;

    float v[VPL], gv[VPL], bv[VPL];
    const float* xp = X + (size_t)wid * D + lane * VPL;
#pragma unroll
    for (int k = 0; k < VPL; ++k) {
        v[k] = xp[k];
        gv[k] = gg[lane * VPL + k];
        bv[k] = bb[lane * VPL + k];
    }
    float s = 0.f;
#pragma unroll
    for (int k = 0; k < VPL; ++k) s += v[k];
#pragma unroll
    for (int off = 32; off > 0; off >>= 1) s += __shfl_xor(s, off, 64);
    float m = s / D;
    float ss = 0.f;
#pragma unroll
    for (int k = 0; k < VPL; ++k) { float d = v[k] - m; ss += d * d; }
#pragma unroll
    for (int off = 32; off > 0; off >>= 1) ss += __shfl_xor(ss, off, 64);
    float rstd = rsqrtf(ss / D + 1e-5f);

    float y[VPL];
#pragma unroll
    for (int k = 0; k < VPL; ++k) {
        y[k] = gv[k] * (v[k] - m) * rstd + bv[k];
        if (RELU) y[k] = fmaxf(y[k], 0.f);
    }
    if (OUTBF) {
        unsigned short* op = (unsigned short*)outp + (size_t)wid * D + lane * VPL;
#pragma unroll
        for (int k = 0; k < VPL; ++k) op[k] = f2bf(y[k]);
    } else {
        float* op = (float*)outp + (size_t)wid * D + lane * VPL;
#pragma unroll
        for (int k = 0; k < VPL; ++k) op[k] = y[k];
    }
}

// ---------------------------------------------------------------------------
extern "C" void kernel_launch(void* const* d_in, const int* in_sizes, int n_in,
                              void* d_out, int out_size, void* d_ws, size_t ws_size,
                              hipStream_t stream)
{
    const int*   x_drug   = (const int*)d_in[0];
    const int*   x_dis    = (const int*)d_in[1];
    const float* emb_drug = (const float*)d_in[2];
    const float* emb_dis  = (const float*)d_in[3];
    const int*   src_dd   = (const int*)d_in[4];
    const int*   dst_dd   = (const int*)d_in[5];
    const int*   src_td   = (const int*)d_in[6];
    const int*   dst_td   = (const int*)d_in[7];
    const int*   src_rd   = (const int*)d_in[8];
    const int*   dst_rd   = (const int*)d_in[9];
    const float* Wl0_dd = (const float*)d_in[10];
    const float* bl0_dd = (const float*)d_in[11];
    const float* Wr0_dd = (const float*)d_in[12];
    const float* Wl0_td = (const float*)d_in[13];
    const float* bl0_td = (const float*)d_in[14];
    const float* Wr0_td = (const float*)d_in[15];
    const float* Wl0_rd = (const float*)d_in[16];
    const float* bl0_rd = (const float*)d_in[17];
    const float* Wr0_rd = (const float*)d_in[18];
    const float* Wl1_dd = (const float*)d_in[19];
    const float* bl1_dd = (const float*)d_in[20];
    const float* Wr1_dd = (const float*)d_in[21];
    const float* Wl1_td = (const float*)d_in[22];
    const float* bl1_td = (const float*)d_in[23];
    const float* Wr1_td = (const float*)d_in[24];
    const float* Wl1_rd = (const float*)d_in[25];
    const float* bl1_rd = (const float*)d_in[26];
    const float* Wr1_rd = (const float*)d_in[27];
    const float* g0_drug = (const float*)d_in[28];
    const float* b0_drug = (const float*)d_in[29];
    const float* g0_dis  = (const float*)d_in[30];
    const float* b0_dis  = (const float*)d_in[31];
    const float* g1_drug = (const float*)d_in[32];
    const float* b1_drug = (const float*)d_in[33];
    const float* g1_dis  = (const float*)d_in[34];
    const float* b1_dis  = (const float*)d_in[35];

    // ---------------- workspace layout ----------------
    char* wp = (char*)d_ws;
    auto alloc = [&](size_t bytes) { char* p = wp; wp += (bytes + 255) & ~size_t(255); return p; };

    unsigned short* hd0  = (unsigned short*)alloc((size_t)ND * HID * 2);
    unsigned short* hz0  = (unsigned short*)alloc((size_t)NZ * HID * 2);
    unsigned short* hd1b = (unsigned short*)alloc((size_t)ND * HID * 2);
    unsigned short* hz1b = (unsigned short*)alloc((size_t)NZ * HID * 2);
    unsigned short* meanA= (unsigned short*)alloc((size_t)ND * HID * 2);
    unsigned short* meanB= (unsigned short*)alloc((size_t)ND * HID * 2);
    unsigned short* meanC= (unsigned short*)alloc((size_t)NZ * HID * 2);
    unsigned short* Zdd  = (unsigned short*)alloc((size_t)ND * OUTD * 2);
    unsigned short* Zrd  = (unsigned short*)alloc((size_t)NZ * OUTD * 2);
    unsigned short* Ztd  = (unsigned short*)alloc((size_t)ND * OUTD * 2);
    float* hd1f = (float*)alloc((size_t)ND * HID * 4);
    float* hz1f = (float*)alloc((size_t)NZ * HID * 4);
    unsigned short* Wt0_dd = (unsigned short*)alloc((size_t)HID * 256 * 2);
    unsigned short* Wt0_rd = (unsigned short*)alloc((size_t)HID * 256 * 2);
    unsigned short* Wt0_td = (unsigned short*)alloc((size_t)HID * 256 * 2);
    unsigned short* Wt1_dd = (unsigned short*)alloc((size_t)OUTD * 256 * 2);
    unsigned short* Wt1_rd = (unsigned short*)alloc((size_t)OUTD * 256 * 2);
    unsigned short* Wt1_td = (unsigned short*)alloc((size_t)OUTD * 256 * 2);
    int* offs_dd = (int*)alloc((ND + 1) * 4);
    int* offs_rd = (int*)alloc((ND + 1) * 4);
    int* offs_td = (int*)alloc((NZ + 1) * 4);
    int* col_dd  = (int*)alloc((size_t)E * 4);
    int* col_rd  = (int*)alloc((size_t)E * 4);
    int* col_td  = (int*)alloc((size_t)E * 4);
    // contiguous count region (one memset covers all three)
    int* cnt_dd  = (int*)alloc(((size_t)(ND + 1) + (ND + 1) + (NZ + 1)) * 4);
    int* cnt_rd  = cnt_dd + (ND + 1);
    int* cnt_td  = cnt_rd + (ND + 1);
    int* cur_dd  = (int*)alloc((ND + 1) * 4);
    int* cur_rd  = (int*)alloc((ND + 1) * 4);
    int* cur_td  = (int*)alloc((NZ + 1) * 4);
    int* part    = (int*)alloc(3 * 64 * 4);
    int* rc      = (int*)alloc(3 * CHK * 8 * 4);
    int* wpos    = (int*)alloc(3 * CHK * 8 * 4);
    int* rbase   = (int*)alloc(3 * 9 * 4);

    // Buckets alias hd1f/hz1f (disjoint lifetime: buckets die before layer-0
    // sage writes hd1f/hz1f).  bkt_dd+bkt_rd = 16 MB <= hd1f 25.6 MB;
    // bkt_td = 8 MB <= hz1f 10.2 MB.
    int2* bkt_dd = (int2*)hd1f;
    int2* bkt_rd = bkt_dd + E;
    int2* bkt_td = (int2*)hz1f;

    float* outD = (float*)d_out;
    float* outZ = outD + (size_t)ND * OUTD;

    // ---------------- independent prep ----------------
    hipMemsetAsync(cnt_dd, 0, ((size_t)(ND + 1) + (ND + 1) + (NZ + 1)) * 4, stream);

    gather_all<<<ceil_div((ND + NZ) * 32, 256), 256, 0, stream>>>(
        emb_drug, x_drug, emb_dis, x_dis, hd0, hz0);

    PrepArgs pa;
    pa.wl[0] = Wl0_dd; pa.wr[0] = Wr0_dd; pa.wt[0] = Wt0_dd; pa.co[0] = HID;
    pa.wl[1] = Wl0_rd; pa.wr[1] = Wr0_rd; pa.wt[1] = Wt0_rd; pa.co[1] = HID;
    pa.wl[2] = Wl0_td; pa.wr[2] = Wr0_td; pa.wt[2] = Wt0_td; pa.co[2] = HID;
    pa.wl[3] = Wl1_dd; pa.wr[3] = Wr1_dd; pa.wt[3] = Wt1_dd; pa.co[3] = OUTD;
    pa.wl[4] = Wl1_rd; pa.wr[4] = Wr1_rd; pa.wt[4] = Wt1_rd; pa.co[4] = OUTD;
    pa.wl[5] = Wl1_td; pa.wr[5] = Wr1_td; pa.wt[5] = Wt1_td; pa.co[5] = OUTD;
    pa.boff[0] = 0;
    for (int s = 0; s < 6; ++s) pa.boff[s + 1] = pa.boff[s] + pa.co[s];
    prep_all<<<pa.boff[6], 256, 0, stream>>>(pa);

    // ---------------- bucketed CSR build ----------------
    bcount<<<3 * CHK, 256, 0, stream>>>(dst_dd, dst_rd, dst_td, rc);
    bscan<<<1, 256, 0, stream>>>(rc, wpos, rbase);
    bscatter<<<3 * CHK, 256, 0, stream>>>(
        src_dd, dst_dd, src_rd, dst_rd, src_td, dst_td,
        wpos, bkt_dd, bkt_rd, bkt_td);
    bhist<<<NXCD * 3 * HB2, 256, 0, stream>>>(
        bkt_dd, bkt_rd, bkt_td, rbase, cnt_dd, cnt_rd, cnt_td);
    scan_part3<<<2 * NB_D + NB_Z, 256, 0, stream>>>(cnt_dd, cnt_rd, cnt_td, part);
    scan_small3<<<3, 64, 0, stream>>>(part, offs_dd, offs_rd, offs_td);
    scan_write3<<<2 * NB_D + NB_Z, 256, 0, stream>>>(
        cnt_dd, cnt_rd, cnt_td, part, offs_dd, offs_rd, offs_td, cur_dd, cur_rd, cur_td);
    bfill<<<NXCD * 3 * HB2, 256, 0, stream>>>(
        bkt_dd, bkt_rd, bkt_td, rbase, cur_dd, cur_rd, cur_td, col_dd, col_rd, col_td);

    // ---------------- layer 0 ----------------
    agg3_128<<<ceil_div((2 * ND + NZ) * 64, 256), 256, 0, stream>>>(
        offs_dd, col_dd, hd0, meanA, ND,
        offs_rd, col_rd, hz0, meanB, ND,
        offs_td, col_td, hd0, meanC, NZ);
    sage2_mfma<HID><<<ceil_div(ND, 64), 256, 0, stream>>>(
        meanA, meanB, hd0, Wt0_dd, Wt0_rd, bl0_dd, bl0_rd, hd1f, ND);
    sage_mfma<HID><<<ceil_div(NZ, 64), 256, 0, stream>>>(
        meanC, hz0, Wt0_td, bl0_td, hz1f, NZ);

    ln_kernel<HID, true, true><<<ceil_div(ND, 4), 256, 0, stream>>>(hd1f, g0_drug, b0_drug, hd1b, ND);
    ln_kernel<HID, true, true><<<ceil_div(NZ, 4), 256, 0, stream>>>(hz1f, g0_dis, b0_dis, hz1b, NZ);

    // ---------------- layer 1 (transform-then-aggregate) ----------------
    xform3<<<ceil_div(ND, 64) * 2 + ceil_div(NZ, 64), 256, 0, stream>>>(
        hd1b, Wt1_dd, Zdd, ND,
        hz1b, Wt1_rd, Zrd, NZ,
        hd1b, Wt1_td, Ztd, ND);

    agg3_64<<<ceil_div((2 * ND + NZ) * 64, 256), 256, 0, stream>>>(
        offs_dd, col_dd, Zdd, meanA, ND,
        offs_rd, col_rd, Zrd, meanB, ND,
        offs_td, col_td, Ztd, meanC, NZ);

    sage2z<<<ceil_div(ND, 64), 256, 0, stream>>>(
        meanA, meanB, hd1b, Wt1_dd, Wt1_rd, bl1_dd, bl1_rd, outD, ND);
    sagez<<<ceil_div(NZ, 64), 256, 0, stream>>>(
        meanC, hz1b, Wt1_td, bl1_td, outZ, NZ);

    ln_kernel<OUTD, false, false><<<ceil_div(ND, 4), 256, 0, stream>>>(outD, g1_drug, b1_drug, outD, ND);
    ln_kernel<OUTD, false, false><<<ceil_div(NZ, 4), 256, 0, stream>>>(outZ, g1_dis, b1_dis, outZ, NZ);
}

// Round 12
// 485.891 us; speedup vs baseline: 2.1959x; 1.3706x over previous
//
#include <hip/hip_runtime.h>

// Problem constants (match reference setup_inputs)
constexpr int ND   = 50000;
constexpr int NZ   = 20000;
constexpr int HID  = 128;
constexpr int OUTD = 64;
constexpr int E    = 1000000;

constexpr int SCAN_TILE = 1024;
constexpr int NB_D = (ND + SCAN_TILE - 1) / SCAN_TILE;   // 49
constexpr int NB_Z = (NZ + SCAN_TILE - 1) / SCAN_TILE;   // 20
constexpr int NXCD = 8;      // XCD count; blockIdx % 8 assumed round-robin -> XCD
constexpr int CHK  = 96;     // edge chunks per list (bucket build)
constexpr int SSUB = 8;      // slices per (list,range) in count/fill
constexpr int RN_D = ND / NXCD;   // 6250 (exact)
constexpr int RN_Z = NZ / NXCD;   // 2500 (exact)
// partial[] bases per list (ints)
constexpr int PB1 = NXCD * SSUB * RN_D;          // 400000
constexpr int PB2 = PB1 + NXCD * SSUB * RN_D;    // 800000
constexpr int PTOT = PB2 + NXCD * SSUB * RN_Z;   // 960000

static inline int ceil_div(int a, int b) { return (a + b - 1) / b; }

typedef __bf16 bf16x8 __attribute__((ext_vector_type(8)));
typedef float  f32x4  __attribute__((ext_vector_type(4)));

__device__ __forceinline__ float bf2f(unsigned short b) {
    return __uint_as_float(((unsigned int)b) << 16);
}
__device__ __forceinline__ unsigned short f2bf(float f) {
    unsigned int u = __float_as_uint(f);
    unsigned int r = (u + 0x7fffu + ((u >> 16) & 1u)) >> 16;
    return (unsigned short)r;
}

// ---------------------------------------------------------------------------
// Fused gather: rows [0,ND) from emb_drug[x_drug], rows [ND,ND+NZ) from emb_dis
// ---------------------------------------------------------------------------
__global__ __launch_bounds__(256) void gather_all(
    const float* __restrict__ emb_d, const int* __restrict__ idx_d,
    const float* __restrict__ emb_z, const int* __restrict__ idx_z,
    unsigned short* __restrict__ out_d, unsigned short* __restrict__ out_z)
{
    int t = blockIdx.x * blockDim.x + threadIdx.x;
    int row = t >> 5;
    int c = (t & 31) * 4;
    if (row >= ND + NZ) return;
    const float* src;
    unsigned short* dst;
    if (row < ND) {
        src = emb_d + (size_t)idx_d[row] * HID;
        dst = out_d + (size_t)row * HID;
    } else {
        int r2 = row - ND;
        src = emb_z + (size_t)idx_z[r2] * HID;
        dst = out_z + (size_t)r2 * HID;
    }
    float4 v = *reinterpret_cast<const float4*>(src + c);
    ushort4 o;
    o.x = f2bf(v.x); o.y = f2bf(v.y); o.z = f2bf(v.z); o.w = f2bf(v.w);
    *reinterpret_cast<ushort4*>(dst + c) = o;
}

// ---------------------------------------------------------------------------
// Fused weight prep: 6 weight pairs -> Wt[j][0:256] = bf16([Wl col j ; Wr col j])
// ---------------------------------------------------------------------------
struct PrepArgs {
    const float* wl[6];
    const float* wr[6];
    unsigned short* wt[6];
    int co[6];
    int boff[7];
};

__global__ __launch_bounds__(256) void prep_all(PrepArgs a)
{
    int sec = 0;
#pragma unroll
    for (int s = 0; s < 6; ++s)
        if ((int)blockIdx.x >= a.boff[s + 1]) sec = s + 1;
    int CO = a.co[sec];
    int idx = (blockIdx.x - a.boff[sec]) * 256 + threadIdx.x;  // CO*256 total
    int j = idx >> 8;
    int k = idx & 255;
    float v = (k < HID) ? a.wl[sec][k * CO + j] : a.wr[sec][(k - HID) * CO + j];
    a.wt[sec][(size_t)j * 256 + k] = f2bf(v);
}

// ---------------------------------------------------------------------------
// Bucketed CSR build, phase 1: per-(list,chunk) range histogram (LDS)
// ---------------------------------------------------------------------------
__global__ __launch_bounds__(256) void bcount(
    const int* __restrict__ d0, const int* __restrict__ d1, const int* __restrict__ d2,
    int* __restrict__ rc)
{
    __shared__ int lc[8];
    const int list = blockIdx.x / CHK;
    const int chunk = blockIdx.x % CHK;
    if (threadIdx.x < 8) lc[threadIdx.x] = 0;
    __syncthreads();
    const int* dst = (list == 0) ? d0 : (list == 1) ? d1 : d2;
    const int rn = (list == 2) ? RN_Z : RN_D;
    const int elo = (int)((long long)chunk * E / CHK);
    const int ehi = (int)((long long)(chunk + 1) * E / CHK);
    for (int e = elo + threadIdx.x; e < ehi; e += 256) {
        int d = dst[e];
        int r = min(d / rn, 7);
        atomicAdd(&lc[r], 1);
    }
    __syncthreads();
    if (threadIdx.x < 8) rc[(list * CHK + chunk) * 8 + threadIdx.x] = lc[threadIdx.x];
}

// ---------------------------------------------------------------------------
// Phase 2: exclusive scan of rc in order (list, range, chunk); per-list reset.
// ---------------------------------------------------------------------------
__global__ __launch_bounds__(256) void bscan(
    const int* __restrict__ rc, int* __restrict__ wpos, int* __restrict__ rbase)
{
    __shared__ int sc[256];
    const int tid = threadIdx.x;
    const int lo = tid * 9;                      // 2304 = 256*9 total
    int v[9];
    int s = 0;
#pragma unroll
    for (int k = 0; k < 9; ++k) {
        int i = lo + k;
        int list = i / (8 * CHK), rem = i % (8 * CHK);
        int r = rem / CHK, c = rem % CHK;
        v[k] = rc[(list * CHK + c) * 8 + r];
        s += v[k];
    }
    sc[tid] = s;
    __syncthreads();
    for (int off = 1; off < 256; off <<= 1) {
        int t = (tid >= off) ? sc[tid - off] : 0;
        __syncthreads();
        sc[tid] += t;
        __syncthreads();
    }
    int run = tid ? sc[tid - 1] : 0;
#pragma unroll
    for (int k = 0; k < 9; ++k) {
        int i = lo + k;
        int list = i / (8 * CHK), rem = i % (8 * CHK);
        int r = rem / CHK, c = rem % CHK;
        int base = run - list * E;               // per-list reset (each list sums to E)
        wpos[(list * CHK + c) * 8 + r] = base;
        if (c == 0) rbase[list * 9 + r] = base;
        run += v[k];
    }
    if (tid < 3) rbase[tid * 9 + 8] = E;
}

// ---------------------------------------------------------------------------
// Phase 3: scatter edges (d,s) into per-range buckets at pre-scanned positions.
// ---------------------------------------------------------------------------
__global__ __launch_bounds__(256) void bscatter(
    const int* __restrict__ s0, const int* __restrict__ d0,
    const int* __restrict__ s1, const int* __restrict__ d1,
    const int* __restrict__ s2, const int* __restrict__ d2,
    const int* __restrict__ wpos,
    int2* __restrict__ b0, int2* __restrict__ b1, int2* __restrict__ b2)
{
    __shared__ int lc[8];
    const int list = blockIdx.x / CHK;
    const int chunk = blockIdx.x % CHK;
    if (threadIdx.x < 8) lc[threadIdx.x] = wpos[(list * CHK + chunk) * 8 + threadIdx.x];
    __syncthreads();
    const int* src = (list == 0) ? s0 : (list == 1) ? s1 : s2;
    const int* dst = (list == 0) ? d0 : (list == 1) ? d1 : d2;
    int2* bkt = (list == 0) ? b0 : (list == 1) ? b1 : b2;
    const int rn = (list == 2) ? RN_Z : RN_D;
    const int elo = (int)((long long)chunk * E / CHK);
    const int ehi = (int)((long long)(chunk + 1) * E / CHK);
    for (int e = elo + threadIdx.x; e < ehi; e += 256) {
        int d = dst[e];
        int s = src[e];
        int r = min(d / rn, 7);
        int p = atomicAdd(&lc[r], 1);
        bkt[p] = make_int2(d, s);
    }
}

// ---------------------------------------------------------------------------
// Phase 4: exact per-(slice,node) counts via LDS histogram. NO global atomics.
// block: range = blockIdx&7, t = blockIdx>>3, list = t%3, sub = t/3.
// partial[pb + (range*SSUB + sub)*rn + local] = count of node in this slice.
// ---------------------------------------------------------------------------
__global__ __launch_bounds__(256) void bcount2(
    const int2* __restrict__ b0, const int2* __restrict__ b1, const int2* __restrict__ b2,
    const int* __restrict__ rbase, int* __restrict__ partial)
{
    __shared__ int lh[RN_D];
    const int range = blockIdx.x & 7;
    const int t = blockIdx.x >> 3;
    const int list = t % 3;
    const int sub = t / 3;
    const int2* bkt = (list == 0) ? b0 : (list == 1) ? b1 : b2;
    const int rn = (list == 2) ? RN_Z : RN_D;
    const int pb = (list == 0) ? 0 : (list == 1) ? PB1 : PB2;
    const int rlo = range * rn;
    for (int i = threadIdx.x; i < rn; i += 256) lh[i] = 0;
    __syncthreads();
    const int s0 = rbase[list * 9 + range];
    const int s1 = rbase[list * 9 + range + 1];
    const int len = s1 - s0;
    const int lo = s0 + (int)((long long)sub * len / SSUB);
    const int hi = s0 + (int)((long long)(sub + 1) * len / SSUB);
    for (int i = lo + threadIdx.x; i < hi; i += 256)
        atomicAdd(&lh[bkt[i].x - rlo], 1);
    __syncthreads();
    int* pout = partial + pb + (range * SSUB + sub) * rn;
    for (int i = threadIdx.x; i < rn; i += 256) pout[i] = lh[i];
}

// ---------------------------------------------------------------------------
// cnt[node] = sum over slices of partial
// ---------------------------------------------------------------------------
__global__ __launch_bounds__(256) void sumcnt(
    const int* __restrict__ partial,
    int* __restrict__ c0, int* __restrict__ c1, int* __restrict__ c2)
{
    int idx = blockIdx.x * 256 + threadIdx.x;
    int list, node;
    if (idx < ND) { list = 0; node = idx; }
    else if (idx < 2 * ND) { list = 1; node = idx - ND; }
    else if (idx < 2 * ND + NZ) { list = 2; node = idx - 2 * ND; }
    else return;
    const int rn = (list == 2) ? RN_Z : RN_D;
    const int pb = (list == 0) ? 0 : (list == 1) ? PB1 : PB2;
    int r = node / rn, local = node % rn;
    const int* p = partial + pb + r * SSUB * rn + local;
    int s = 0;
#pragma unroll
    for (int k = 0; k < SSUB; ++k) s += p[(size_t)k * rn];
    int* cnt = (list == 0) ? c0 : (list == 1) ? c1 : c2;
    cnt[node] = s;
}

// ---------------------------------------------------------------------------
// Fused 3-phase scan over the 3 count arrays (unchanged)
// ---------------------------------------------------------------------------
__device__ __forceinline__ void scan_map(int b, int& which, int& tile) {
    if (b < NB_D) { which = 0; tile = b; }
    else if (b < 2 * NB_D) { which = 1; tile = b - NB_D; }
    else { which = 2; tile = b - 2 * NB_D; }
}

__global__ __launch_bounds__(256) void scan_part3(
    const int* __restrict__ c0, const int* __restrict__ c1, const int* __restrict__ c2,
    int* __restrict__ part)
{
    __shared__ int red[256];
    int which, tile;
    scan_map(blockIdx.x, which, tile);
    const int* cnt = (which == 0) ? c0 : (which == 1) ? c1 : c2;
    int n = (which == 2) ? NZ : ND;
    int base = tile * SCAN_TILE;
    int s = 0;
    for (int i = threadIdx.x; i < SCAN_TILE; i += 256) {
        int idx = base + i;
        if (idx < n) s += cnt[idx];
    }
    red[threadIdx.x] = s;
    __syncthreads();
#pragma unroll
    for (int off = 128; off > 0; off >>= 1) {
        if (threadIdx.x < off) red[threadIdx.x] += red[threadIdx.x + off];
        __syncthreads();
    }
    if (threadIdx.x == 0) part[which * 64 + tile] = red[0];
}

__global__ __launch_bounds__(64) void scan_small3(
    int* __restrict__ part,
    int* __restrict__ o0, int* __restrict__ o1, int* __restrict__ o2)
{
    int w = blockIdx.x;
    int np = (w == 2) ? NB_Z : NB_D;
    int n = (w == 2) ? NZ : ND;
    int* offs = (w == 0) ? o0 : (w == 1) ? o1 : o2;
    int* pb = part + w * 64;
    int lane = threadIdx.x;
    int orig = (lane < np) ? pb[lane] : 0;
    int v = orig;
#pragma unroll
    for (int off = 1; off < 64; off <<= 1) {
        int t = __shfl_up(v, off, 64);
        if (lane >= off) v += t;
    }
    if (lane < np) pb[lane] = v - orig;   // exclusive
    if (lane == 63) offs[n] = v;          // total
}

__global__ __launch_bounds__(256) void scan_write3(
    const int* __restrict__ c0, const int* __restrict__ c1, const int* __restrict__ c2,
    const int* __restrict__ part,
    int* __restrict__ o0, int* __restrict__ o1, int* __restrict__ o2)
{
    __shared__ int sc[256];
    int which, tile;
    scan_map(blockIdx.x, which, tile);
    const int* cnt = (which == 0) ? c0 : (which == 1) ? c1 : c2;
    int* offs = (which == 0) ? o0 : (which == 1) ? o1 : o2;
    int n = (which == 2) ? NZ : ND;

    const int tid = threadIdx.x;
    const int tb = tile * SCAN_TILE + tid * 4;
    int v[4];
    int s = 0;
#pragma unroll
    for (int k = 0; k < 4; ++k) {
        v[k] = (tb + k < n) ? cnt[tb + k] : 0;
        s += v[k];
    }
    sc[tid] = s;
    __syncthreads();
#pragma unroll
    for (int off = 1; off < 256; off <<= 1) {
        int t = (tid >= off) ? sc[tid - off] : 0;
        __syncthreads();
        sc[tid] += t;
        __syncthreads();
    }
    int ex = part[which * 64 + tile] + (tid ? sc[tid - 1] : 0);
#pragma unroll
    for (int k = 0; k < 4; ++k) {
        if (tb + k < n) {
            offs[tb + k] = ex;
            ex += v[k];
        }
    }
}

// ---------------------------------------------------------------------------
// Convert partial counts -> per-slice write bases (in place):
//   bases[sub][node] = offs[node] + sum_{sub'<sub} partial[sub'][node]
// ---------------------------------------------------------------------------
__global__ __launch_bounds__(256) void basek(
    int* __restrict__ partial,
    const int* __restrict__ o0, const int* __restrict__ o1, const int* __restrict__ o2)
{
    int idx = blockIdx.x * 256 + threadIdx.x;
    int list, node;
    if (idx < ND) { list = 0; node = idx; }
    else if (idx < 2 * ND) { list = 1; node = idx - ND; }
    else if (idx < 2 * ND + NZ) { list = 2; node = idx - 2 * ND; }
    else return;
    const int rn = (list == 2) ? RN_Z : RN_D;
    const int pb = (list == 0) ? 0 : (list == 1) ? PB1 : PB2;
    const int* offs = (list == 0) ? o0 : (list == 1) ? o1 : o2;
    int r = node / rn, local = node % rn;
    int* p = partial + pb + r * SSUB * rn + local;
    int run = offs[node];
#pragma unroll
    for (int k = 0; k < SSUB; ++k) {
        int* q = p + (size_t)k * rn;
        int t = *q;
        *q = run;
        run += t;
    }
}

// ---------------------------------------------------------------------------
// Phase 5: CSR fill from buckets with LDS cursors. NO global atomics.
// ---------------------------------------------------------------------------
__global__ __launch_bounds__(256) void bfill2(
    const int2* __restrict__ b0, const int2* __restrict__ b1, const int2* __restrict__ b2,
    const int* __restrict__ rbase, const int* __restrict__ partial,
    int* __restrict__ l0, int* __restrict__ l1, int* __restrict__ l2)
{
    __shared__ int lcur[RN_D];
    const int range = blockIdx.x & 7;
    const int t = blockIdx.x >> 3;
    const int list = t % 3;
    const int sub = t / 3;
    const int2* bkt = (list == 0) ? b0 : (list == 1) ? b1 : b2;
    int* col = (list == 0) ? l0 : (list == 1) ? l1 : l2;
    const int rn = (list == 2) ? RN_Z : RN_D;
    const int pb = (list == 0) ? 0 : (list == 1) ? PB1 : PB2;
    const int rlo = range * rn;
    const int* bin = partial + pb + (range * SSUB + sub) * rn;
    for (int i = threadIdx.x; i < rn; i += 256) lcur[i] = bin[i];
    __syncthreads();
    const int s0 = rbase[list * 9 + range];
    const int s1 = rbase[list * 9 + range + 1];
    const int len = s1 - s0;
    const int lo = s0 + (int)((long long)sub * len / SSUB);
    const int hi = s0 + (int)((long long)(sub + 1) * len / SSUB);
    for (int i = lo + threadIdx.x; i < hi; i += 256) {
        int2 e = bkt[i];
        int p = atomicAdd(&lcur[e.x - rlo], 1);
        col[p] = e.y;
    }
}

// ---------------------------------------------------------------------------
// Fused CSR mean-aggregation, 128-col rows; one wave per node, 4-edge unroll.
// ---------------------------------------------------------------------------
__global__ __launch_bounds__(256) void agg3_128(
    const int* __restrict__ o0, const int* __restrict__ c0,
    const unsigned short* __restrict__ X0, unsigned short* __restrict__ M0, int n0,
    const int* __restrict__ o1, const int* __restrict__ c1,
    const unsigned short* __restrict__ X1, unsigned short* __restrict__ M1, int n1,
    const int* __restrict__ o2, const int* __restrict__ c2,
    const unsigned short* __restrict__ X2, unsigned short* __restrict__ M2, int n2)
{
    int wid = (blockIdx.x * blockDim.x + threadIdx.x) >> 6;
    const int lane = threadIdx.x & 63;
    const int half = lane >> 5;
    const int l32 = lane & 31;

    const int* offs; const int* col;
    const unsigned short* X; unsigned short* M;
    if (wid < n0) { offs = o0; col = c0; X = X0; M = M0; }
    else if (wid < n0 + n1) { wid -= n0; offs = o1; col = c1; X = X1; M = M1; }
    else { wid -= n0 + n1; if (wid >= n2) return; offs = o2; col = c2; X = X2; M = M2; }

    const int start = offs[wid];
    const int end = offs[wid + 1];
    const unsigned short* Xl = X + l32 * 4;

    float a0 = 0.f, a1 = 0.f, a2 = 0.f, a3 = 0.f;
    float b0 = 0.f, b1 = 0.f, b2 = 0.f, b3 = 0.f;
    int e = start;
    for (; e + 3 < end; e += 4) {
        int sA = col[e + 2 * half];
        int sB = col[e + 2 * half + 1];
        uint2 vA = *reinterpret_cast<const uint2*>(Xl + (size_t)sA * HID);
        uint2 vB = *reinterpret_cast<const uint2*>(Xl + (size_t)sB * HID);
        a0 += bf2f((unsigned short)(vA.x & 0xffffu));
        a1 += bf2f((unsigned short)(vA.x >> 16));
        a2 += bf2f((unsigned short)(vA.y & 0xffffu));
        a3 += bf2f((unsigned short)(vA.y >> 16));
        b0 += bf2f((unsigned short)(vB.x & 0xffffu));
        b1 += bf2f((unsigned short)(vB.x >> 16));
        b2 += bf2f((unsigned short)(vB.y & 0xffffu));
        b3 += bf2f((unsigned short)(vB.y >> 16));
    }
    if (e + 1 < end) {
        int sA = col[e + half];
        uint2 vA = *reinterpret_cast<const uint2*>(Xl + (size_t)sA * HID);
        a0 += bf2f((unsigned short)(vA.x & 0xffffu));
        a1 += bf2f((unsigned short)(vA.x >> 16));
        a2 += bf2f((unsigned short)(vA.y & 0xffffu));
        a3 += bf2f((unsigned short)(vA.y >> 16));
        e += 2;
    }
    if (e < end && half == 0) {
        int sA = col[e];
        uint2 vA = *reinterpret_cast<const uint2*>(Xl + (size_t)sA * HID);
        a0 += bf2f((unsigned short)(vA.x & 0xffffu));
        a1 += bf2f((unsigned short)(vA.x >> 16));
        a2 += bf2f((unsigned short)(vA.y & 0xffffu));
        a3 += bf2f((unsigned short)(vA.y >> 16));
    }
    a0 += b0; a1 += b1; a2 += b2; a3 += b3;
    a0 += __shfl_xor(a0, 32, 64);
    a1 += __shfl_xor(a1, 32, 64);
    a2 += __shfl_xor(a2, 32, 64);
    a3 += __shfl_xor(a3, 32, 64);

    if (half == 0) {
        float inv = 1.0f / (float)max(end - start, 1);
        uint2 o;
        o.x = (unsigned int)f2bf(a0 * inv) | ((unsigned int)f2bf(a1 * inv) << 16);
        o.y = (unsigned int)f2bf(a2 * inv) | ((unsigned int)f2bf(a3 * inv) << 16);
        *reinterpret_cast<uint2*>(M + (size_t)wid * HID + l32 * 4) = o;
    }
}

// ---------------------------------------------------------------------------
// Fused CSR mean-aggregation, 64-col rows (pre-transformed Z). 128 B/edge.
// ---------------------------------------------------------------------------
__global__ __launch_bounds__(256) void agg3_64(
    const int* __restrict__ o0, const int* __restrict__ c0,
    const unsigned short* __restrict__ X0, unsigned short* __restrict__ M0, int n0,
    const int* __restrict__ o1, const int* __restrict__ c1,
    const unsigned short* __restrict__ X1, unsigned short* __restrict__ M1, int n1,
    const int* __restrict__ o2, const int* __restrict__ c2,
    const unsigned short* __restrict__ X2, unsigned short* __restrict__ M2, int n2)
{
    int wid = (blockIdx.x * blockDim.x + threadIdx.x) >> 6;
    const int lane = threadIdx.x & 63;
    const int half = lane >> 5;
    const int l32 = lane & 31;

    const int* offs; const int* col;
    const unsigned short* X; unsigned short* M;
    if (wid < n0) { offs = o0; col = c0; X = X0; M = M0; }
    else if (wid < n0 + n1) { wid -= n0; offs = o1; col = c1; X = X1; M = M1; }
    else { wid -= n0 + n1; if (wid >= n2) return; offs = o2; col = c2; X = X2; M = M2; }

    const int start = offs[wid];
    const int end = offs[wid + 1];
    const unsigned short* Xl = X + l32 * 2;

    float a0 = 0.f, a1 = 0.f, b0 = 0.f, b1 = 0.f;
    int e = start;
    for (; e + 3 < end; e += 4) {
        int sA = col[e + 2 * half];
        int sB = col[e + 2 * half + 1];
        unsigned vA = *reinterpret_cast<const unsigned*>(Xl + (size_t)sA * OUTD);
        unsigned vB = *reinterpret_cast<const unsigned*>(Xl + (size_t)sB * OUTD);
        a0 += bf2f((unsigned short)(vA & 0xffffu));
        a1 += bf2f((unsigned short)(vA >> 16));
        b0 += bf2f((unsigned short)(vB & 0xffffu));
        b1 += bf2f((unsigned short)(vB >> 16));
    }
    if (e + 1 < end) {
        int sA = col[e + half];
        unsigned vA = *reinterpret_cast<const unsigned*>(Xl + (size_t)sA * OUTD);
        a0 += bf2f((unsigned short)(vA & 0xffffu));
        a1 += bf2f((unsigned short)(vA >> 16));
        e += 2;
    }
    if (e < end && half == 0) {
        int sA = col[e];
        unsigned vA = *reinterpret_cast<const unsigned*>(Xl + (size_t)sA * OUTD);
        a0 += bf2f((unsigned short)(vA & 0xffffu));
        a1 += bf2f((unsigned short)(vA >> 16));
    }
    a0 += b0; a1 += b1;
    a0 += __shfl_xor(a0, 32, 64);
    a1 += __shfl_xor(a1, 32, 64);

    if (half == 0) {
        float inv = 1.0f / (float)max(end - start, 1);
        unsigned o = (unsigned)f2bf(a0 * inv) | ((unsigned)f2bf(a1 * inv) << 16);
        *reinterpret_cast<unsigned*>(M + (size_t)wid * OUTD + l32 * 2) = o;
    }
}

// ---------------------------------------------------------------------------
// Fused transform: Z = H @ Wl (first half of Wt), CO=64, K=128. 3 sections.
// ---------------------------------------------------------------------------
__global__ __launch_bounds__(256) void xform3(
    const unsigned short* __restrict__ H0, const unsigned short* __restrict__ W0,
    unsigned short* __restrict__ Z0, int n0,
    const unsigned short* __restrict__ H1, const unsigned short* __restrict__ W1,
    unsigned short* __restrict__ Z1, int n1,
    const unsigned short* __restrict__ H2, const unsigned short* __restrict__ W2,
    unsigned short* __restrict__ Z2, int n2)
{
    const int b0 = (n0 + 63) / 64, b1 = (n1 + 63) / 64;
    int b = blockIdx.x;
    const unsigned short *H, *W; unsigned short* Z; int n;
    if (b < b0) { H = H0; W = W0; Z = Z0; n = n0; }
    else if (b < b0 + b1) { b -= b0; H = H1; W = W1; Z = Z1; n = n1; }
    else { b -= b0 + b1; H = H2; W = W2; Z = Z2; n = n2; }

    constexpr int NT = OUTD / 16;   // 4
    const int wave = threadIdx.x >> 6;
    const int lane = threadIdx.x & 63;
    const int r16 = lane & 15;
    const int chunk = lane >> 4;
    const int rowbase = b * 64 + wave * 16;
    if (rowbase >= n) return;

    const int arow = min(rowbase + r16, n - 1);
    const unsigned short* hrow = H + (size_t)arow * HID;

    bf16x8 a[4];
#pragma unroll
    for (int s = 0; s < 4; ++s)
        a[s] = *reinterpret_cast<const bf16x8*>(hrow + s * 32 + chunk * 8);

    f32x4 acc[NT];
#pragma unroll
    for (int t = 0; t < NT; ++t) acc[t] = f32x4{0.f, 0.f, 0.f, 0.f};

#pragma unroll
    for (int t = 0; t < NT; ++t) {
        const unsigned short* w_ = W + (size_t)(t * 16 + r16) * 256;   // Wl half
#pragma unroll
        for (int s = 0; s < 4; ++s) {
            bf16x8 bfrag = *reinterpret_cast<const bf16x8*>(w_ + s * 32 + chunk * 8);
            acc[t] = __builtin_amdgcn_mfma_f32_16x16x32_bf16(a[s], bfrag, acc[t], 0, 0, 0);
        }
    }

#pragma unroll
    for (int r = 0; r < 4; ++r) {
        int node = rowbase + chunk * 4 + r;
        if (node < n) {
#pragma unroll
            for (int t = 0; t < NT; ++t)
                Z[(size_t)node * OUTD + t * 16 + r16] = f2bf(acc[t][r]);
        }
    }
}

// ---------------------------------------------------------------------------
// Layer-0 SAGE kernels (K=256 over [mean|x]).
// C/D layout: col = lane&15, row = (lane>>4)*4 + reg   [verified m89]
// ---------------------------------------------------------------------------
template <int CO>
__global__ __launch_bounds__(256) void sage_mfma(
    const unsigned short* __restrict__ Mb,
    const unsigned short* __restrict__ Xb,
    const unsigned short* __restrict__ Wt,
    const float* __restrict__ bl,
    float* __restrict__ H, int n)
{
    constexpr int NT = CO / 16;
    const int wave = threadIdx.x >> 6;
    const int lane = threadIdx.x & 63;
    const int r16 = lane & 15;
    const int chunk = lane >> 4;
    const int rowbase = blockIdx.x * 64 + wave * 16;
    if (rowbase >= n) return;

    const int arow = min(rowbase + r16, n - 1);
    const unsigned short* mrow = Mb + (size_t)arow * HID;
    const unsigned short* xrow = Xb + (size_t)arow * HID;

    bf16x8 a[8];
#pragma unroll
    for (int s = 0; s < 4; ++s) {
        a[s]     = *reinterpret_cast<const bf16x8*>(mrow + s * 32 + chunk * 8);
        a[4 + s] = *reinterpret_cast<const bf16x8*>(xrow + s * 32 + chunk * 8);
    }

    f32x4 acc[NT];
#pragma unroll
    for (int t = 0; t < NT; ++t) acc[t] = f32x4{0.f, 0.f, 0.f, 0.f};

#pragma unroll
    for (int t = 0; t < NT; ++t) {
        const unsigned short* wr_ = Wt + (size_t)(t * 16 + r16) * 256;
#pragma unroll
        for (int s = 0; s < 8; ++s) {
            bf16x8 b = *reinterpret_cast<const bf16x8*>(wr_ + s * 32 + chunk * 8);
            acc[t] = __builtin_amdgcn_mfma_f32_16x16x32_bf16(a[s], b, acc[t], 0, 0, 0);
        }
    }

    float ss[4] = {0.f, 0.f, 0.f, 0.f};
#pragma unroll
    for (int t = 0; t < NT; ++t) {
        float bias = bl[t * 16 + r16];
#pragma unroll
        for (int r = 0; r < 4; ++r) {
            acc[t][r] += bias;
            ss[r] += acc[t][r] * acc[t][r];
        }
    }
#pragma unroll
    for (int r = 0; r < 4; ++r)
#pragma unroll
        for (int m = 1; m < 16; m <<= 1)
            ss[r] += __shfl_xor(ss[r], m, 64);

#pragma unroll
    for (int r = 0; r < 4; ++r) {
        int node = rowbase + chunk * 4 + r;
        if (node < n) {
            float inv = 1.0f / fmaxf(sqrtf(ss[r]), 1e-12f);
#pragma unroll
            for (int t = 0; t < NT; ++t)
                H[(size_t)node * CO + t * 16 + r16] = acc[t][r] * inv;
        }
    }
}

template <int CO>
__global__ __launch_bounds__(256) void sage2_mfma(
    const unsigned short* __restrict__ MbA,
    const unsigned short* __restrict__ MbB,
    const unsigned short* __restrict__ Xb,
    const unsigned short* __restrict__ WtA,
    const unsigned short* __restrict__ WtB,
    const float* __restrict__ blA, const float* __restrict__ blB,
    float* __restrict__ H, int n)
{
    constexpr int NT = CO / 16;
    const int wave = threadIdx.x >> 6;
    const int lane = threadIdx.x & 63;
    const int r16 = lane & 15;
    const int chunk = lane >> 4;
    const int rowbase = blockIdx.x * 64 + wave * 16;
    if (rowbase >= n) return;

    const int arow = min(rowbase + r16, n - 1);
    const unsigned short* marow = MbA + (size_t)arow * HID;
    const unsigned short* mbrow = MbB + (size_t)arow * HID;
    const unsigned short* xrow  = Xb  + (size_t)arow * HID;

    bf16x8 aA[4], aB[4], ax[4];
#pragma unroll
    for (int s = 0; s < 4; ++s) {
        aA[s] = *reinterpret_cast<const bf16x8*>(marow + s * 32 + chunk * 8);
        aB[s] = *reinterpret_cast<const bf16x8*>(mbrow + s * 32 + chunk * 8);
        ax[s] = *reinterpret_cast<const bf16x8*>(xrow  + s * 32 + chunk * 8);
    }

    f32x4 accA[NT], accB[NT];
#pragma unroll
    for (int t = 0; t < NT; ++t) {
        accA[t] = f32x4{0.f, 0.f, 0.f, 0.f};
        accB[t] = f32x4{0.f, 0.f, 0.f, 0.f};
    }

#pragma unroll
    for (int t = 0; t < NT; ++t) {
        const unsigned short* wA = WtA + (size_t)(t * 16 + r16) * 256;
        const unsigned short* wB = WtB + (size_t)(t * 16 + r16) * 256;
#pragma unroll
        for (int s = 0; s < 4; ++s) {
            bf16x8 b0 = *reinterpret_cast<const bf16x8*>(wA + s * 32 + chunk * 8);
            accA[t] = __builtin_amdgcn_mfma_f32_16x16x32_bf16(aA[s], b0, accA[t], 0, 0, 0);
            bf16x8 b1 = *reinterpret_cast<const bf16x8*>(wA + HID + s * 32 + chunk * 8);
            accA[t] = __builtin_amdgcn_mfma_f32_16x16x32_bf16(ax[s], b1, accA[t], 0, 0, 0);
            bf16x8 b2 = *reinterpret_cast<const bf16x8*>(wB + s * 32 + chunk * 8);
            accB[t] = __builtin_amdgcn_mfma_f32_16x16x32_bf16(aB[s], b2, accB[t], 0, 0, 0);
            bf16x8 b3 = *reinterpret_cast<const bf16x8*>(wB + HID + s * 32 + chunk * 8);
            accB[t] = __builtin_amdgcn_mfma_f32_16x16x32_bf16(ax[s], b3, accB[t], 0, 0, 0);
        }
    }

    float ssA[4] = {0.f, 0.f, 0.f, 0.f};
    float ssB[4] = {0.f, 0.f, 0.f, 0.f};
#pragma unroll
    for (int t = 0; t < NT; ++t) {
        float biasA = blA[t * 16 + r16];
        float biasB = blB[t * 16 + r16];
#pragma unroll
        for (int r = 0; r < 4; ++r) {
            accA[t][r] += biasA;
            ssA[r] += accA[t][r] * accA[t][r];
            accB[t][r] += biasB;
            ssB[r] += accB[t][r] * accB[t][r];
        }
    }
#pragma unroll
    for (int r = 0; r < 4; ++r)
#pragma unroll
        for (int m = 1; m < 16; m <<= 1) {
            ssA[r] += __shfl_xor(ssA[r], m, 64);
            ssB[r] += __shfl_xor(ssB[r], m, 64);
        }

#pragma unroll
    for (int r = 0; r < 4; ++r) {
        int node = rowbase + chunk * 4 + r;
        if (node < n) {
            float invA = 1.0f / fmaxf(sqrtf(ssA[r]), 1e-12f);
            float invB = 1.0f / fmaxf(sqrtf(ssB[r]), 1e-12f);
#pragma unroll
            for (int t = 0; t < NT; ++t)
                H[(size_t)node * CO + t * 16 + r16] =
                    accA[t][r] * invA + accB[t][r] * invB;
        }
    }
}

// ---------------------------------------------------------------------------
// Layer-1 SAGE with pre-aggregated meanZ (= mean@Wl): only x@Wr via MFMA.
// ---------------------------------------------------------------------------
__global__ __launch_bounds__(256) void sage2z(
    const unsigned short* __restrict__ MZa,   // [n][64]
    const unsigned short* __restrict__ MZb,   // [n][64]
    const unsigned short* __restrict__ Xb,    // [n][128]
    const unsigned short* __restrict__ WtA,   // [64][256] (Wr at +HID)
    const unsigned short* __restrict__ WtB,
    const float* __restrict__ blA, const float* __restrict__ blB,
    float* __restrict__ H, int n)
{
    constexpr int NT = OUTD / 16;
    const int wave = threadIdx.x >> 6;
    const int lane = threadIdx.x & 63;
    const int r16 = lane & 15;
    const int chunk = lane >> 4;
    const int rowbase = blockIdx.x * 64 + wave * 16;
    if (rowbase >= n) return;

    const int arow = min(rowbase + r16, n - 1);
    const unsigned short* xrow = Xb + (size_t)arow * HID;

    bf16x8 ax[4];
#pragma unroll
    for (int s = 0; s < 4; ++s)
        ax[s] = *reinterpret_cast<const bf16x8*>(xrow + s * 32 + chunk * 8);

    f32x4 accA[NT], accB[NT];
#pragma unroll
    for (int t = 0; t < NT; ++t) {
        accA[t] = f32x4{0.f, 0.f, 0.f, 0.f};
        accB[t] = f32x4{0.f, 0.f, 0.f, 0.f};
    }

#pragma unroll
    for (int t = 0; t < NT; ++t) {
        const unsigned short* wA = WtA + (size_t)(t * 16 + r16) * 256 + HID;
        const unsigned short* wB = WtB + (size_t)(t * 16 + r16) * 256 + HID;
#pragma unroll
        for (int s = 0; s < 4; ++s) {
            bf16x8 b0 = *reinterpret_cast<const bf16x8*>(wA + s * 32 + chunk * 8);
            accA[t] = __builtin_amdgcn_mfma_f32_16x16x32_bf16(ax[s], b0, accA[t], 0, 0, 0);
            bf16x8 b1 = *reinterpret_cast<const bf16x8*>(wB + s * 32 + chunk * 8);
            accB[t] = __builtin_amdgcn_mfma_f32_16x16x32_bf16(ax[s], b1, accB[t], 0, 0, 0);
        }
    }

    float ssA[4] = {0.f, 0.f, 0.f, 0.f};
    float ssB[4] = {0.f, 0.f, 0.f, 0.f};
#pragma unroll
    for (int r = 0; r < 4; ++r) {
        int cl = min(rowbase + chunk * 4 + r, n - 1);
#pragma unroll
        for (int t = 0; t < NT; ++t) {
            int j = t * 16 + r16;
            float vA = accA[t][r] + blA[j] + bf2f(MZa[(size_t)cl * OUTD + j]);
            accA[t][r] = vA;
            ssA[r] += vA * vA;
            float vB = accB[t][r] + blB[j] + bf2f(MZb[(size_t)cl * OUTD + j]);
            accB[t][r] = vB;
            ssB[r] += vB * vB;
        }
    }
#pragma unroll
    for (int r = 0; r < 4; ++r)
#pragma unroll
        for (int m = 1; m < 16; m <<= 1) {
            ssA[r] += __shfl_xor(ssA[r], m, 64);
            ssB[r] += __shfl_xor(ssB[r], m, 64);
        }

#pragma unroll
    for (int r = 0; r < 4; ++r) {
        int node = rowbase + chunk * 4 + r;
        if (node < n) {
            float invA = 1.0f / fmaxf(sqrtf(ssA[r]), 1e-12f);
            float invB = 1.0f / fmaxf(sqrtf(ssB[r]), 1e-12f);
#pragma unroll
            for (int t = 0; t < NT; ++t)
                H[(size_t)node * OUTD + t * 16 + r16] =
                    accA[t][r] * invA + accB[t][r] * invB;
        }
    }
}

__global__ __launch_bounds__(256) void sagez(
    const unsigned short* __restrict__ MZ,    // [n][64]
    const unsigned short* __restrict__ Xb,    // [n][128]
    const unsigned short* __restrict__ Wt,    // [64][256] (Wr at +HID)
    const float* __restrict__ bl,
    float* __restrict__ H, int n)
{
    constexpr int NT = OUTD / 16;
    const int wave = threadIdx.x >> 6;
    const int lane = threadIdx.x & 63;
    const int r16 = lane & 15;
    const int chunk = lane >> 4;
    const int rowbase = blockIdx.x * 64 + wave * 16;
    if (rowbase >= n) return;

    const int arow = min(rowbase + r16, n - 1);
    const unsigned short* xrow = Xb + (size_t)arow * HID;

    bf16x8 ax[4];
#pragma unroll
    for (int s = 0; s < 4; ++s)
        ax[s] = *reinterpret_cast<const bf16x8*>(xrow + s * 32 + chunk * 8);

    f32x4 acc[NT];
#pragma unroll
    for (int t = 0; t < NT; ++t) acc[t] = f32x4{0.f, 0.f, 0.f, 0.f};

#pragma unroll
    for (int t = 0; t < NT; ++t) {
        const unsigned short* w_ = Wt + (size_t)(t * 16 + r16) * 256 + HID;
#pragma unroll
        for (int s = 0; s < 4; ++s) {
            bf16x8 b = *reinterpret_cast<const bf16x8*>(w_ + s * 32 + chunk * 8);
            acc[t] = __builtin_amdgcn_mfma_f32_16x16x32_bf16(ax[s], b, acc[t], 0, 0, 0);
        }
    }

    float ss[4] = {0.f, 0.f, 0.f, 0.f};
#pragma unroll
    for (int r = 0; r < 4; ++r) {
        int cl = min(rowbase + chunk * 4 + r, n - 1);
#pragma unroll
        for (int t = 0; t < NT; ++t) {
            int j = t * 16 + r16;
            float v = acc[t][r] + bl[j] + bf2f(MZ[(size_t)cl * OUTD + j]);
            acc[t][r] = v;
            ss[r] += v * v;
        }
    }
#pragma unroll
    for (int r = 0; r < 4; ++r)
#pragma unroll
        for (int m = 1; m < 16; m <<= 1)
            ss[r] += __shfl_xor(ss[r], m, 64);

#pragma unroll
    for (int r = 0; r < 4; ++r) {
        int node = rowbase + chunk * 4 + r;
        if (node < n) {
            float inv = 1.0f / fmaxf(sqrtf(ss[r]), 1e-12f);
#pragma unroll
            for (int t = 0; t < NT; ++t)
                H[(size_t)node * OUTD + t * 16 + r16] = acc[t][r] * inv;
        }
    }
}

// ---------------------------------------------------------------------------
// LayerNorm (+optional ReLU), one wave per row; fp32 in; bf16 or fp32 out.
// ---------------------------------------------------------------------------
template <int D, bool RELU, bool OUTBF>
__global__ __launch_bounds__(256) void ln_kernel(
    const float* __restrict__ X, const float* __restrict__ gg,
    const float* __restrict__ bb, void* __restrict__ outp, int n)
{
    constexpr int VPL = D / 64;
    int wid = (blockIdx.x * blockDim.x + threadIdx.x) >> 6;
    int lane = threadIdx.x & 63;
    if (wid >= n) return;

    float v[VPL], gv[VPL], bv[VPL];
    const float* xp = X + (size_t)wid * D + lane * VPL;
#pragma unroll
    for (int k = 0; k < VPL; ++k) {
        v[k] = xp[k];
        gv[k] = gg[lane * VPL + k];
        bv[k] = bb[lane * VPL + k];
    }
    float s = 0.f;
#pragma unroll
    for (int k = 0; k < VPL; ++k) s += v[k];
#pragma unroll
    for (int off = 32; off > 0; off >>= 1) s += __shfl_xor(s, off, 64);
    float m = s / D;
    float ss = 0.f;
#pragma unroll
    for (int k = 0; k < VPL; ++k) { float d = v[k] - m; ss += d * d; }
#pragma unroll
    for (int off = 32; off > 0; off >>= 1) ss += __shfl_xor(ss, off, 64);
    float rstd = rsqrtf(ss / D + 1e-5f);

    float y[VPL];
#pragma unroll
    for (int k = 0; k < VPL; ++k) {
        y[k] = gv[k] * (v[k] - m) * rstd + bv[k];
        if (RELU) y[k] = fmaxf(y[k], 0.f);
    }
    if (OUTBF) {
        unsigned short* op = (unsigned short*)outp + (size_t)wid * D + lane * VPL;
#pragma unroll
        for (int k = 0; k < VPL; ++k) op[k] = f2bf(y[k]);
    } else {
        float* op = (float*)outp + (size_t)wid * D + lane * VPL;
#pragma unroll
        for (int k = 0; k < VPL; ++k) op[k] = y[k];
    }
}

// ---------------------------------------------------------------------------
extern "C" void kernel_launch(void* const* d_in, const int* in_sizes, int n_in,
                              void* d_out, int out_size, void* d_ws, size_t ws_size,
                              hipStream_t stream)
{
    const int*   x_drug   = (const int*)d_in[0];
    const int*   x_dis    = (const int*)d_in[1];
    const float* emb_drug = (const float*)d_in[2];
    const float* emb_dis  = (const float*)d_in[3];
    const int*   src_dd   = (const int*)d_in[4];
    const int*   dst_dd   = (const int*)d_in[5];
    const int*   src_td   = (const int*)d_in[6];
    const int*   dst_td   = (const int*)d_in[7];
    const int*   src_rd   = (const int*)d_in[8];
    const int*   dst_rd   = (const int*)d_in[9];
    const float* Wl0_dd = (const float*)d_in[10];
    const float* bl0_dd = (const float*)d_in[11];
    const float* Wr0_dd = (const float*)d_in[12];
    const float* Wl0_td = (const float*)d_in[13];
    const float* bl0_td = (const float*)d_in[14];
    const float* Wr0_td = (const float*)d_in[15];
    const float* Wl0_rd = (const float*)d_in[16];
    const float* bl0_rd = (const float*)d_in[17];
    const float* Wr0_rd = (const float*)d_in[18];
    const float* Wl1_dd = (const float*)d_in[19];
    const float* bl1_dd = (const float*)d_in[20];
    const float* Wr1_dd = (const float*)d_in[21];
    const float* Wl1_td = (const float*)d_in[22];
    const float* bl1_td = (const float*)d_in[23];
    const float* Wr1_td = (const float*)d_in[24];
    const float* Wl1_rd = (const float*)d_in[25];
    const float* bl1_rd = (const float*)d_in[26];
    const float* Wr1_rd = (const float*)d_in[27];
    const float* g0_drug = (const float*)d_in[28];
    const float* b0_drug = (const float*)d_in[29];
    const float* g0_dis  = (const float*)d_in[30];
    const float* b0_dis  = (const float*)d_in[31];
    const float* g1_drug = (const float*)d_in[32];
    const float* b1_drug = (const float*)d_in[33];
    const float* g1_dis  = (const float*)d_in[34];
    const float* b1_dis  = (const float*)d_in[35];

    // ---------------- workspace layout ----------------
    char* wp = (char*)d_ws;
    auto alloc = [&](size_t bytes) { char* p = wp; wp += (bytes + 255) & ~size_t(255); return p; };

    unsigned short* hd0  = (unsigned short*)alloc((size_t)ND * HID * 2);
    unsigned short* hz0  = (unsigned short*)alloc((size_t)NZ * HID * 2);
    unsigned short* hd1b = (unsigned short*)alloc((size_t)ND * HID * 2);
    unsigned short* hz1b = (unsigned short*)alloc((size_t)NZ * HID * 2);
    unsigned short* meanA= (unsigned short*)alloc((size_t)ND * HID * 2);
    unsigned short* meanB= (unsigned short*)alloc((size_t)ND * HID * 2);
    unsigned short* meanC= (unsigned short*)alloc((size_t)NZ * HID * 2);
    unsigned short* Zdd  = (unsigned short*)alloc((size_t)ND * OUTD * 2);
    unsigned short* Zrd  = (unsigned short*)alloc((size_t)NZ * OUTD * 2);
    unsigned short* Ztd  = (unsigned short*)alloc((size_t)ND * OUTD * 2);
    float* hd1f = (float*)alloc((size_t)ND * HID * 4);
    float* hz1f = (float*)alloc((size_t)NZ * HID * 4);
    unsigned short* Wt0_dd = (unsigned short*)alloc((size_t)HID * 256 * 2);
    unsigned short* Wt0_rd = (unsigned short*)alloc((size_t)HID * 256 * 2);
    unsigned short* Wt0_td = (unsigned short*)alloc((size_t)HID * 256 * 2);
    unsigned short* Wt1_dd = (unsigned short*)alloc((size_t)OUTD * 256 * 2);
    unsigned short* Wt1_rd = (unsigned short*)alloc((size_t)OUTD * 256 * 2);
    unsigned short* Wt1_td = (unsigned short*)alloc((size_t)OUTD * 256 * 2);
    int* offs_dd = (int*)alloc((ND + 1) * 4);
    int* offs_rd = (int*)alloc((ND + 1) * 4);
    int* offs_td = (int*)alloc((NZ + 1) * 4);
    int* col_dd  = (int*)alloc((size_t)E * 4);
    int* col_rd  = (int*)alloc((size_t)E * 4);
    int* col_td  = (int*)alloc((size_t)E * 4);
    // contiguous count region (one memset covers all three)
    int* cnt_dd  = (int*)alloc(((size_t)(ND + 1) + (ND + 1) + (NZ + 1)) * 4);
    int* cnt_rd  = cnt_dd + (ND + 1);
    int* cnt_td  = cnt_rd + (ND + 1);
    int* part    = (int*)alloc(3 * 64 * 4);
    int* rc      = (int*)alloc(3 * CHK * 8 * 4);
    int* wpos    = (int*)alloc(3 * CHK * 8 * 4);
    int* rbase   = (int*)alloc(3 * 9 * 4);

    // Buckets alias hd1f/hz1f (disjoint lifetime: buckets die before layer-0
    // sage writes hd1f/hz1f).
    int2* bkt_dd = (int2*)hd1f;
    int2* bkt_rd = bkt_dd + E;
    int2* bkt_td = (int2*)hz1f;
    // partial/bases (PTOT ints = 3.84 MB) alias meanA (12.8 MB, used post-build)
    int* partial = (int*)meanA;

    float* outD = (float*)d_out;
    float* outZ = outD + (size_t)ND * OUTD;

    // ---------------- independent prep ----------------
    gather_all<<<ceil_div((ND + NZ) * 32, 256), 256, 0, stream>>>(
        emb_drug, x_drug, emb_dis, x_dis, hd0, hz0);

    PrepArgs pa;
    pa.wl[0] = Wl0_dd; pa.wr[0] = Wr0_dd; pa.wt[0] = Wt0_dd; pa.co[0] = HID;
    pa.wl[1] = Wl0_rd; pa.wr[1] = Wr0_rd; pa.wt[1] = Wt0_rd; pa.co[1] = HID;
    pa.wl[2] = Wl0_td; pa.wr[2] = Wr0_td; pa.wt[2] = Wt0_td; pa.co[2] = HID;
    pa.wl[3] = Wl1_dd; pa.wr[3] = Wr1_dd; pa.wt[3] = Wt1_dd; pa.co[3] = OUTD;
    pa.wl[4] = Wl1_rd; pa.wr[4] = Wr1_rd; pa.wt[4] = Wt1_rd; pa.co[4] = OUTD;
    pa.wl[5] = Wl1_td; pa.wr[5] = Wr1_td; pa.wt[5] = Wt1_td; pa.co[5] = OUTD;
    pa.boff[0] = 0;
    for (int s = 0; s < 6; ++s) pa.boff[s + 1] = pa.boff[s] + pa.co[s];
    prep_all<<<pa.boff[6], 256, 0, stream>>>(pa);

    // ---------------- bucketed CSR build (NO global atomics) ----------------
    bcount<<<3 * CHK, 256, 0, stream>>>(dst_dd, dst_rd, dst_td, rc);
    bscan<<<1, 256, 0, stream>>>(rc, wpos, rbase);
    bscatter<<<3 * CHK, 256, 0, stream>>>(
        src_dd, dst_dd, src_rd, dst_rd, src_td, dst_td,
        wpos, bkt_dd, bkt_rd, bkt_td);
    bcount2<<<NXCD * 3 * SSUB, 256, 0, stream>>>(
        bkt_dd, bkt_rd, bkt_td, rbase, partial);
    sumcnt<<<ceil_div(2 * ND + NZ, 256), 256, 0, stream>>>(
        partial, cnt_dd, cnt_rd, cnt_td);
    scan_part3<<<2 * NB_D + NB_Z, 256, 0, stream>>>(cnt_dd, cnt_rd, cnt_td, part);
    scan_small3<<<3, 64, 0, stream>>>(part, offs_dd, offs_rd, offs_td);
    scan_write3<<<2 * NB_D + NB_Z, 256, 0, stream>>>(
        cnt_dd, cnt_rd, cnt_td, part, offs_dd, offs_rd, offs_td);
    basek<<<ceil_div(2 * ND + NZ, 256), 256, 0, stream>>>(
        partial, offs_dd, offs_rd, offs_td);
    bfill2<<<NXCD * 3 * SSUB, 256, 0, stream>>>(
        bkt_dd, bkt_rd, bkt_td, rbase, partial, col_dd, col_rd, col_td);

    // ---------------- layer 0 ----------------
    agg3_128<<<ceil_div((2 * ND + NZ) * 64, 256), 256, 0, stream>>>(
        offs_dd, col_dd, hd0, meanA, ND,
        offs_rd, col_rd, hz0, meanB, ND,
        offs_td, col_td, hd0, meanC, NZ);
    sage2_mfma<HID><<<ceil_div(ND, 64), 256, 0, stream>>>(
        meanA, meanB, hd0, Wt0_dd, Wt0_rd, bl0_dd, bl0_rd, hd1f, ND);
    sage_mfma<HID><<<ceil_div(NZ, 64), 256, 0, stream>>>(
        meanC, hz0, Wt0_td, bl0_td, hz1f, NZ);

    ln_kernel<HID, true, true><<<ceil_div(ND, 4), 256, 0, stream>>>(hd1f, g0_drug, b0_drug, hd1b, ND);
    ln_kernel<HID, true, true><<<ceil_div(NZ, 4), 256, 0, stream>>>(hz1f, g0_dis, b0_dis, hz1b, NZ);

    // ---------------- layer 1 (transform-then-aggregate) ----------------
    xform3<<<ceil_div(ND, 64) * 2 + ceil_div(NZ, 64), 256, 0, stream>>>(
        hd1b, Wt1_dd, Zdd, ND,
        hz1b, Wt1_rd, Zrd, NZ,
        hd1b, Wt1_td, Ztd, ND);

    agg3_64<<<ceil_div((2 * ND + NZ) * 64, 256), 256, 0, stream>>>(
        offs_dd, col_dd, Zdd, meanA, ND,
        offs_rd, col_rd, Zrd, meanB, ND,
        offs_td, col_td, Ztd, meanC, NZ);

    sage2z<<<ceil_div(ND, 64), 256, 0, stream>>>(
        meanA, meanB, hd1b, Wt1_dd, Wt1_rd, bl1_dd, bl1_rd, outD, ND);
    sagez<<<ceil_div(NZ, 64), 256, 0, stream>>>(
        meanC, hz1b, Wt1_td, bl1_td, outZ, NZ);

    ln_kernel<OUTD, false, false><<<ceil_div(ND, 4), 256, 0, stream>>>(outD, g1_drug, b1_drug, outD, ND);
    ln_kernel<OUTD, false, false><<<ceil_div(NZ, 4), 256, 0, stream>>>(outZ, g1_dis, b1_dis, outZ, NZ);
}

// Round 13
// 483.431 us; speedup vs baseline: 2.2071x; 1.0051x over previous
//
#include <hip/hip_runtime.h>

// Problem constants (match reference setup_inputs)
constexpr int ND   = 50000;
constexpr int NZ   = 20000;
constexpr int HID  = 128;
constexpr int OUTD = 64;
constexpr int E    = 1000000;

constexpr int SCAN_TILE = 1024;
constexpr int NB_D = (ND + SCAN_TILE - 1) / SCAN_TILE;   // 49
constexpr int NB_Z = (NZ + SCAN_TILE - 1) / SCAN_TILE;   // 20
constexpr int NXCD = 8;
constexpr int CHK  = 96;     // edge chunks per list (bucket build)
constexpr int SSUB = 8;      // slices per (list,range) in count/fill
constexpr int RN_D = ND / NXCD;   // 6250
constexpr int RN_Z = NZ / NXCD;   // 2500
constexpr int PB1 = NXCD * SSUB * RN_D;
constexpr int PB2 = PB1 + NXCD * SSUB * RN_D;
constexpr int PTOT = PB2 + NXCD * SSUB * RN_Z;

static inline int ceil_div(int a, int b) { return (a + b - 1) / b; }

typedef __bf16 bf16x8 __attribute__((ext_vector_type(8)));
typedef float  f32x4  __attribute__((ext_vector_type(4)));

__device__ __forceinline__ float bf2f(unsigned short b) {
    return __uint_as_float(((unsigned int)b) << 16);
}
__device__ __forceinline__ unsigned short f2bf(float f) {
    unsigned int u = __float_as_uint(f);
    unsigned int r = (u + 0x7fffu + ((u >> 16) & 1u)) >> 16;
    return (unsigned short)r;
}

// ---------------------------------------------------------------------------
// Fused gather: rows [0,ND) from emb_drug[x_drug], rows [ND,ND+NZ) from emb_dis
// ---------------------------------------------------------------------------
__global__ __launch_bounds__(256) void gather_all(
    const float* __restrict__ emb_d, const int* __restrict__ idx_d,
    const float* __restrict__ emb_z, const int* __restrict__ idx_z,
    unsigned short* __restrict__ out_d, unsigned short* __restrict__ out_z)
{
    int t = blockIdx.x * blockDim.x + threadIdx.x;
    int row = t >> 5;
    int c = (t & 31) * 4;
    if (row >= ND + NZ) return;
    const float* src;
    unsigned short* dst;
    if (row < ND) {
        src = emb_d + (size_t)idx_d[row] * HID;
        dst = out_d + (size_t)row * HID;
    } else {
        int r2 = row - ND;
        src = emb_z + (size_t)idx_z[r2] * HID;
        dst = out_z + (size_t)r2 * HID;
    }
    float4 v = *reinterpret_cast<const float4*>(src + c);
    ushort4 o;
    o.x = f2bf(v.x); o.y = f2bf(v.y); o.z = f2bf(v.z); o.w = f2bf(v.w);
    *reinterpret_cast<ushort4*>(dst + c) = o;
}

// ---------------------------------------------------------------------------
// Fused weight prep
// ---------------------------------------------------------------------------
struct PrepArgs {
    const float* wl[6];
    const float* wr[6];
    unsigned short* wt[6];
    int co[6];
    int boff[7];
};

__global__ __launch_bounds__(256) void prep_all(PrepArgs a)
{
    int sec = 0;
#pragma unroll
    for (int s = 0; s < 6; ++s)
        if ((int)blockIdx.x >= a.boff[s + 1]) sec = s + 1;
    int CO = a.co[sec];
    int idx = (blockIdx.x - a.boff[sec]) * 256 + threadIdx.x;
    int j = idx >> 8;
    int k = idx & 255;
    float v = (k < HID) ? a.wl[sec][k * CO + j] : a.wr[sec][(k - HID) * CO + j];
    a.wt[sec][(size_t)j * 256 + k] = f2bf(v);
}

// ---------------------------------------------------------------------------
// Bucketed CSR build, phase 1: per-(list,chunk) range histogram (LDS)
// ---------------------------------------------------------------------------
__global__ __launch_bounds__(256) void bcount(
    const int* __restrict__ d0, const int* __restrict__ d1, const int* __restrict__ d2,
    int* __restrict__ rc)
{
    __shared__ int lc[8];
    const int list = blockIdx.x / CHK;
    const int chunk = blockIdx.x % CHK;
    if (threadIdx.x < 8) lc[threadIdx.x] = 0;
    __syncthreads();
    const int* dst = (list == 0) ? d0 : (list == 1) ? d1 : d2;
    const int rn = (list == 2) ? RN_Z : RN_D;
    const int elo = (int)((long long)chunk * E / CHK);
    const int ehi = (int)((long long)(chunk + 1) * E / CHK);
    for (int e = elo + threadIdx.x; e < ehi; e += 256) {
        int d = dst[e];
        int r = min(d / rn, 7);
        atomicAdd(&lc[r], 1);
    }
    __syncthreads();
    if (threadIdx.x < 8) rc[(list * CHK + chunk) * 8 + threadIdx.x] = lc[threadIdx.x];
}

// ---------------------------------------------------------------------------
// Phase 2: exclusive scan of rc in order (list, range, chunk); per-list reset.
// ---------------------------------------------------------------------------
__global__ __launch_bounds__(256) void bscan(
    const int* __restrict__ rc, int* __restrict__ wpos, int* __restrict__ rbase)
{
    __shared__ int sc[256];
    const int tid = threadIdx.x;
    const int lo = tid * 9;
    int v[9];
    int s = 0;
#pragma unroll
    for (int k = 0; k < 9; ++k) {
        int i = lo + k;
        int list = i / (8 * CHK), rem = i % (8 * CHK);
        int r = rem / CHK, c = rem % CHK;
        v[k] = rc[(list * CHK + c) * 8 + r];
        s += v[k];
    }
    sc[tid] = s;
    __syncthreads();
    for (int off = 1; off < 256; off <<= 1) {
        int t = (tid >= off) ? sc[tid - off] : 0;
        __syncthreads();
        sc[tid] += t;
        __syncthreads();
    }
    int run = tid ? sc[tid - 1] : 0;
#pragma unroll
    for (int k = 0; k < 9; ++k) {
        int i = lo + k;
        int list = i / (8 * CHK), rem = i % (8 * CHK);
        int r = rem / CHK, c = rem % CHK;
        int base = run - list * E;
        wpos[(list * CHK + c) * 8 + r] = base;
        if (c == 0) rbase[list * 9 + r] = base;
        run += v[k];
    }
    if (tid < 3) rbase[tid * 9 + 8] = E;
}

// ---------------------------------------------------------------------------
// Phase 3: scatter edges (d,s) into per-range buckets
// ---------------------------------------------------------------------------
__global__ __launch_bounds__(256) void bscatter(
    const int* __restrict__ s0, const int* __restrict__ d0,
    const int* __restrict__ s1, const int* __restrict__ d1,
    const int* __restrict__ s2, const int* __restrict__ d2,
    const int* __restrict__ wpos,
    int2* __restrict__ b0, int2* __restrict__ b1, int2* __restrict__ b2)
{
    __shared__ int lc[8];
    const int list = blockIdx.x / CHK;
    const int chunk = blockIdx.x % CHK;
    if (threadIdx.x < 8) lc[threadIdx.x] = wpos[(list * CHK + chunk) * 8 + threadIdx.x];
    __syncthreads();
    const int* src = (list == 0) ? s0 : (list == 1) ? s1 : s2;
    const int* dst = (list == 0) ? d0 : (list == 1) ? d1 : d2;
    int2* bkt = (list == 0) ? b0 : (list == 1) ? b1 : b2;
    const int rn = (list == 2) ? RN_Z : RN_D;
    const int elo = (int)((long long)chunk * E / CHK);
    const int ehi = (int)((long long)(chunk + 1) * E / CHK);
    for (int e = elo + threadIdx.x; e < ehi; e += 256) {
        int d = dst[e];
        int s = src[e];
        int r = min(d / rn, 7);
        int p = atomicAdd(&lc[r], 1);
        bkt[p] = make_int2(d, s);
    }
}

// ---------------------------------------------------------------------------
// Phase 4: exact per-(slice,node) counts via LDS histogram. NO global atomics.
// ---------------------------------------------------------------------------
__global__ __launch_bounds__(256) void bcount2(
    const int2* __restrict__ b0, const int2* __restrict__ b1, const int2* __restrict__ b2,
    const int* __restrict__ rbase, int* __restrict__ partial)
{
    __shared__ int lh[RN_D];
    const int range = blockIdx.x & 7;
    const int t = blockIdx.x >> 3;
    const int list = t % 3;
    const int sub = t / 3;
    const int2* bkt = (list == 0) ? b0 : (list == 1) ? b1 : b2;
    const int rn = (list == 2) ? RN_Z : RN_D;
    const int pb = (list == 0) ? 0 : (list == 1) ? PB1 : PB2;
    const int rlo = range * rn;
    for (int i = threadIdx.x; i < rn; i += 256) lh[i] = 0;
    __syncthreads();
    const int s0 = rbase[list * 9 + range];
    const int s1 = rbase[list * 9 + range + 1];
    const int len = s1 - s0;
    const int lo = s0 + (int)((long long)sub * len / SSUB);
    const int hi = s0 + (int)((long long)(sub + 1) * len / SSUB);
    for (int i = lo + threadIdx.x; i < hi; i += 256)
        atomicAdd(&lh[bkt[i].x - rlo], 1);
    __syncthreads();
    int* pout = partial + pb + (range * SSUB + sub) * rn;
    for (int i = threadIdx.x; i < rn; i += 256) pout[i] = lh[i];
}

// ---------------------------------------------------------------------------
// cnt[node] = sum over slices of partial
// ---------------------------------------------------------------------------
__global__ __launch_bounds__(256) void sumcnt(
    const int* __restrict__ partial,
    int* __restrict__ c0, int* __restrict__ c1, int* __restrict__ c2)
{
    int idx = blockIdx.x * 256 + threadIdx.x;
    int list, node;
    if (idx < ND) { list = 0; node = idx; }
    else if (idx < 2 * ND) { list = 1; node = idx - ND; }
    else if (idx < 2 * ND + NZ) { list = 2; node = idx - 2 * ND; }
    else return;
    const int rn = (list == 2) ? RN_Z : RN_D;
    const int pb = (list == 0) ? 0 : (list == 1) ? PB1 : PB2;
    int r = node / rn, local = node % rn;
    const int* p = partial + pb + r * SSUB * rn + local;
    int s = 0;
#pragma unroll
    for (int k = 0; k < SSUB; ++k) s += p[(size_t)k * rn];
    int* cnt = (list == 0) ? c0 : (list == 1) ? c1 : c2;
    cnt[node] = s;
}

// ---------------------------------------------------------------------------
// Fused 3-phase scan over the 3 count arrays
// ---------------------------------------------------------------------------
__device__ __forceinline__ void scan_map(int b, int& which, int& tile) {
    if (b < NB_D) { which = 0; tile = b; }
    else if (b < 2 * NB_D) { which = 1; tile = b - NB_D; }
    else { which = 2; tile = b - 2 * NB_D; }
}

__global__ __launch_bounds__(256) void scan_part3(
    const int* __restrict__ c0, const int* __restrict__ c1, const int* __restrict__ c2,
    int* __restrict__ part)
{
    __shared__ int red[256];
    int which, tile;
    scan_map(blockIdx.x, which, tile);
    const int* cnt = (which == 0) ? c0 : (which == 1) ? c1 : c2;
    int n = (which == 2) ? NZ : ND;
    int base = tile * SCAN_TILE;
    int s = 0;
    for (int i = threadIdx.x; i < SCAN_TILE; i += 256) {
        int idx = base + i;
        if (idx < n) s += cnt[idx];
    }
    red[threadIdx.x] = s;
    __syncthreads();
#pragma unroll
    for (int off = 128; off > 0; off >>= 1) {
        if (threadIdx.x < off) red[threadIdx.x] += red[threadIdx.x + off];
        __syncthreads();
    }
    if (threadIdx.x == 0) part[which * 64 + tile] = red[0];
}

__global__ __launch_bounds__(64) void scan_small3(
    int* __restrict__ part,
    int* __restrict__ o0, int* __restrict__ o1, int* __restrict__ o2)
{
    int w = blockIdx.x;
    int np = (w == 2) ? NB_Z : NB_D;
    int n = (w == 2) ? NZ : ND;
    int* offs = (w == 0) ? o0 : (w == 1) ? o1 : o2;
    int* pb = part + w * 64;
    int lane = threadIdx.x;
    int orig = (lane < np) ? pb[lane] : 0;
    int v = orig;
#pragma unroll
    for (int off = 1; off < 64; off <<= 1) {
        int t = __shfl_up(v, off, 64);
        if (lane >= off) v += t;
    }
    if (lane < np) pb[lane] = v - orig;
    if (lane == 63) offs[n] = v;
}

__global__ __launch_bounds__(256) void scan_write3(
    const int* __restrict__ c0, const int* __restrict__ c1, const int* __restrict__ c2,
    const int* __restrict__ part,
    int* __restrict__ o0, int* __restrict__ o1, int* __restrict__ o2)
{
    __shared__ int sc[256];
    int which, tile;
    scan_map(blockIdx.x, which, tile);
    const int* cnt = (which == 0) ? c0 : (which == 1) ? c1 : c2;
    int* offs = (which == 0) ? o0 : (which == 1) ? o1 : o2;
    int n = (which == 2) ? NZ : ND;

    const int tid = threadIdx.x;
    const int tb = tile * SCAN_TILE + tid * 4;
    int v[4];
    int s = 0;
#pragma unroll
    for (int k = 0; k < 4; ++k) {
        v[k] = (tb + k < n) ? cnt[tb + k] : 0;
        s += v[k];
    }
    sc[tid] = s;
    __syncthreads();
#pragma unroll
    for (int off = 1; off < 256; off <<= 1) {
        int t = (tid >= off) ? sc[tid - off] : 0;
        __syncthreads();
        sc[tid] += t;
        __syncthreads();
    }
    int ex = part[which * 64 + tile] + (tid ? sc[tid - 1] : 0);
#pragma unroll
    for (int k = 0; k < 4; ++k) {
        if (tb + k < n) {
            offs[tb + k] = ex;
            ex += v[k];
        }
    }
}

// ---------------------------------------------------------------------------
// Convert partial counts -> per-slice write bases (in place)
// ---------------------------------------------------------------------------
__global__ __launch_bounds__(256) void basek(
    int* __restrict__ partial,
    const int* __restrict__ o0, const int* __restrict__ o1, const int* __restrict__ o2)
{
    int idx = blockIdx.x * 256 + threadIdx.x;
    int list, node;
    if (idx < ND) { list = 0; node = idx; }
    else if (idx < 2 * ND) { list = 1; node = idx - ND; }
    else if (idx < 2 * ND + NZ) { list = 2; node = idx - 2 * ND; }
    else return;
    const int rn = (list == 2) ? RN_Z : RN_D;
    const int pb = (list == 0) ? 0 : (list == 1) ? PB1 : PB2;
    const int* offs = (list == 0) ? o0 : (list == 1) ? o1 : o2;
    int r = node / rn, local = node % rn;
    int* p = partial + pb + r * SSUB * rn + local;
    int run = offs[node];
#pragma unroll
    for (int k = 0; k < SSUB; ++k) {
        int* q = p + (size_t)k * rn;
        int t = *q;
        *q = run;
        run += t;
    }
}

// ---------------------------------------------------------------------------
// Phase 5: CSR fill from buckets with LDS cursors. NO global atomics.
// ---------------------------------------------------------------------------
__global__ __launch_bounds__(256) void bfill2(
    const int2* __restrict__ b0, const int2* __restrict__ b1, const int2* __restrict__ b2,
    const int* __restrict__ rbase, const int* __restrict__ partial,
    int* __restrict__ l0, int* __restrict__ l1, int* __restrict__ l2)
{
    __shared__ int lcur[RN_D];
    const int range = blockIdx.x & 7;
    const int t = blockIdx.x >> 3;
    const int list = t % 3;
    const int sub = t / 3;
    const int2* bkt = (list == 0) ? b0 : (list == 1) ? b1 : b2;
    int* col = (list == 0) ? l0 : (list == 1) ? l1 : l2;
    const int rn = (list == 2) ? RN_Z : RN_D;
    const int pb = (list == 0) ? 0 : (list == 1) ? PB1 : PB2;
    const int rlo = range * rn;
    const int* bin = partial + pb + (range * SSUB + sub) * rn;
    for (int i = threadIdx.x; i < rn; i += 256) lcur[i] = bin[i];
    __syncthreads();
    const int s0 = rbase[list * 9 + range];
    const int s1 = rbase[list * 9 + range + 1];
    const int len = s1 - s0;
    const int lo = s0 + (int)((long long)sub * len / SSUB);
    const int hi = s0 + (int)((long long)(sub + 1) * len / SSUB);
    for (int i = lo + threadIdx.x; i < hi; i += 256) {
        int2 e = bkt[i];
        int p = atomicAdd(&lcur[e.x - rlo], 1);
        col[p] = e.y;
    }
}

// ---------------------------------------------------------------------------
// CSR mean-aggregation, 128-col rows. Wave = 1 node; sub=lane>>4 edge slot
// (4 edges/issue), cl=lane&15 covers 16B each (16 lanes = full 256B row).
// 2-deep unroll -> 8 edges in flight.
// ---------------------------------------------------------------------------
__global__ __launch_bounds__(256) void agg3_128(
    const int* __restrict__ o0, const int* __restrict__ c0,
    const unsigned short* __restrict__ X0, unsigned short* __restrict__ M0, int n0,
    const int* __restrict__ o1, const int* __restrict__ c1,
    const unsigned short* __restrict__ X1, unsigned short* __restrict__ M1, int n1,
    const int* __restrict__ o2, const int* __restrict__ c2,
    const unsigned short* __restrict__ X2, unsigned short* __restrict__ M2, int n2)
{
    int wid = (blockIdx.x * blockDim.x + threadIdx.x) >> 6;
    const int lane = threadIdx.x & 63;
    const int sub = lane >> 4;       // edge slot 0..3
    const int cl  = lane & 15;       // 16B column slice

    const int* offs; const int* col;
    const unsigned short* X; unsigned short* M;
    if (wid < n0) { offs = o0; col = c0; X = X0; M = M0; }
    else if (wid < n0 + n1) { wid -= n0; offs = o1; col = c1; X = X1; M = M1; }
    else { wid -= n0 + n1; if (wid >= n2) return; offs = o2; col = c2; X = X2; M = M2; }

    const int start = offs[wid];
    const int end = offs[wid + 1];
    const unsigned short* Xl = X + cl * 8;

    float a[8] = {0.f, 0.f, 0.f, 0.f, 0.f, 0.f, 0.f, 0.f};
    float b[8] = {0.f, 0.f, 0.f, 0.f, 0.f, 0.f, 0.f, 0.f};
    for (int e0 = start; e0 < end; e0 += 8) {
        int eA = e0 + sub;
        int eB = e0 + 4 + sub;
        if (eA < end) {
            int s = col[eA];
            uint4 v = *reinterpret_cast<const uint4*>(Xl + (size_t)s * HID);
            a[0] += bf2f((unsigned short)(v.x & 0xffffu));
            a[1] += bf2f((unsigned short)(v.x >> 16));
            a[2] += bf2f((unsigned short)(v.y & 0xffffu));
            a[3] += bf2f((unsigned short)(v.y >> 16));
            a[4] += bf2f((unsigned short)(v.z & 0xffffu));
            a[5] += bf2f((unsigned short)(v.z >> 16));
            a[6] += bf2f((unsigned short)(v.w & 0xffffu));
            a[7] += bf2f((unsigned short)(v.w >> 16));
        }
        if (eB < end) {
            int s = col[eB];
            uint4 v = *reinterpret_cast<const uint4*>(Xl + (size_t)s * HID);
            b[0] += bf2f((unsigned short)(v.x & 0xffffu));
            b[1] += bf2f((unsigned short)(v.x >> 16));
            b[2] += bf2f((unsigned short)(v.y & 0xffffu));
            b[3] += bf2f((unsigned short)(v.y >> 16));
            b[4] += bf2f((unsigned short)(v.z & 0xffffu));
            b[5] += bf2f((unsigned short)(v.z >> 16));
            b[6] += bf2f((unsigned short)(v.w & 0xffffu));
            b[7] += bf2f((unsigned short)(v.w >> 16));
        }
    }
#pragma unroll
    for (int k = 0; k < 8; ++k) {
        a[k] += b[k];
        a[k] += __shfl_xor(a[k], 16, 64);
        a[k] += __shfl_xor(a[k], 32, 64);
    }

    if (sub == 0) {
        float inv = 1.0f / (float)max(end - start, 1);
        uint4 o;
        o.x = (unsigned)f2bf(a[0] * inv) | ((unsigned)f2bf(a[1] * inv) << 16);
        o.y = (unsigned)f2bf(a[2] * inv) | ((unsigned)f2bf(a[3] * inv) << 16);
        o.z = (unsigned)f2bf(a[4] * inv) | ((unsigned)f2bf(a[5] * inv) << 16);
        o.w = (unsigned)f2bf(a[6] * inv) | ((unsigned)f2bf(a[7] * inv) << 16);
        *reinterpret_cast<uint4*>(M + (size_t)wid * HID + cl * 8) = o;
    }
}

// ---------------------------------------------------------------------------
// CSR mean-aggregation, 64-col rows (pre-transformed Z). sub/cl layout,
// uint2 (8B) per lane, 16 lanes = 128B row, 8 edges in flight.
// ---------------------------------------------------------------------------
__global__ __launch_bounds__(256) void agg3_64(
    const int* __restrict__ o0, const int* __restrict__ c0,
    const unsigned short* __restrict__ X0, unsigned short* __restrict__ M0, int n0,
    const int* __restrict__ o1, const int* __restrict__ c1,
    const unsigned short* __restrict__ X1, unsigned short* __restrict__ M1, int n1,
    const int* __restrict__ o2, const int* __restrict__ c2,
    const unsigned short* __restrict__ X2, unsigned short* __restrict__ M2, int n2)
{
    int wid = (blockIdx.x * blockDim.x + threadIdx.x) >> 6;
    const int lane = threadIdx.x & 63;
    const int sub = lane >> 4;
    const int cl  = lane & 15;

    const int* offs; const int* col;
    const unsigned short* X; unsigned short* M;
    if (wid < n0) { offs = o0; col = c0; X = X0; M = M0; }
    else if (wid < n0 + n1) { wid -= n0; offs = o1; col = c1; X = X1; M = M1; }
    else { wid -= n0 + n1; if (wid >= n2) return; offs = o2; col = c2; X = X2; M = M2; }

    const int start = offs[wid];
    const int end = offs[wid + 1];
    const unsigned short* Xl = X + cl * 4;

    float a[4] = {0.f, 0.f, 0.f, 0.f};
    float b[4] = {0.f, 0.f, 0.f, 0.f};
    for (int e0 = start; e0 < end; e0 += 8) {
        int eA = e0 + sub;
        int eB = e0 + 4 + sub;
        if (eA < end) {
            int s = col[eA];
            uint2 v = *reinterpret_cast<const uint2*>(Xl + (size_t)s * OUTD);
            a[0] += bf2f((unsigned short)(v.x & 0xffffu));
            a[1] += bf2f((unsigned short)(v.x >> 16));
            a[2] += bf2f((unsigned short)(v.y & 0xffffu));
            a[3] += bf2f((unsigned short)(v.y >> 16));
        }
        if (eB < end) {
            int s = col[eB];
            uint2 v = *reinterpret_cast<const uint2*>(Xl + (size_t)s * OUTD);
            b[0] += bf2f((unsigned short)(v.x & 0xffffu));
            b[1] += bf2f((unsigned short)(v.x >> 16));
            b[2] += bf2f((unsigned short)(v.y & 0xffffu));
            b[3] += bf2f((unsigned short)(v.y >> 16));
        }
    }
#pragma unroll
    for (int k = 0; k < 4; ++k) {
        a[k] += b[k];
        a[k] += __shfl_xor(a[k], 16, 64);
        a[k] += __shfl_xor(a[k], 32, 64);
    }

    if (sub == 0) {
        float inv = 1.0f / (float)max(end - start, 1);
        uint2 o;
        o.x = (unsigned)f2bf(a[0] * inv) | ((unsigned)f2bf(a[1] * inv) << 16);
        o.y = (unsigned)f2bf(a[2] * inv) | ((unsigned)f2bf(a[3] * inv) << 16);
        *reinterpret_cast<uint2*>(M + (size_t)wid * OUTD + cl * 4) = o;
    }
}

// ---------------------------------------------------------------------------
// Fused transform: Z = H @ Wl (first half of Wt), CO=64, K=128. 3 sections.
// ---------------------------------------------------------------------------
__global__ __launch_bounds__(256) void xform3(
    const unsigned short* __restrict__ H0, const unsigned short* __restrict__ W0,
    unsigned short* __restrict__ Z0, int n0,
    const unsigned short* __restrict__ H1, const unsigned short* __restrict__ W1,
    unsigned short* __restrict__ Z1, int n1,
    const unsigned short* __restrict__ H2, const unsigned short* __restrict__ W2,
    unsigned short* __restrict__ Z2, int n2)
{
    const int b0 = (n0 + 63) / 64, b1 = (n1 + 63) / 64;
    int b = blockIdx.x;
    const unsigned short *H, *W; unsigned short* Z; int n;
    if (b < b0) { H = H0; W = W0; Z = Z0; n = n0; }
    else if (b < b0 + b1) { b -= b0; H = H1; W = W1; Z = Z1; n = n1; }
    else { b -= b0 + b1; H = H2; W = W2; Z = Z2; n = n2; }

    constexpr int NT = OUTD / 16;
    const int wave = threadIdx.x >> 6;
    const int lane = threadIdx.x & 63;
    const int r16 = lane & 15;
    const int chunk = lane >> 4;
    const int rowbase = b * 64 + wave * 16;
    if (rowbase >= n) return;

    const int arow = min(rowbase + r16, n - 1);
    const unsigned short* hrow = H + (size_t)arow * HID;

    bf16x8 a[4];
#pragma unroll
    for (int s = 0; s < 4; ++s)
        a[s] = *reinterpret_cast<const bf16x8*>(hrow + s * 32 + chunk * 8);

    f32x4 acc[NT];
#pragma unroll
    for (int t = 0; t < NT; ++t) acc[t] = f32x4{0.f, 0.f, 0.f, 0.f};

#pragma unroll
    for (int t = 0; t < NT; ++t) {
        const unsigned short* w_ = W + (size_t)(t * 16 + r16) * 256;
#pragma unroll
        for (int s = 0; s < 4; ++s) {
            bf16x8 bfrag = *reinterpret_cast<const bf16x8*>(w_ + s * 32 + chunk * 8);
            acc[t] = __builtin_amdgcn_mfma_f32_16x16x32_bf16(a[s], bfrag, acc[t], 0, 0, 0);
        }
    }

#pragma unroll
    for (int r = 0; r < 4; ++r) {
        int node = rowbase + chunk * 4 + r;
        if (node < n) {
#pragma unroll
            for (int t = 0; t < NT; ++t)
                Z[(size_t)node * OUTD + t * 16 + r16] = f2bf(acc[t][r]);
        }
    }
}

// ---------------------------------------------------------------------------
// Layer-0 SAGE kernels (K=256 over [mean|x]).
// C/D layout: col = lane&15, row = (lane>>4)*4 + reg   [verified m89]
// ---------------------------------------------------------------------------
template <int CO>
__global__ __launch_bounds__(256) void sage_mfma(
    const unsigned short* __restrict__ Mb,
    const unsigned short* __restrict__ Xb,
    const unsigned short* __restrict__ Wt,
    const float* __restrict__ bl,
    float* __restrict__ H, int n)
{
    constexpr int NT = CO / 16;
    const int wave = threadIdx.x >> 6;
    const int lane = threadIdx.x & 63;
    const int r16 = lane & 15;
    const int chunk = lane >> 4;
    const int rowbase = blockIdx.x * 64 + wave * 16;
    if (rowbase >= n) return;

    const int arow = min(rowbase + r16, n - 1);
    const unsigned short* mrow = Mb + (size_t)arow * HID;
    const unsigned short* xrow = Xb + (size_t)arow * HID;

    bf16x8 a[8];
#pragma unroll
    for (int s = 0; s < 4; ++s) {
        a[s]     = *reinterpret_cast<const bf16x8*>(mrow + s * 32 + chunk * 8);
        a[4 + s] = *reinterpret_cast<const bf16x8*>(xrow + s * 32 + chunk * 8);
    }

    f32x4 acc[NT];
#pragma unroll
    for (int t = 0; t < NT; ++t) acc[t] = f32x4{0.f, 0.f, 0.f, 0.f};

#pragma unroll
    for (int t = 0; t < NT; ++t) {
        const unsigned short* wr_ = Wt + (size_t)(t * 16 + r16) * 256;
#pragma unroll
        for (int s = 0; s < 8; ++s) {
            bf16x8 b = *reinterpret_cast<const bf16x8*>(wr_ + s * 32 + chunk * 8);
            acc[t] = __builtin_amdgcn_mfma_f32_16x16x32_bf16(a[s], b, acc[t], 0, 0, 0);
        }
    }

    float ss[4] = {0.f, 0.f, 0.f, 0.f};
#pragma unroll
    for (int t = 0; t < NT; ++t) {
        float bias = bl[t * 16 + r16];
#pragma unroll
        for (int r = 0; r < 4; ++r) {
            acc[t][r] += bias;
            ss[r] += acc[t][r] * acc[t][r];
        }
    }
#pragma unroll
    for (int r = 0; r < 4; ++r)
#pragma unroll
        for (int m = 1; m < 16; m <<= 1)
            ss[r] += __shfl_xor(ss[r], m, 64);

#pragma unroll
    for (int r = 0; r < 4; ++r) {
        int node = rowbase + chunk * 4 + r;
        if (node < n) {
            float inv = 1.0f / fmaxf(sqrtf(ss[r]), 1e-12f);
#pragma unroll
            for (int t = 0; t < NT; ++t)
                H[(size_t)node * CO + t * 16 + r16] = acc[t][r] * inv;
        }
    }
}

template <int CO>
__global__ __launch_bounds__(256) void sage2_mfma(
    const unsigned short* __restrict__ MbA,
    const unsigned short* __restrict__ MbB,
    const unsigned short* __restrict__ Xb,
    const unsigned short* __restrict__ WtA,
    const unsigned short* __restrict__ WtB,
    const float* __restrict__ blA, const float* __restrict__ blB,
    float* __restrict__ H, int n)
{
    constexpr int NT = CO / 16;
    const int wave = threadIdx.x >> 6;
    const int lane = threadIdx.x & 63;
    const int r16 = lane & 15;
    const int chunk = lane >> 4;
    const int rowbase = blockIdx.x * 64 + wave * 16;
    if (rowbase >= n) return;

    const int arow = min(rowbase + r16, n - 1);
    const unsigned short* marow = MbA + (size_t)arow * HID;
    const unsigned short* mbrow = MbB + (size_t)arow * HID;
    const unsigned short* xrow  = Xb  + (size_t)arow * HID;

    bf16x8 aA[4], aB[4], ax[4];
#pragma unroll
    for (int s = 0; s < 4; ++s) {
        aA[s] = *reinterpret_cast<const bf16x8*>(marow + s * 32 + chunk * 8);
        aB[s] = *reinterpret_cast<const bf16x8*>(mbrow + s * 32 + chunk * 8);
        ax[s] = *reinterpret_cast<const bf16x8*>(xrow  + s * 32 + chunk * 8);
    }

    f32x4 accA[NT], accB[NT];
#pragma unroll
    for (int t = 0; t < NT; ++t) {
        accA[t] = f32x4{0.f, 0.f, 0.f, 0.f};
        accB[t] = f32x4{0.f, 0.f, 0.f, 0.f};
    }

#pragma unroll
    for (int t = 0; t < NT; ++t) {
        const unsigned short* wA = WtA + (size_t)(t * 16 + r16) * 256;
        const unsigned short* wB = WtB + (size_t)(t * 16 + r16) * 256;
#pragma unroll
        for (int s = 0; s < 4; ++s) {
            bf16x8 b0 = *reinterpret_cast<const bf16x8*>(wA + s * 32 + chunk * 8);
            accA[t] = __builtin_amdgcn_mfma_f32_16x16x32_bf16(aA[s], b0, accA[t], 0, 0, 0);
            bf16x8 b1 = *reinterpret_cast<const bf16x8*>(wA + HID + s * 32 + chunk * 8);
            accA[t] = __builtin_amdgcn_mfma_f32_16x16x32_bf16(ax[s], b1, accA[t], 0, 0, 0);
            bf16x8 b2 = *reinterpret_cast<const bf16x8*>(wB + s * 32 + chunk * 8);
            accB[t] = __builtin_amdgcn_mfma_f32_16x16x32_bf16(aB[s], b2, accB[t], 0, 0, 0);
            bf16x8 b3 = *reinterpret_cast<const bf16x8*>(wB + HID + s * 32 + chunk * 8);
            accB[t] = __builtin_amdgcn_mfma_f32_16x16x32_bf16(ax[s], b3, accB[t], 0, 0, 0);
        }
    }

    float ssA[4] = {0.f, 0.f, 0.f, 0.f};
    float ssB[4] = {0.f, 0.f, 0.f, 0.f};
#pragma unroll
    for (int t = 0; t < NT; ++t) {
        float biasA = blA[t * 16 + r16];
        float biasB = blB[t * 16 + r16];
#pragma unroll
        for (int r = 0; r < 4; ++r) {
            accA[t][r] += biasA;
            ssA[r] += accA[t][r] * accA[t][r];
            accB[t][r] += biasB;
            ssB[r] += accB[t][r] * accB[t][r];
        }
    }
#pragma unroll
    for (int r = 0; r < 4; ++r)
#pragma unroll
        for (int m = 1; m < 16; m <<= 1) {
            ssA[r] += __shfl_xor(ssA[r], m, 64);
            ssB[r] += __shfl_xor(ssB[r], m, 64);
        }

#pragma unroll
    for (int r = 0; r < 4; ++r) {
        int node = rowbase + chunk * 4 + r;
        if (node < n) {
            float invA = 1.0f / fmaxf(sqrtf(ssA[r]), 1e-12f);
            float invB = 1.0f / fmaxf(sqrtf(ssB[r]), 1e-12f);
#pragma unroll
            for (int t = 0; t < NT; ++t)
                H[(size_t)node * CO + t * 16 + r16] =
                    accA[t][r] * invA + accB[t][r] * invB;
        }
    }
}

// ---------------------------------------------------------------------------
// Layer-1 SAGE with pre-aggregated meanZ (= mean@Wl): only x@Wr via MFMA.
// ---------------------------------------------------------------------------
__global__ __launch_bounds__(256) void sage2z(
    const unsigned short* __restrict__ MZa,
    const unsigned short* __restrict__ MZb,
    const unsigned short* __restrict__ Xb,
    const unsigned short* __restrict__ WtA,
    const unsigned short* __restrict__ WtB,
    const float* __restrict__ blA, const float* __restrict__ blB,
    float* __restrict__ H, int n)
{
    constexpr int NT = OUTD / 16;
    const int wave = threadIdx.x >> 6;
    const int lane = threadIdx.x & 63;
    const int r16 = lane & 15;
    const int chunk = lane >> 4;
    const int rowbase = blockIdx.x * 64 + wave * 16;
    if (rowbase >= n) return;

    const int arow = min(rowbase + r16, n - 1);
    const unsigned short* xrow = Xb + (size_t)arow * HID;

    bf16x8 ax[4];
#pragma unroll
    for (int s = 0; s < 4; ++s)
        ax[s] = *reinterpret_cast<const bf16x8*>(xrow + s * 32 + chunk * 8);

    f32x4 accA[NT], accB[NT];
#pragma unroll
    for (int t = 0; t < NT; ++t) {
        accA[t] = f32x4{0.f, 0.f, 0.f, 0.f};
        accB[t] = f32x4{0.f, 0.f, 0.f, 0.f};
    }

#pragma unroll
    for (int t = 0; t < NT; ++t) {
        const unsigned short* wA = WtA + (size_t)(t * 16 + r16) * 256 + HID;
        const unsigned short* wB = WtB + (size_t)(t * 16 + r16) * 256 + HID;
#pragma unroll
        for (int s = 0; s < 4; ++s) {
            bf16x8 b0 = *reinterpret_cast<const bf16x8*>(wA + s * 32 + chunk * 8);
            accA[t] = __builtin_amdgcn_mfma_f32_16x16x32_bf16(ax[s], b0, accA[t], 0, 0, 0);
            bf16x8 b1 = *reinterpret_cast<const bf16x8*>(wB + s * 32 + chunk * 8);
            accB[t] = __builtin_amdgcn_mfma_f32_16x16x32_bf16(ax[s], b1, accB[t], 0, 0, 0);
        }
    }

    float ssA[4] = {0.f, 0.f, 0.f, 0.f};
    float ssB[4] = {0.f, 0.f, 0.f, 0.f};
#pragma unroll
    for (int r = 0; r < 4; ++r) {
        int cl = min(rowbase + chunk * 4 + r, n - 1);
#pragma unroll
        for (int t = 0; t < NT; ++t) {
            int j = t * 16 + r16;
            float vA = accA[t][r] + blA[j] + bf2f(MZa[(size_t)cl * OUTD + j]);
            accA[t][r] = vA;
            ssA[r] += vA * vA;
            float vB = accB[t][r] + blB[j] + bf2f(MZb[(size_t)cl * OUTD + j]);
            accB[t][r] = vB;
            ssB[r] += vB * vB;
        }
    }
#pragma unroll
    for (int r = 0; r < 4; ++r)
#pragma unroll
        for (int m = 1; m < 16; m <<= 1) {
            ssA[r] += __shfl_xor(ssA[r], m, 64);
            ssB[r] += __shfl_xor(ssB[r], m, 64);
        }

#pragma unroll
    for (int r = 0; r < 4; ++r) {
        int node = rowbase + chunk * 4 + r;
        if (node < n) {
            float invA = 1.0f / fmaxf(sqrtf(ssA[r]), 1e-12f);
            float invB = 1.0f / fmaxf(sqrtf(ssB[r]), 1e-12f);
#pragma unroll
            for (int t = 0; t < NT; ++t)
                H[(size_t)node * OUTD + t * 16 + r16] =
                    accA[t][r] * invA + accB[t][r] * invB;
        }
    }
}

__global__ __launch_bounds__(256) void sagez(
    const unsigned short* __restrict__ MZ,
    const unsigned short* __restrict__ Xb,
    const unsigned short* __restrict__ Wt,
    const float* __restrict__ bl,
    float* __restrict__ H, int n)
{
    constexpr int NT = OUTD / 16;
    const int wave = threadIdx.x >> 6;
    const int lane = threadIdx.x & 63;
    const int r16 = lane & 15;
    const int chunk = lane >> 4;
    const int rowbase = blockIdx.x * 64 + wave * 16;
    if (rowbase >= n) return;

    const int arow = min(rowbase + r16, n - 1);
    const unsigned short* xrow = Xb + (size_t)arow * HID;

    bf16x8 ax[4];
#pragma unroll
    for (int s = 0; s < 4; ++s)
        ax[s] = *reinterpret_cast<const bf16x8*>(xrow + s * 32 + chunk * 8);

    f32x4 acc[NT];
#pragma unroll
    for (int t = 0; t < NT; ++t) acc[t] = f32x4{0.f, 0.f, 0.f, 0.f};

#pragma unroll
    for (int t = 0; t < NT; ++t) {
        const unsigned short* w_ = Wt + (size_t)(t * 16 + r16) * 256 + HID;
#pragma unroll
        for (int s = 0; s < 4; ++s) {
            bf16x8 b = *reinterpret_cast<const bf16x8*>(w_ + s * 32 + chunk * 8);
            acc[t] = __builtin_amdgcn_mfma_f32_16x16x32_bf16(ax[s], b, acc[t], 0, 0, 0);
        }
    }

    float ss[4] = {0.f, 0.f, 0.f, 0.f};
#pragma unroll
    for (int r = 0; r < 4; ++r) {
        int cl = min(rowbase + chunk * 4 + r, n - 1);
#pragma unroll
        for (int t = 0; t < NT; ++t) {
            int j = t * 16 + r16;
            float v = acc[t][r] + bl[j] + bf2f(MZ[(size_t)cl * OUTD + j]);
            acc[t][r] = v;
            ss[r] += v * v;
        }
    }
#pragma unroll
    for (int r = 0; r < 4; ++r)
#pragma unroll
        for (int m = 1; m < 16; m <<= 1)
            ss[r] += __shfl_xor(ss[r], m, 64);

#pragma unroll
    for (int r = 0; r < 4; ++r) {
        int node = rowbase + chunk * 4 + r;
        if (node < n) {
            float inv = 1.0f / fmaxf(sqrtf(ss[r]), 1e-12f);
#pragma unroll
            for (int t = 0; t < NT; ++t)
                H[(size_t)node * OUTD + t * 16 + r16] = acc[t][r] * inv;
        }
    }
}

// ---------------------------------------------------------------------------
// Fused LayerNorm over 2 tensors (sections), one wave per row.
// ---------------------------------------------------------------------------
template <int D, bool RELU, bool OUTBF>
__global__ __launch_bounds__(256) void ln2_kernel(
    const float* __restrict__ X1, const float* __restrict__ g1,
    const float* __restrict__ b1, void* __restrict__ out1, int n1,
    const float* __restrict__ X2, const float* __restrict__ g2,
    const float* __restrict__ b2, void* __restrict__ out2, int n2)
{
    constexpr int VPL = D / 64;
    int wid = (blockIdx.x * blockDim.x + threadIdx.x) >> 6;
    int lane = threadIdx.x & 63;
    const float *X, *gg, *bb; void* outp; int n;
    if (wid < n1) { X = X1; gg = g1; bb = b1; outp = out1; n = n1; }
    else { wid -= n1; if (wid >= n2) return; X = X2; gg = g2; bb = b2; outp = out2; n = n2; }

    float v[VPL], gv[VPL], bv[VPL];
    const float* xp = X + (size_t)wid * D + lane * VPL;
#pragma unroll
    for (int k = 0; k < VPL; ++k) {
        v[k] = xp[k];
        gv[k] = gg[lane * VPL + k];
        bv[k] = bb[lane * VPL + k];
    }
    float s = 0.f;
#pragma unroll
    for (int k = 0; k < VPL; ++k) s += v[k];
#pragma unroll
    for (int off = 32; off > 0; off >>= 1) s += __shfl_xor(s, off, 64);
    float m = s / D;
    float ss = 0.f;
#pragma unroll
    for (int k = 0; k < VPL; ++k) { float d = v[k] - m; ss += d * d; }
#pragma unroll
    for (int off = 32; off > 0; off >>= 1) ss += __shfl_xor(ss, off, 64);
    float rstd = rsqrtf(ss / D + 1e-5f);

    float y[VPL];
#pragma unroll
    for (int k = 0; k < VPL; ++k) {
        y[k] = gv[k] * (v[k] - m) * rstd + bv[k];
        if (RELU) y[k] = fmaxf(y[k], 0.f);
    }
    if (OUTBF) {
        unsigned short* op = (unsigned short*)outp + (size_t)wid * D + lane * VPL;
#pragma unroll
        for (int k = 0; k < VPL; ++k) op[k] = f2bf(y[k]);
    } else {
        float* op = (float*)outp + (size_t)wid * D + lane * VPL;
#pragma unroll
        for (int k = 0; k < VPL; ++k) op[k] = y[k];
    }
}

// ---------------------------------------------------------------------------
extern "C" void kernel_launch(void* const* d_in, const int* in_sizes, int n_in,
                              void* d_out, int out_size, void* d_ws, size_t ws_size,
                              hipStream_t stream)
{
    const int*   x_drug   = (const int*)d_in[0];
    const int*   x_dis    = (const int*)d_in[1];
    const float* emb_drug = (const float*)d_in[2];
    const float* emb_dis  = (const float*)d_in[3];
    const int*   src_dd   = (const int*)d_in[4];
    const int*   dst_dd   = (const int*)d_in[5];
    const int*   src_td   = (const int*)d_in[6];
    const int*   dst_td   = (const int*)d_in[7];
    const int*   src_rd   = (const int*)d_in[8];
    const int*   dst_rd   = (const int*)d_in[9];
    const float* Wl0_dd = (const float*)d_in[10];
    const float* bl0_dd = (const float*)d_in[11];
    const float* Wr0_dd = (const float*)d_in[12];
    const float* Wl0_td = (const float*)d_in[13];
    const float* bl0_td = (const float*)d_in[14];
    const float* Wr0_td = (const float*)d_in[15];
    const float* Wl0_rd = (const float*)d_in[16];
    const float* bl0_rd = (const float*)d_in[17];
    const float* Wr0_rd = (const float*)d_in[18];
    const float* Wl1_dd = (const float*)d_in[19];
    const float* bl1_dd = (const float*)d_in[20];
    const float* Wr1_dd = (const float*)d_in[21];
    const float* Wl1_td = (const float*)d_in[22];
    const float* bl1_td = (const float*)d_in[23];
    const float* Wr1_td = (const float*)d_in[24];
    const float* Wl1_rd = (const float*)d_in[25];
    const float* bl1_rd = (const float*)d_in[26];
    const float* Wr1_rd = (const float*)d_in[27];
    const float* g0_drug = (const float*)d_in[28];
    const float* b0_drug = (const float*)d_in[29];
    const float* g0_dis  = (const float*)d_in[30];
    const float* b0_dis  = (const float*)d_in[31];
    const float* g1_drug = (const float*)d_in[32];
    const float* b1_drug = (const float*)d_in[33];
    const float* g1_dis  = (const float*)d_in[34];
    const float* b1_dis  = (const float*)d_in[35];

    // ---------------- workspace layout ----------------
    char* wp = (char*)d_ws;
    auto alloc = [&](size_t bytes) { char* p = wp; wp += (bytes + 255) & ~size_t(255); return p; };

    unsigned short* hd0  = (unsigned short*)alloc((size_t)ND * HID * 2);
    unsigned short* hz0  = (unsigned short*)alloc((size_t)NZ * HID * 2);
    unsigned short* hd1b = (unsigned short*)alloc((size_t)ND * HID * 2);
    unsigned short* hz1b = (unsigned short*)alloc((size_t)NZ * HID * 2);
    unsigned short* meanA= (unsigned short*)alloc((size_t)ND * HID * 2);
    unsigned short* meanB= (unsigned short*)alloc((size_t)ND * HID * 2);
    unsigned short* meanC= (unsigned short*)alloc((size_t)NZ * HID * 2);
    unsigned short* Zdd  = (unsigned short*)alloc((size_t)ND * OUTD * 2);
    unsigned short* Zrd  = (unsigned short*)alloc((size_t)NZ * OUTD * 2);
    unsigned short* Ztd  = (unsigned short*)alloc((size_t)ND * OUTD * 2);
    float* hd1f = (float*)alloc((size_t)ND * HID * 4);
    float* hz1f = (float*)alloc((size_t)NZ * HID * 4);
    unsigned short* Wt0_dd = (unsigned short*)alloc((size_t)HID * 256 * 2);
    unsigned short* Wt0_rd = (unsigned short*)alloc((size_t)HID * 256 * 2);
    unsigned short* Wt0_td = (unsigned short*)alloc((size_t)HID * 256 * 2);
    unsigned short* Wt1_dd = (unsigned short*)alloc((size_t)OUTD * 256 * 2);
    unsigned short* Wt1_rd = (unsigned short*)alloc((size_t)OUTD * 256 * 2);
    unsigned short* Wt1_td = (unsigned short*)alloc((size_t)OUTD * 256 * 2);
    int* offs_dd = (int*)alloc((ND + 1) * 4);
    int* offs_rd = (int*)alloc((ND + 1) * 4);
    int* offs_td = (int*)alloc((NZ + 1) * 4);
    int* col_dd  = (int*)alloc((size_t)E * 4);
    int* col_rd  = (int*)alloc((size_t)E * 4);
    int* col_td  = (int*)alloc((size_t)E * 4);
    int* cnt_dd  = (int*)alloc(((size_t)(ND + 1) + (ND + 1) + (NZ + 1)) * 4);
    int* cnt_rd  = cnt_dd + (ND + 1);
    int* cnt_td  = cnt_rd + (ND + 1);
    int* part    = (int*)alloc(3 * 64 * 4);
    int* rc      = (int*)alloc(3 * CHK * 8 * 4);
    int* wpos    = (int*)alloc(3 * CHK * 8 * 4);
    int* rbase   = (int*)alloc(3 * 9 * 4);

    int2* bkt_dd = (int2*)hd1f;
    int2* bkt_rd = bkt_dd + E;
    int2* bkt_td = (int2*)hz1f;
    int* partial = (int*)meanA;

    float* outD = (float*)d_out;
    float* outZ = outD + (size_t)ND * OUTD;

    // ---------------- independent prep ----------------
    gather_all<<<ceil_div((ND + NZ) * 32, 256), 256, 0, stream>>>(
        emb_drug, x_drug, emb_dis, x_dis, hd0, hz0);

    PrepArgs pa;
    pa.wl[0] = Wl0_dd; pa.wr[0] = Wr0_dd; pa.wt[0] = Wt0_dd; pa.co[0] = HID;
    pa.wl[1] = Wl0_rd; pa.wr[1] = Wr0_rd; pa.wt[1] = Wt0_rd; pa.co[1] = HID;
    pa.wl[2] = Wl0_td; pa.wr[2] = Wr0_td; pa.wt[2] = Wt0_td; pa.co[2] = HID;
    pa.wl[3] = Wl1_dd; pa.wr[3] = Wr1_dd; pa.wt[3] = Wt1_dd; pa.co[3] = OUTD;
    pa.wl[4] = Wl1_rd; pa.wr[4] = Wr1_rd; pa.wt[4] = Wt1_rd; pa.co[4] = OUTD;
    pa.wl[5] = Wl1_td; pa.wr[5] = Wr1_td; pa.wt[5] = Wt1_td; pa.co[5] = OUTD;
    pa.boff[0] = 0;
    for (int s = 0; s < 6; ++s) pa.boff[s + 1] = pa.boff[s] + pa.co[s];
    prep_all<<<pa.boff[6], 256, 0, stream>>>(pa);

    // ---------------- bucketed CSR build (NO global atomics) ----------------
    bcount<<<3 * CHK, 256, 0, stream>>>(dst_dd, dst_rd, dst_td, rc);
    bscan<<<1, 256, 0, stream>>>(rc, wpos, rbase);
    bscatter<<<3 * CHK, 256, 0, stream>>>(
        src_dd, dst_dd, src_rd, dst_rd, src_td, dst_td,
        wpos, bkt_dd, bkt_rd, bkt_td);
    bcount2<<<NXCD * 3 * SSUB, 256, 0, stream>>>(
        bkt_dd, bkt_rd, bkt_td, rbase, partial);
    sumcnt<<<ceil_div(2 * ND + NZ, 256), 256, 0, stream>>>(
        partial, cnt_dd, cnt_rd, cnt_td);
    scan_part3<<<2 * NB_D + NB_Z, 256, 0, stream>>>(cnt_dd, cnt_rd, cnt_td, part);
    scan_small3<<<3, 64, 0, stream>>>(part, offs_dd, offs_rd, offs_td);
    scan_write3<<<2 * NB_D + NB_Z, 256, 0, stream>>>(
        cnt_dd, cnt_rd, cnt_td, part, offs_dd, offs_rd, offs_td);
    basek<<<ceil_div(2 * ND + NZ, 256), 256, 0, stream>>>(
        partial, offs_dd, offs_rd, offs_td);
    bfill2<<<NXCD * 3 * SSUB, 256, 0, stream>>>(
        bkt_dd, bkt_rd, bkt_td, rbase, partial, col_dd, col_rd, col_td);

    // ---------------- layer 0 ----------------
    agg3_128<<<ceil_div((2 * ND + NZ) * 64, 256), 256, 0, stream>>>(
        offs_dd, col_dd, hd0, meanA, ND,
        offs_rd, col_rd, hz0, meanB, ND,
        offs_td, col_td, hd0, meanC, NZ);
    sage2_mfma<HID><<<ceil_div(ND, 64), 256, 0, stream>>>(
        meanA, meanB, hd0, Wt0_dd, Wt0_rd, bl0_dd, bl0_rd, hd1f, ND);
    sage_mfma<HID><<<ceil_div(NZ, 64), 256, 0, stream>>>(
        meanC, hz0, Wt0_td, bl0_td, hz1f, NZ);

    ln2_kernel<HID, true, true><<<ceil_div(ND + NZ, 4), 256, 0, stream>>>(
        hd1f, g0_drug, b0_drug, hd1b, ND,
        hz1f, g0_dis, b0_dis, hz1b, NZ);

    // ---------------- layer 1 (transform-then-aggregate) ----------------
    xform3<<<ceil_div(ND, 64) * 2 + ceil_div(NZ, 64), 256, 0, stream>>>(
        hd1b, Wt1_dd, Zdd, ND,
        hz1b, Wt1_rd, Zrd, NZ,
        hd1b, Wt1_td, Ztd, ND);

    agg3_64<<<ceil_div((2 * ND + NZ) * 64, 256), 256, 0, stream>>>(
        offs_dd, col_dd, Zdd, meanA, ND,
        offs_rd, col_rd, Zrd, meanB, ND,
        offs_td, col_td, Ztd, meanC, NZ);

    sage2z<<<ceil_div(ND, 64), 256, 0, stream>>>(
        meanA, meanB, hd1b, Wt1_dd, Wt1_rd, bl1_dd, bl1_rd, outD, ND);
    sagez<<<ceil_div(NZ, 64), 256, 0, stream>>>(
        meanC, hz1b, Wt1_td, bl1_td, outZ, NZ);

    ln2_kernel<OUTD, false, false><<<ceil_div(ND + NZ, 4), 256, 0, stream>>>(
        outD, g1_drug, b1_drug, outD, ND,
        outZ, g1_dis, b1_dis, outZ, NZ);
}

// Round 14
// 479.177 us; speedup vs baseline: 2.2267x; 1.0089x over previous
//
#include <hip/hip_runtime.h>

// Problem constants (match reference setup_inputs)
constexpr int ND   = 50000;
constexpr int NZ   = 20000;
constexpr int HID  = 128;
constexpr int OUTD = 64;
constexpr int E    = 1000000;

constexpr int SCAN_TILE = 1024;
constexpr int NB_D = (ND + SCAN_TILE - 1) / SCAN_TILE;   // 49
constexpr int NB_Z = (NZ + SCAN_TILE - 1) / SCAN_TILE;   // 20
constexpr int NXCD = 8;
constexpr int CHK  = 96;     // edge chunks per list (bucket build)
constexpr int SSUB = 8;      // slices per (list,range) in count/fill
constexpr int RN_D = ND / NXCD;   // 6250
constexpr int RN_Z = NZ / NXCD;   // 2500
constexpr int PB1 = NXCD * SSUB * RN_D;
constexpr int PB2 = PB1 + NXCD * SSUB * RN_D;
constexpr int PTOT = PB2 + NXCD * SSUB * RN_Z;

static inline int ceil_div(int a, int b) { return (a + b - 1) / b; }

typedef __bf16 bf16x8 __attribute__((ext_vector_type(8)));
typedef float  f32x4  __attribute__((ext_vector_type(4)));

__device__ __forceinline__ float bf2f(unsigned short b) {
    return __uint_as_float(((unsigned int)b) << 16);
}
__device__ __forceinline__ unsigned short f2bf(float f) {
    unsigned int u = __float_as_uint(f);
    unsigned int r = (u + 0x7fffu + ((u >> 16) & 1u)) >> 16;
    return (unsigned short)r;
}

// ---------------------------------------------------------------------------
// Fused gather + weight prep (sections by blockIdx)
// ---------------------------------------------------------------------------
struct PrepArgs {
    const float* wl[6];
    const float* wr[6];
    unsigned short* wt[6];
    int co[6];
    int boff[7];
};

__global__ __launch_bounds__(256) void gather_prep(
    const float* __restrict__ emb_d, const int* __restrict__ idx_d,
    const float* __restrict__ emb_z, const int* __restrict__ idx_z,
    unsigned short* __restrict__ out_d, unsigned short* __restrict__ out_z,
    int gblocks, PrepArgs a)
{
    if ((int)blockIdx.x < gblocks) {
        int t = blockIdx.x * blockDim.x + threadIdx.x;
        int row = t >> 5;
        int c = (t & 31) * 4;
        if (row >= ND + NZ) return;
        const float* src;
        unsigned short* dst;
        if (row < ND) {
            src = emb_d + (size_t)idx_d[row] * HID;
            dst = out_d + (size_t)row * HID;
        } else {
            int r2 = row - ND;
            src = emb_z + (size_t)idx_z[r2] * HID;
            dst = out_z + (size_t)r2 * HID;
        }
        float4 v = *reinterpret_cast<const float4*>(src + c);
        ushort4 o;
        o.x = f2bf(v.x); o.y = f2bf(v.y); o.z = f2bf(v.z); o.w = f2bf(v.w);
        *reinterpret_cast<ushort4*>(dst + c) = o;
        return;
    }
    int pb = blockIdx.x - gblocks;
    int sec = 0;
#pragma unroll
    for (int s = 0; s < 6; ++s)
        if (pb >= a.boff[s + 1]) sec = s + 1;
    int CO = a.co[sec];
    int idx = (pb - a.boff[sec]) * 256 + threadIdx.x;
    int j = idx >> 8;
    int k = idx & 255;
    float v = (k < HID) ? a.wl[sec][k * CO + j] : a.wr[sec][(k - HID) * CO + j];
    a.wt[sec][(size_t)j * 256 + k] = f2bf(v);
}

// ---------------------------------------------------------------------------
// Bucketed CSR build, phase 1: per-(list,chunk) range histogram (LDS)
// ---------------------------------------------------------------------------
__global__ __launch_bounds__(256) void bcount(
    const int* __restrict__ d0, const int* __restrict__ d1, const int* __restrict__ d2,
    int* __restrict__ rc)
{
    __shared__ int lc[8];
    const int list = blockIdx.x / CHK;
    const int chunk = blockIdx.x % CHK;
    if (threadIdx.x < 8) lc[threadIdx.x] = 0;
    __syncthreads();
    const int* dst = (list == 0) ? d0 : (list == 1) ? d1 : d2;
    const int rn = (list == 2) ? RN_Z : RN_D;
    const int elo = (int)((long long)chunk * E / CHK);
    const int ehi = (int)((long long)(chunk + 1) * E / CHK);
    for (int e = elo + threadIdx.x; e < ehi; e += 256) {
        int d = dst[e];
        int r = min(d / rn, 7);
        atomicAdd(&lc[r], 1);
    }
    __syncthreads();
    if (threadIdx.x < 8) rc[(list * CHK + chunk) * 8 + threadIdx.x] = lc[threadIdx.x];
}

// ---------------------------------------------------------------------------
// Phase 2: exclusive scan of rc in order (list, range, chunk); per-list reset.
// ---------------------------------------------------------------------------
__global__ __launch_bounds__(256) void bscan(
    const int* __restrict__ rc, int* __restrict__ wpos, int* __restrict__ rbase)
{
    __shared__ int sc[256];
    const int tid = threadIdx.x;
    const int lo = tid * 9;
    int v[9];
    int s = 0;
#pragma unroll
    for (int k = 0; k < 9; ++k) {
        int i = lo + k;
        int list = i / (8 * CHK), rem = i % (8 * CHK);
        int r = rem / CHK, c = rem % CHK;
        v[k] = rc[(list * CHK + c) * 8 + r];
        s += v[k];
    }
    sc[tid] = s;
    __syncthreads();
    for (int off = 1; off < 256; off <<= 1) {
        int t = (tid >= off) ? sc[tid - off] : 0;
        __syncthreads();
        sc[tid] += t;
        __syncthreads();
    }
    int run = tid ? sc[tid - 1] : 0;
#pragma unroll
    for (int k = 0; k < 9; ++k) {
        int i = lo + k;
        int list = i / (8 * CHK), rem = i % (8 * CHK);
        int r = rem / CHK, c = rem % CHK;
        int base = run - list * E;
        wpos[(list * CHK + c) * 8 + r] = base;
        if (c == 0) rbase[list * 9 + r] = base;
        run += v[k];
    }
    if (tid < 3) rbase[tid * 9 + 8] = E;
}

// ---------------------------------------------------------------------------
// Phase 3: scatter edges into per-range buckets, PACKED u32:
//   w = (local_dst << 19) | src   (local_dst < 6250 < 2^13, src < 50000 < 2^19)
// ---------------------------------------------------------------------------
__global__ __launch_bounds__(256) void bscatter(
    const int* __restrict__ s0, const int* __restrict__ d0,
    const int* __restrict__ s1, const int* __restrict__ d1,
    const int* __restrict__ s2, const int* __restrict__ d2,
    const int* __restrict__ wpos,
    unsigned* __restrict__ b0, unsigned* __restrict__ b1, unsigned* __restrict__ b2)
{
    __shared__ int lc[8];
    const int list = blockIdx.x / CHK;
    const int chunk = blockIdx.x % CHK;
    if (threadIdx.x < 8) lc[threadIdx.x] = wpos[(list * CHK + chunk) * 8 + threadIdx.x];
    __syncthreads();
    const int* src = (list == 0) ? s0 : (list == 1) ? s1 : s2;
    const int* dst = (list == 0) ? d0 : (list == 1) ? d1 : d2;
    unsigned* bkt = (list == 0) ? b0 : (list == 1) ? b1 : b2;
    const int rn = (list == 2) ? RN_Z : RN_D;
    const int elo = (int)((long long)chunk * E / CHK);
    const int ehi = (int)((long long)(chunk + 1) * E / CHK);
    for (int e = elo + threadIdx.x; e < ehi; e += 256) {
        int d = dst[e];
        int s = src[e];
        int r = min(d / rn, 7);
        int p = atomicAdd(&lc[r], 1);
        bkt[p] = ((unsigned)(d - r * rn) << 19) | (unsigned)s;
    }
}

// ---------------------------------------------------------------------------
// Phase 4: exact per-(slice,node) counts via LDS histogram. NO global atomics.
// ---------------------------------------------------------------------------
__global__ __launch_bounds__(256) void bcount2(
    const unsigned* __restrict__ b0, const unsigned* __restrict__ b1,
    const unsigned* __restrict__ b2,
    const int* __restrict__ rbase, int* __restrict__ partial)
{
    __shared__ int lh[RN_D];
    const int range = blockIdx.x & 7;
    const int t = blockIdx.x >> 3;
    const int list = t % 3;
    const int sub = t / 3;
    const unsigned* bkt = (list == 0) ? b0 : (list == 1) ? b1 : b2;
    const int rn = (list == 2) ? RN_Z : RN_D;
    const int pb = (list == 0) ? 0 : (list == 1) ? PB1 : PB2;
    for (int i = threadIdx.x; i < rn; i += 256) lh[i] = 0;
    __syncthreads();
    const int s0 = rbase[list * 9 + range];
    const int s1 = rbase[list * 9 + range + 1];
    const int len = s1 - s0;
    const int lo = s0 + (int)((long long)sub * len / SSUB);
    const int hi = s0 + (int)((long long)(sub + 1) * len / SSUB);
    for (int i = lo + threadIdx.x; i < hi; i += 256)
        atomicAdd(&lh[bkt[i] >> 19], 1);
    __syncthreads();
    int* pout = partial + pb + (range * SSUB + sub) * rn;
    for (int i = threadIdx.x; i < rn; i += 256) pout[i] = lh[i];
}

// ---------------------------------------------------------------------------
// Fused: cnt[node] = sum over slices of partial, AND per-tile partial sums.
// grid = 2*NB_D + NB_Z blocks; block = 1024-node tile (256 thr x 4).
// ---------------------------------------------------------------------------
__device__ __forceinline__ void scan_map(int b, int& which, int& tile) {
    if (b < NB_D) { which = 0; tile = b; }
    else if (b < 2 * NB_D) { which = 1; tile = b - NB_D; }
    else { which = 2; tile = b - 2 * NB_D; }
}

__global__ __launch_bounds__(256) void sumcnt_part(
    const int* __restrict__ partial,
    int* __restrict__ c0, int* __restrict__ c1, int* __restrict__ c2,
    int* __restrict__ part)
{
    __shared__ int red[256];
    int which, tile;
    scan_map(blockIdx.x, which, tile);
    const int n = (which == 2) ? NZ : ND;
    const int rn = (which == 2) ? RN_Z : RN_D;
    const int pb = (which == 0) ? 0 : (which == 1) ? PB1 : PB2;
    int* cnt = (which == 0) ? c0 : (which == 1) ? c1 : c2;

    const int tb = tile * SCAN_TILE + threadIdx.x * 4;
    int blocksum = 0;
#pragma unroll
    for (int k = 0; k < 4; ++k) {
        int node = tb + k;
        if (node < n) {
            int r = node / rn, local = node % rn;
            const int* p = partial + pb + r * SSUB * rn + local;
            int s = 0;
#pragma unroll
            for (int kk = 0; kk < SSUB; ++kk) s += p[(size_t)kk * rn];
            cnt[node] = s;
            blocksum += s;
        }
    }
    red[threadIdx.x] = blocksum;
    __syncthreads();
#pragma unroll
    for (int off = 128; off > 0; off >>= 1) {
        if (threadIdx.x < off) red[threadIdx.x] += red[threadIdx.x + off];
        __syncthreads();
    }
    if (threadIdx.x == 0) part[which * 64 + tile] = red[0];
}

__global__ __launch_bounds__(64) void scan_small3(
    int* __restrict__ part,
    int* __restrict__ o0, int* __restrict__ o1, int* __restrict__ o2)
{
    int w = blockIdx.x;
    int np = (w == 2) ? NB_Z : NB_D;
    int n = (w == 2) ? NZ : ND;
    int* offs = (w == 0) ? o0 : (w == 1) ? o1 : o2;
    int* pb = part + w * 64;
    int lane = threadIdx.x;
    int orig = (lane < np) ? pb[lane] : 0;
    int v = orig;
#pragma unroll
    for (int off = 1; off < 64; off <<= 1) {
        int t = __shfl_up(v, off, 64);
        if (lane >= off) v += t;
    }
    if (lane < np) pb[lane] = v - orig;
    if (lane == 63) offs[n] = v;
}

// ---------------------------------------------------------------------------
// Fused: tile scan -> offs, AND convert partial counts -> per-slice bases.
// ---------------------------------------------------------------------------
__global__ __launch_bounds__(256) void scan_write_base(
    const int* __restrict__ c0, const int* __restrict__ c1, const int* __restrict__ c2,
    const int* __restrict__ part,
    int* __restrict__ o0, int* __restrict__ o1, int* __restrict__ o2,
    int* __restrict__ partial)
{
    __shared__ int sc[256];
    int which, tile;
    scan_map(blockIdx.x, which, tile);
    const int* cnt = (which == 0) ? c0 : (which == 1) ? c1 : c2;
    int* offs = (which == 0) ? o0 : (which == 1) ? o1 : o2;
    const int n = (which == 2) ? NZ : ND;
    const int rn = (which == 2) ? RN_Z : RN_D;
    const int pb = (which == 0) ? 0 : (which == 1) ? PB1 : PB2;

    const int tid = threadIdx.x;
    const int tb = tile * SCAN_TILE + tid * 4;
    int v[4];
    int s = 0;
#pragma unroll
    for (int k = 0; k < 4; ++k) {
        v[k] = (tb + k < n) ? cnt[tb + k] : 0;
        s += v[k];
    }
    sc[tid] = s;
    __syncthreads();
#pragma unroll
    for (int off = 1; off < 256; off <<= 1) {
        int t = (tid >= off) ? sc[tid - off] : 0;
        __syncthreads();
        sc[tid] += t;
        __syncthreads();
    }
    int ex = part[which * 64 + tile] + (tid ? sc[tid - 1] : 0);
#pragma unroll
    for (int k = 0; k < 4; ++k) {
        int node = tb + k;
        if (node < n) {
            offs[node] = ex;
            // convert this node's SSUB partial counts into write bases
            int r = node / rn, local = node % rn;
            int* p = partial + pb + r * SSUB * rn + local;
            int run = ex;
#pragma unroll
            for (int kk = 0; kk < SSUB; ++kk) {
                int* q = p + (size_t)kk * rn;
                int t = *q;
                *q = run;
                run += t;
            }
            ex += v[k];
        }
    }
}

// ---------------------------------------------------------------------------
// Phase 5: CSR fill from packed buckets with LDS cursors. NO global atomics.
// ---------------------------------------------------------------------------
__global__ __launch_bounds__(256) void bfill2(
    const unsigned* __restrict__ b0, const unsigned* __restrict__ b1,
    const unsigned* __restrict__ b2,
    const int* __restrict__ rbase, const int* __restrict__ partial,
    int* __restrict__ l0, int* __restrict__ l1, int* __restrict__ l2)
{
    __shared__ int lcur[RN_D];
    const int range = blockIdx.x & 7;
    const int t = blockIdx.x >> 3;
    const int list = t % 3;
    const int sub = t / 3;
    const unsigned* bkt = (list == 0) ? b0 : (list == 1) ? b1 : b2;
    int* col = (list == 0) ? l0 : (list == 1) ? l1 : l2;
    const int rn = (list == 2) ? RN_Z : RN_D;
    const int pb = (list == 0) ? 0 : (list == 1) ? PB1 : PB2;
    const int* bin = partial + pb + (range * SSUB + sub) * rn;
    for (int i = threadIdx.x; i < rn; i += 256) lcur[i] = bin[i];
    __syncthreads();
    const int s0 = rbase[list * 9 + range];
    const int s1 = rbase[list * 9 + range + 1];
    const int len = s1 - s0;
    const int lo = s0 + (int)((long long)sub * len / SSUB);
    const int hi = s0 + (int)((long long)(sub + 1) * len / SSUB);
    for (int i = lo + threadIdx.x; i < hi; i += 256) {
        unsigned w = bkt[i];
        int p = atomicAdd(&lcur[w >> 19], 1);
        col[p] = (int)(w & 0x7FFFFu);
    }
}

// ---------------------------------------------------------------------------
// CSR mean-aggregation, 128-col rows. sub=lane>>4 edge slot, cl=lane&15 x 16B.
// ---------------------------------------------------------------------------
__global__ __launch_bounds__(256) void agg3_128(
    const int* __restrict__ o0, const int* __restrict__ c0,
    const unsigned short* __restrict__ X0, unsigned short* __restrict__ M0, int n0,
    const int* __restrict__ o1, const int* __restrict__ c1,
    const unsigned short* __restrict__ X1, unsigned short* __restrict__ M1, int n1,
    const int* __restrict__ o2, const int* __restrict__ c2,
    const unsigned short* __restrict__ X2, unsigned short* __restrict__ M2, int n2)
{
    int wid = (blockIdx.x * blockDim.x + threadIdx.x) >> 6;
    const int lane = threadIdx.x & 63;
    const int sub = lane >> 4;
    const int cl  = lane & 15;

    const int* offs; const int* col;
    const unsigned short* X; unsigned short* M;
    if (wid < n0) { offs = o0; col = c0; X = X0; M = M0; }
    else if (wid < n0 + n1) { wid -= n0; offs = o1; col = c1; X = X1; M = M1; }
    else { wid -= n0 + n1; if (wid >= n2) return; offs = o2; col = c2; X = X2; M = M2; }

    const int start = offs[wid];
    const int end = offs[wid + 1];
    const unsigned short* Xl = X + cl * 8;

    float a[8] = {0.f, 0.f, 0.f, 0.f, 0.f, 0.f, 0.f, 0.f};
    float b[8] = {0.f, 0.f, 0.f, 0.f, 0.f, 0.f, 0.f, 0.f};
    for (int e0 = start; e0 < end; e0 += 8) {
        int eA = e0 + sub;
        int eB = e0 + 4 + sub;
        if (eA < end) {
            int s = col[eA];
            uint4 v = *reinterpret_cast<const uint4*>(Xl + (size_t)s * HID);
            a[0] += bf2f((unsigned short)(v.x & 0xffffu));
            a[1] += bf2f((unsigned short)(v.x >> 16));
            a[2] += bf2f((unsigned short)(v.y & 0xffffu));
            a[3] += bf2f((unsigned short)(v.y >> 16));
            a[4] += bf2f((unsigned short)(v.z & 0xffffu));
            a[5] += bf2f((unsigned short)(v.z >> 16));
            a[6] += bf2f((unsigned short)(v.w & 0xffffu));
            a[7] += bf2f((unsigned short)(v.w >> 16));
        }
        if (eB < end) {
            int s = col[eB];
            uint4 v = *reinterpret_cast<const uint4*>(Xl + (size_t)s * HID);
            b[0] += bf2f((unsigned short)(v.x & 0xffffu));
            b[1] += bf2f((unsigned short)(v.x >> 16));
            b[2] += bf2f((unsigned short)(v.y & 0xffffu));
            b[3] += bf2f((unsigned short)(v.y >> 16));
            b[4] += bf2f((unsigned short)(v.z & 0xffffu));
            b[5] += bf2f((unsigned short)(v.z >> 16));
            b[6] += bf2f((unsigned short)(v.w & 0xffffu));
            b[7] += bf2f((unsigned short)(v.w >> 16));
        }
    }
#pragma unroll
    for (int k = 0; k < 8; ++k) {
        a[k] += b[k];
        a[k] += __shfl_xor(a[k], 16, 64);
        a[k] += __shfl_xor(a[k], 32, 64);
    }

    if (sub == 0) {
        float inv = 1.0f / (float)max(end - start, 1);
        uint4 o;
        o.x = (unsigned)f2bf(a[0] * inv) | ((unsigned)f2bf(a[1] * inv) << 16);
        o.y = (unsigned)f2bf(a[2] * inv) | ((unsigned)f2bf(a[3] * inv) << 16);
        o.z = (unsigned)f2bf(a[4] * inv) | ((unsigned)f2bf(a[5] * inv) << 16);
        o.w = (unsigned)f2bf(a[6] * inv) | ((unsigned)f2bf(a[7] * inv) << 16);
        *reinterpret_cast<uint4*>(M + (size_t)wid * HID + cl * 8) = o;
    }
}

// ---------------------------------------------------------------------------
// CSR mean-aggregation, 64-col rows (pre-transformed Z).
// ---------------------------------------------------------------------------
__global__ __launch_bounds__(256) void agg3_64(
    const int* __restrict__ o0, const int* __restrict__ c0,
    const unsigned short* __restrict__ X0, unsigned short* __restrict__ M0, int n0,
    const int* __restrict__ o1, const int* __restrict__ c1,
    const unsigned short* __restrict__ X1, unsigned short* __restrict__ M1, int n1,
    const int* __restrict__ o2, const int* __restrict__ c2,
    const unsigned short* __restrict__ X2, unsigned short* __restrict__ M2, int n2)
{
    int wid = (blockIdx.x * blockDim.x + threadIdx.x) >> 6;
    const int lane = threadIdx.x & 63;
    const int sub = lane >> 4;
    const int cl  = lane & 15;

    const int* offs; const int* col;
    const unsigned short* X; unsigned short* M;
    if (wid < n0) { offs = o0; col = c0; X = X0; M = M0; }
    else if (wid < n0 + n1) { wid -= n0; offs = o1; col = c1; X = X1; M = M1; }
    else { wid -= n0 + n1; if (wid >= n2) return; offs = o2; col = c2; X = X2; M = M2; }

    const int start = offs[wid];
    const int end = offs[wid + 1];
    const unsigned short* Xl = X + cl * 4;

    float a[4] = {0.f, 0.f, 0.f, 0.f};
    float b[4] = {0.f, 0.f, 0.f, 0.f};
    for (int e0 = start; e0 < end; e0 += 8) {
        int eA = e0 + sub;
        int eB = e0 + 4 + sub;
        if (eA < end) {
            int s = col[eA];
            uint2 v = *reinterpret_cast<const uint2*>(Xl + (size_t)s * OUTD);
            a[0] += bf2f((unsigned short)(v.x & 0xffffu));
            a[1] += bf2f((unsigned short)(v.x >> 16));
            a[2] += bf2f((unsigned short)(v.y & 0xffffu));
            a[3] += bf2f((unsigned short)(v.y >> 16));
        }
        if (eB < end) {
            int s = col[eB];
            uint2 v = *reinterpret_cast<const uint2*>(Xl + (size_t)s * OUTD);
            b[0] += bf2f((unsigned short)(v.x & 0xffffu));
            b[1] += bf2f((unsigned short)(v.x >> 16));
            b[2] += bf2f((unsigned short)(v.y & 0xffffu));
            b[3] += bf2f((unsigned short)(v.y >> 16));
        }
    }
#pragma unroll
    for (int k = 0; k < 4; ++k) {
        a[k] += b[k];
        a[k] += __shfl_xor(a[k], 16, 64);
        a[k] += __shfl_xor(a[k], 32, 64);
    }

    if (sub == 0) {
        float inv = 1.0f / (float)max(end - start, 1);
        uint2 o;
        o.x = (unsigned)f2bf(a[0] * inv) | ((unsigned)f2bf(a[1] * inv) << 16);
        o.y = (unsigned)f2bf(a[2] * inv) | ((unsigned)f2bf(a[3] * inv) << 16);
        *reinterpret_cast<uint2*>(M + (size_t)wid * OUTD + cl * 4) = o;
    }
}

// ---------------------------------------------------------------------------
// Fused transform: Z = H @ Wl (first half of Wt), CO=64, K=128. 3 sections.
// ---------------------------------------------------------------------------
__global__ __launch_bounds__(256) void xform3(
    const unsigned short* __restrict__ H0, const unsigned short* __restrict__ W0,
    unsigned short* __restrict__ Z0, int n0,
    const unsigned short* __restrict__ H1, const unsigned short* __restrict__ W1,
    unsigned short* __restrict__ Z1, int n1,
    const unsigned short* __restrict__ H2, const unsigned short* __restrict__ W2,
    unsigned short* __restrict__ Z2, int n2)
{
    const int b0 = (n0 + 63) / 64, b1 = (n1 + 63) / 64;
    int b = blockIdx.x;
    const unsigned short *H, *W; unsigned short* Z; int n;
    if (b < b0) { H = H0; W = W0; Z = Z0; n = n0; }
    else if (b < b0 + b1) { b -= b0; H = H1; W = W1; Z = Z1; n = n1; }
    else { b -= b0 + b1; H = H2; W = W2; Z = Z2; n = n2; }

    constexpr int NT = OUTD / 16;
    const int wave = threadIdx.x >> 6;
    const int lane = threadIdx.x & 63;
    const int r16 = lane & 15;
    const int chunk = lane >> 4;
    const int rowbase = b * 64 + wave * 16;
    if (rowbase >= n) return;

    const int arow = min(rowbase + r16, n - 1);
    const unsigned short* hrow = H + (size_t)arow * HID;

    bf16x8 a[4];
#pragma unroll
    for (int s = 0; s < 4; ++s)
        a[s] = *reinterpret_cast<const bf16x8*>(hrow + s * 32 + chunk * 8);

    f32x4 acc[NT];
#pragma unroll
    for (int t = 0; t < NT; ++t) acc[t] = f32x4{0.f, 0.f, 0.f, 0.f};

#pragma unroll
    for (int t = 0; t < NT; ++t) {
        const unsigned short* w_ = W + (size_t)(t * 16 + r16) * 256;
#pragma unroll
        for (int s = 0; s < 4; ++s) {
            bf16x8 bfrag = *reinterpret_cast<const bf16x8*>(w_ + s * 32 + chunk * 8);
            acc[t] = __builtin_amdgcn_mfma_f32_16x16x32_bf16(a[s], bfrag, acc[t], 0, 0, 0);
        }
    }

#pragma unroll
    for (int r = 0; r < 4; ++r) {
        int node = rowbase + chunk * 4 + r;
        if (node < n) {
#pragma unroll
            for (int t = 0; t < NT; ++t)
                Z[(size_t)node * OUTD + t * 16 + r16] = f2bf(acc[t][r]);
        }
    }
}

// ---------------------------------------------------------------------------
// Layer-0 SAGE kernels (K=256 over [mean|x]).
// C/D layout: col = lane&15, row = (lane>>4)*4 + reg   [verified m89]
// ---------------------------------------------------------------------------
template <int CO>
__global__ __launch_bounds__(256) void sage_mfma(
    const unsigned short* __restrict__ Mb,
    const unsigned short* __restrict__ Xb,
    const unsigned short* __restrict__ Wt,
    const float* __restrict__ bl,
    float* __restrict__ H, int n)
{
    constexpr int NT = CO / 16;
    const int wave = threadIdx.x >> 6;
    const int lane = threadIdx.x & 63;
    const int r16 = lane & 15;
    const int chunk = lane >> 4;
    const int rowbase = blockIdx.x * 64 + wave * 16;
    if (rowbase >= n) return;

    const int arow = min(rowbase + r16, n - 1);
    const unsigned short* mrow = Mb + (size_t)arow * HID;
    const unsigned short* xrow = Xb + (size_t)arow * HID;

    bf16x8 a[8];
#pragma unroll
    for (int s = 0; s < 4; ++s) {
        a[s]     = *reinterpret_cast<const bf16x8*>(mrow + s * 32 + chunk * 8);
        a[4 + s] = *reinterpret_cast<const bf16x8*>(xrow + s * 32 + chunk * 8);
    }

    f32x4 acc[NT];
#pragma unroll
    for (int t = 0; t < NT; ++t) acc[t] = f32x4{0.f, 0.f, 0.f, 0.f};

#pragma unroll
    for (int t = 0; t < NT; ++t) {
        const unsigned short* wr_ = Wt + (size_t)(t * 16 + r16) * 256;
#pragma unroll
        for (int s = 0; s < 8; ++s) {
            bf16x8 b = *reinterpret_cast<const bf16x8*>(wr_ + s * 32 + chunk * 8);
            acc[t] = __builtin_amdgcn_mfma_f32_16x16x32_bf16(a[s], b, acc[t], 0, 0, 0);
        }
    }

    float ss[4] = {0.f, 0.f, 0.f, 0.f};
#pragma unroll
    for (int t = 0; t < NT; ++t) {
        float bias = bl[t * 16 + r16];
#pragma unroll
        for (int r = 0; r < 4; ++r) {
            acc[t][r] += bias;
            ss[r] += acc[t][r] * acc[t][r];
        }
    }
#pragma unroll
    for (int r = 0; r < 4; ++r)
#pragma unroll
        for (int m = 1; m < 16; m <<= 1)
            ss[r] += __shfl_xor(ss[r], m, 64);

#pragma unroll
    for (int r = 0; r < 4; ++r) {
        int node = rowbase + chunk * 4 + r;
        if (node < n) {
            float inv = 1.0f / fmaxf(sqrtf(ss[r]), 1e-12f);
#pragma unroll
            for (int t = 0; t < NT; ++t)
                H[(size_t)node * CO + t * 16 + r16] = acc[t][r] * inv;
        }
    }
}

template <int CO>
__global__ __launch_bounds__(256) void sage2_mfma(
    const unsigned short* __restrict__ MbA,
    const unsigned short* __restrict__ MbB,
    const unsigned short* __restrict__ Xb,
    const unsigned short* __restrict__ WtA,
    const unsigned short* __restrict__ WtB,
    const float* __restrict__ blA, const float* __restrict__ blB,
    float* __restrict__ H, int n)
{
    constexpr int NT = CO / 16;
    const int wave = threadIdx.x >> 6;
    const int lane = threadIdx.x & 63;
    const int r16 = lane & 15;
    const int chunk = lane >> 4;
    const int rowbase = blockIdx.x * 64 + wave * 16;
    if (rowbase >= n) return;

    const int arow = min(rowbase + r16, n - 1);
    const unsigned short* marow = MbA + (size_t)arow * HID;
    const unsigned short* mbrow = MbB + (size_t)arow * HID;
    const unsigned short* xrow  = Xb  + (size_t)arow * HID;

    bf16x8 aA[4], aB[4], ax[4];
#pragma unroll
    for (int s = 0; s < 4; ++s) {
        aA[s] = *reinterpret_cast<const bf16x8*>(marow + s * 32 + chunk * 8);
        aB[s] = *reinterpret_cast<const bf16x8*>(mbrow + s * 32 + chunk * 8);
        ax[s] = *reinterpret_cast<const bf16x8*>(xrow  + s * 32 + chunk * 8);
    }

    f32x4 accA[NT], accB[NT];
#pragma unroll
    for (int t = 0; t < NT; ++t) {
        accA[t] = f32x4{0.f, 0.f, 0.f, 0.f};
        accB[t] = f32x4{0.f, 0.f, 0.f, 0.f};
    }

#pragma unroll
    for (int t = 0; t < NT; ++t) {
        const unsigned short* wA = WtA + (size_t)(t * 16 + r16) * 256;
        const unsigned short* wB = WtB + (size_t)(t * 16 + r16) * 256;
#pragma unroll
        for (int s = 0; s < 4; ++s) {
            bf16x8 b0 = *reinterpret_cast<const bf16x8*>(wA + s * 32 + chunk * 8);
            accA[t] = __builtin_amdgcn_mfma_f32_16x16x32_bf16(aA[s], b0, accA[t], 0, 0, 0);
            bf16x8 b1 = *reinterpret_cast<const bf16x8*>(wA + HID + s * 32 + chunk * 8);
            accA[t] = __builtin_amdgcn_mfma_f32_16x16x32_bf16(ax[s], b1, accA[t], 0, 0, 0);
            bf16x8 b2 = *reinterpret_cast<const bf16x8*>(wB + s * 32 + chunk * 8);
            accB[t] = __builtin_amdgcn_mfma_f32_16x16x32_bf16(aB[s], b2, accB[t], 0, 0, 0);
            bf16x8 b3 = *reinterpret_cast<const bf16x8*>(wB + HID + s * 32 + chunk * 8);
            accB[t] = __builtin_amdgcn_mfma_f32_16x16x32_bf16(ax[s], b3, accB[t], 0, 0, 0);
        }
    }

    float ssA[4] = {0.f, 0.f, 0.f, 0.f};
    float ssB[4] = {0.f, 0.f, 0.f, 0.f};
#pragma unroll
    for (int t = 0; t < NT; ++t) {
        float biasA = blA[t * 16 + r16];
        float biasB = blB[t * 16 + r16];
#pragma unroll
        for (int r = 0; r < 4; ++r) {
            accA[t][r] += biasA;
            ssA[r] += accA[t][r] * accA[t][r];
            accB[t][r] += biasB;
            ssB[r] += accB[t][r] * accB[t][r];
        }
    }
#pragma unroll
    for (int r = 0; r < 4; ++r)
#pragma unroll
        for (int m = 1; m < 16; m <<= 1) {
            ssA[r] += __shfl_xor(ssA[r], m, 64);
            ssB[r] += __shfl_xor(ssB[r], m, 64);
        }

#pragma unroll
    for (int r = 0; r < 4; ++r) {
        int node = rowbase + chunk * 4 + r;
        if (node < n) {
            float invA = 1.0f / fmaxf(sqrtf(ssA[r]), 1e-12f);
            float invB = 1.0f / fmaxf(sqrtf(ssB[r]), 1e-12f);
#pragma unroll
            for (int t = 0; t < NT; ++t)
                H[(size_t)node * CO + t * 16 + r16] =
                    accA[t][r] * invA + accB[t][r] * invB;
        }
    }
}

// ---------------------------------------------------------------------------
// Layer-1 SAGE with pre-aggregated meanZ (= mean@Wl): only x@Wr via MFMA.
// ---------------------------------------------------------------------------
__global__ __launch_bounds__(256) void sage2z(
    const unsigned short* __restrict__ MZa,
    const unsigned short* __restrict__ MZb,
    const unsigned short* __restrict__ Xb,
    const unsigned short* __restrict__ WtA,
    const unsigned short* __restrict__ WtB,
    const float* __restrict__ blA, const float* __restrict__ blB,
    float* __restrict__ H, int n)
{
    constexpr int NT = OUTD / 16;
    const int wave = threadIdx.x >> 6;
    const int lane = threadIdx.x & 63;
    const int r16 = lane & 15;
    const int chunk = lane >> 4;
    const int rowbase = blockIdx.x * 64 + wave * 16;
    if (rowbase >= n) return;

    const int arow = min(rowbase + r16, n - 1);
    const unsigned short* xrow = Xb + (size_t)arow * HID;

    bf16x8 ax[4];
#pragma unroll
    for (int s = 0; s < 4; ++s)
        ax[s] = *reinterpret_cast<const bf16x8*>(xrow + s * 32 + chunk * 8);

    f32x4 accA[NT], accB[NT];
#pragma unroll
    for (int t = 0; t < NT; ++t) {
        accA[t] = f32x4{0.f, 0.f, 0.f, 0.f};
        accB[t] = f32x4{0.f, 0.f, 0.f, 0.f};
    }

#pragma unroll
    for (int t = 0; t < NT; ++t) {
        const unsigned short* wA = WtA + (size_t)(t * 16 + r16) * 256 + HID;
        const unsigned short* wB = WtB + (size_t)(t * 16 + r16) * 256 + HID;
#pragma unroll
        for (int s = 0; s < 4; ++s) {
            bf16x8 b0 = *reinterpret_cast<const bf16x8*>(wA + s * 32 + chunk * 8);
            accA[t] = __builtin_amdgcn_mfma_f32_16x16x32_bf16(ax[s], b0, accA[t], 0, 0, 0);
            bf16x8 b1 = *reinterpret_cast<const bf16x8*>(wB + s * 32 + chunk * 8);
            accB[t] = __builtin_amdgcn_mfma_f32_16x16x32_bf16(ax[s], b1, accB[t], 0, 0, 0);
        }
    }

    float ssA[4] = {0.f, 0.f, 0.f, 0.f};
    float ssB[4] = {0.f, 0.f, 0.f, 0.f};
#pragma unroll
    for (int r = 0; r < 4; ++r) {
        int cl = min(rowbase + chunk * 4 + r, n - 1);
#pragma unroll
        for (int t = 0; t < NT; ++t) {
            int j = t * 16 + r16;
            float vA = accA[t][r] + blA[j] + bf2f(MZa[(size_t)cl * OUTD + j]);
            accA[t][r] = vA;
            ssA[r] += vA * vA;
            float vB = accB[t][r] + blB[j] + bf2f(MZb[(size_t)cl * OUTD + j]);
            accB[t][r] = vB;
            ssB[r] += vB * vB;
        }
    }
#pragma unroll
    for (int r = 0; r < 4; ++r)
#pragma unroll
        for (int m = 1; m < 16; m <<= 1) {
            ssA[r] += __shfl_xor(ssA[r], m, 64);
            ssB[r] += __shfl_xor(ssB[r], m, 64);
        }

#pragma unroll
    for (int r = 0; r < 4; ++r) {
        int node = rowbase + chunk * 4 + r;
        if (node < n) {
            float invA = 1.0f / fmaxf(sqrtf(ssA[r]), 1e-12f);
            float invB = 1.0f / fmaxf(sqrtf(ssB[r]), 1e-12f);
#pragma unroll
            for (int t = 0; t < NT; ++t)
                H[(size_t)node * OUTD + t * 16 + r16] =
                    accA[t][r] * invA + accB[t][r] * invB;
        }
    }
}

__global__ __launch_bounds__(256) void sagez(
    const unsigned short* __restrict__ MZ,
    const unsigned short* __restrict__ Xb,
    const unsigned short* __restrict__ Wt,
    const float* __restrict__ bl,
    float* __restrict__ H, int n)
{
    constexpr int NT = OUTD / 16;
    const int wave = threadIdx.x >> 6;
    const int lane = threadIdx.x & 63;
    const int r16 = lane & 15;
    const int chunk = lane >> 4;
    const int rowbase = blockIdx.x * 64 + wave * 16;
    if (rowbase >= n) return;

    const int arow = min(rowbase + r16, n - 1);
    const unsigned short* xrow = Xb + (size_t)arow * HID;

    bf16x8 ax[4];
#pragma unroll
    for (int s = 0; s < 4; ++s)
        ax[s] = *reinterpret_cast<const bf16x8*>(xrow + s * 32 + chunk * 8);

    f32x4 acc[NT];
#pragma unroll
    for (int t = 0; t < NT; ++t) acc[t] = f32x4{0.f, 0.f, 0.f, 0.f};

#pragma unroll
    for (int t = 0; t < NT; ++t) {
        const unsigned short* w_ = Wt + (size_t)(t * 16 + r16) * 256 + HID;
#pragma unroll
        for (int s = 0; s < 4; ++s) {
            bf16x8 b = *reinterpret_cast<const bf16x8*>(w_ + s * 32 + chunk * 8);
            acc[t] = __builtin_amdgcn_mfma_f32_16x16x32_bf16(ax[s], b, acc[t], 0, 0, 0);
        }
    }

    float ss[4] = {0.f, 0.f, 0.f, 0.f};
#pragma unroll
    for (int r = 0; r < 4; ++r) {
        int cl = min(rowbase + chunk * 4 + r, n - 1);
#pragma unroll
        for (int t = 0; t < NT; ++t) {
            int j = t * 16 + r16;
            float v = acc[t][r] + bl[j] + bf2f(MZ[(size_t)cl * OUTD + j]);
            acc[t][r] = v;
            ss[r] += v * v;
        }
    }
#pragma unroll
    for (int r = 0; r < 4; ++r)
#pragma unroll
        for (int m = 1; m < 16; m <<= 1)
            ss[r] += __shfl_xor(ss[r], m, 64);

#pragma unroll
    for (int r = 0; r < 4; ++r) {
        int node = rowbase + chunk * 4 + r;
        if (node < n) {
            float inv = 1.0f / fmaxf(sqrtf(ss[r]), 1e-12f);
#pragma unroll
            for (int t = 0; t < NT; ++t)
                H[(size_t)node * OUTD + t * 16 + r16] = acc[t][r] * inv;
        }
    }
}

// ---------------------------------------------------------------------------
// Fused LayerNorm over 2 tensors (sections), one wave per row.
// ---------------------------------------------------------------------------
template <int D, bool RELU, bool OUTBF>
__global__ __launch_bounds__(256) void ln2_kernel(
    const float* __restrict__ X1, const float* __restrict__ g1,
    const float* __restrict__ b1, void* __restrict__ out1, int n1,
    const float* __restrict__ X2, const float* __restrict__ g2,
    const float* __restrict__ b2, void* __restrict__ out2, int n2)
{
    constexpr int VPL = D / 64;
    int wid = (blockIdx.x * blockDim.x + threadIdx.x) >> 6;
    int lane = threadIdx.x & 63;
    const float *X, *gg, *bb; void* outp; int n;
    if (wid < n1) { X = X1; gg = g1; bb = b1; outp = out1; n = n1; }
    else { wid -= n1; if (wid >= n2) return; X = X2; gg = g2; bb = b2; outp = out2; n = n2; }

    float v[VPL], gv[VPL], bv[VPL];
    const float* xp = X + (size_t)wid * D + lane * VPL;
#pragma unroll
    for (int k = 0; k < VPL; ++k) {
        v[k] = xp[k];
        gv[k] = gg[lane * VPL + k];
        bv[k] = bb[lane * VPL + k];
    }
    float s = 0.f;
#pragma unroll
    for (int k = 0; k < VPL; ++k) s += v[k];
#pragma unroll
    for (int off = 32; off > 0; off >>= 1) s += __shfl_xor(s, off, 64);
    float m = s / D;
    float ss = 0.f;
#pragma unroll
    for (int k = 0; k < VPL; ++k) { float d = v[k] - m; ss += d * d; }
#pragma unroll
    for (int off = 32; off > 0; off >>= 1) ss += __shfl_xor(ss, off, 64);
    float rstd = rsqrtf(ss / D + 1e-5f);

    float y[VPL];
#pragma unroll
    for (int k = 0; k < VPL; ++k) {
        y[k] = gv[k] * (v[k] - m) * rstd + bv[k];
        if (RELU) y[k] = fmaxf(y[k], 0.f);
    }
    if (OUTBF) {
        unsigned short* op = (unsigned short*)outp + (size_t)wid * D + lane * VPL;
#pragma unroll
        for (int k = 0; k < VPL; ++k) op[k] = f2bf(y[k]);
    } else {
        float* op = (float*)outp + (size_t)wid * D + lane * VPL;
#pragma unroll
        for (int k = 0; k < VPL; ++k) op[k] = y[k];
    }
}

// ---------------------------------------------------------------------------
extern "C" void kernel_launch(void* const* d_in, const int* in_sizes, int n_in,
                              void* d_out, int out_size, void* d_ws, size_t ws_size,
                              hipStream_t stream)
{
    const int*   x_drug   = (const int*)d_in[0];
    const int*   x_dis    = (const int*)d_in[1];
    const float* emb_drug = (const float*)d_in[2];
    const float* emb_dis  = (const float*)d_in[3];
    const int*   src_dd   = (const int*)d_in[4];
    const int*   dst_dd   = (const int*)d_in[5];
    const int*   src_td   = (const int*)d_in[6];
    const int*   dst_td   = (const int*)d_in[7];
    const int*   src_rd   = (const int*)d_in[8];
    const int*   dst_rd   = (const int*)d_in[9];
    const float* Wl0_dd = (const float*)d_in[10];
    const float* bl0_dd = (const float*)d_in[11];
    const float* Wr0_dd = (const float*)d_in[12];
    const float* Wl0_td = (const float*)d_in[13];
    const float* bl0_td = (const float*)d_in[14];
    const float* Wr0_td = (const float*)d_in[15];
    const float* Wl0_rd = (const float*)d_in[16];
    const float* bl0_rd = (const float*)d_in[17];
    const float* Wr0_rd = (const float*)d_in[18];
    const float* Wl1_dd = (const float*)d_in[19];
    const float* bl1_dd = (const float*)d_in[20];
    const float* Wr1_dd = (const float*)d_in[21];
    const float* Wl1_td = (const float*)d_in[22];
    const float* bl1_td = (const float*)d_in[23];
    const float* Wr1_td = (const float*)d_in[24];
    const float* Wl1_rd = (const float*)d_in[25];
    const float* bl1_rd = (const float*)d_in[26];
    const float* Wr1_rd = (const float*)d_in[27];
    const float* g0_drug = (const float*)d_in[28];
    const float* b0_drug = (const float*)d_in[29];
    const float* g0_dis  = (const float*)d_in[30];
    const float* b0_dis  = (const float*)d_in[31];
    const float* g1_drug = (const float*)d_in[32];
    const float* b1_drug = (const float*)d_in[33];
    const float* g1_dis  = (const float*)d_in[34];
    const float* b1_dis  = (const float*)d_in[35];

    // ---------------- workspace layout ----------------
    char* wp = (char*)d_ws;
    auto alloc = [&](size_t bytes) { char* p = wp; wp += (bytes + 255) & ~size_t(255); return p; };

    unsigned short* hd0  = (unsigned short*)alloc((size_t)ND * HID * 2);
    unsigned short* hz0  = (unsigned short*)alloc((size_t)NZ * HID * 2);
    unsigned short* hd1b = (unsigned short*)alloc((size_t)ND * HID * 2);
    unsigned short* hz1b = (unsigned short*)alloc((size_t)NZ * HID * 2);
    unsigned short* meanA= (unsigned short*)alloc((size_t)ND * HID * 2);
    unsigned short* meanB= (unsigned short*)alloc((size_t)ND * HID * 2);
    unsigned short* meanC= (unsigned short*)alloc((size_t)NZ * HID * 2);
    unsigned short* Zdd  = (unsigned short*)alloc((size_t)ND * OUTD * 2);
    unsigned short* Zrd  = (unsigned short*)alloc((size_t)NZ * OUTD * 2);
    unsigned short* Ztd  = (unsigned short*)alloc((size_t)ND * OUTD * 2);
    float* hd1f = (float*)alloc((size_t)ND * HID * 4);
    float* hz1f = (float*)alloc((size_t)NZ * HID * 4);
    unsigned short* Wt0_dd = (unsigned short*)alloc((size_t)HID * 256 * 2);
    unsigned short* Wt0_rd = (unsigned short*)alloc((size_t)HID * 256 * 2);
    unsigned short* Wt0_td = (unsigned short*)alloc((size_t)HID * 256 * 2);
    unsigned short* Wt1_dd = (unsigned short*)alloc((size_t)OUTD * 256 * 2);
    unsigned short* Wt1_rd = (unsigned short*)alloc((size_t)OUTD * 256 * 2);
    unsigned short* Wt1_td = (unsigned short*)alloc((size_t)OUTD * 256 * 2);
    int* offs_dd = (int*)alloc((ND + 1) * 4);
    int* offs_rd = (int*)alloc((ND + 1) * 4);
    int* offs_td = (int*)alloc((NZ + 1) * 4);
    int* col_dd  = (int*)alloc((size_t)E * 4);
    int* col_rd  = (int*)alloc((size_t)E * 4);
    int* col_td  = (int*)alloc((size_t)E * 4);
    int* cnt_dd  = (int*)alloc(((size_t)(ND + 1) + (ND + 1) + (NZ + 1)) * 4);
    int* cnt_rd  = cnt_dd + (ND + 1);
    int* cnt_td  = cnt_rd + (ND + 1);
    int* part    = (int*)alloc(3 * 64 * 4);
    int* rc      = (int*)alloc(3 * CHK * 8 * 4);
    int* wpos    = (int*)alloc(3 * CHK * 8 * 4);
    int* rbase   = (int*)alloc(3 * 9 * 4);

    // Packed u32 buckets alias hd1f/hz1f (disjoint lifetime)
    unsigned* bkt_dd = (unsigned*)hd1f;
    unsigned* bkt_rd = bkt_dd + E;
    unsigned* bkt_td = (unsigned*)hz1f;
    int* partial = (int*)meanA;

    float* outD = (float*)d_out;
    float* outZ = outD + (size_t)ND * OUTD;

    // ---------------- fused gather + weight prep ----------------
    PrepArgs pa;
    pa.wl[0] = Wl0_dd; pa.wr[0] = Wr0_dd; pa.wt[0] = Wt0_dd; pa.co[0] = HID;
    pa.wl[1] = Wl0_rd; pa.wr[1] = Wr0_rd; pa.wt[1] = Wt0_rd; pa.co[1] = HID;
    pa.wl[2] = Wl0_td; pa.wr[2] = Wr0_td; pa.wt[2] = Wt0_td; pa.co[2] = HID;
    pa.wl[3] = Wl1_dd; pa.wr[3] = Wr1_dd; pa.wt[3] = Wt1_dd; pa.co[3] = OUTD;
    pa.wl[4] = Wl1_rd; pa.wr[4] = Wr1_rd; pa.wt[4] = Wt1_rd; pa.co[4] = OUTD;
    pa.wl[5] = Wl1_td; pa.wr[5] = Wr1_td; pa.wt[5] = Wt1_td; pa.co[5] = OUTD;
    pa.boff[0] = 0;
    for (int s = 0; s < 6; ++s) pa.boff[s + 1] = pa.boff[s] + pa.co[s];
    const int GB = ceil_div((ND + NZ) * 32, 256);
    gather_prep<<<GB + pa.boff[6], 256, 0, stream>>>(
        emb_drug, x_drug, emb_dis, x_dis, hd0, hz0, GB, pa);

    // ---------------- bucketed CSR build (NO global atomics) ----------------
    bcount<<<3 * CHK, 256, 0, stream>>>(dst_dd, dst_rd, dst_td, rc);
    bscan<<<1, 256, 0, stream>>>(rc, wpos, rbase);
    bscatter<<<3 * CHK, 256, 0, stream>>>(
        src_dd, dst_dd, src_rd, dst_rd, src_td, dst_td,
        wpos, bkt_dd, bkt_rd, bkt_td);
    bcount2<<<NXCD * 3 * SSUB, 256, 0, stream>>>(
        bkt_dd, bkt_rd, bkt_td, rbase, partial);
    sumcnt_part<<<2 * NB_D + NB_Z, 256, 0, stream>>>(
        partial, cnt_dd, cnt_rd, cnt_td, part);
    scan_small3<<<3, 64, 0, stream>>>(part, offs_dd, offs_rd, offs_td);
    scan_write_base<<<2 * NB_D + NB_Z, 256, 0, stream>>>(
        cnt_dd, cnt_rd, cnt_td, part, offs_dd, offs_rd, offs_td, partial);
    bfill2<<<NXCD * 3 * SSUB, 256, 0, stream>>>(
        bkt_dd, bkt_rd, bkt_td, rbase, partial, col_dd, col_rd, col_td);

    // ---------------- layer 0 ----------------
    agg3_128<<<ceil_div((2 * ND + NZ) * 64, 256), 256, 0, stream>>>(
        offs_dd, col_dd, hd0, meanA, ND,
        offs_rd, col_rd, hz0, meanB, ND,
        offs_td, col_td, hd0, meanC, NZ);
    sage2_mfma<HID><<<ceil_div(ND, 64), 256, 0, stream>>>(
        meanA, meanB, hd0, Wt0_dd, Wt0_rd, bl0_dd, bl0_rd, hd1f, ND);
    sage_mfma<HID><<<ceil_div(NZ, 64), 256, 0, stream>>>(
        meanC, hz0, Wt0_td, bl0_td, hz1f, NZ);

    ln2_kernel<HID, true, true><<<ceil_div(ND + NZ, 4), 256, 0, stream>>>(
        hd1f, g0_drug, b0_drug, hd1b, ND,
        hz1f, g0_dis, b0_dis, hz1b, NZ);

    // ---------------- layer 1 (transform-then-aggregate) ----------------
    xform3<<<ceil_div(ND, 64) * 2 + ceil_div(NZ, 64), 256, 0, stream>>>(
        hd1b, Wt1_dd, Zdd, ND,
        hz1b, Wt1_rd, Zrd, NZ,
        hd1b, Wt1_td, Ztd, ND);

    agg3_64<<<ceil_div((2 * ND + NZ) * 64, 256), 256, 0, stream>>>(
        offs_dd, col_dd, Zdd, meanA, ND,
        offs_rd, col_rd, Zrd, meanB, ND,
        offs_td, col_td, Ztd, meanC, NZ);

    sage2z<<<ceil_div(ND, 64), 256, 0, stream>>>(
        meanA, meanB, hd1b, Wt1_dd, Wt1_rd, bl1_dd, bl1_rd, outD, ND);
    sagez<<<ceil_div(NZ, 64), 256, 0, stream>>>(
        meanC, hz1b, Wt1_td, bl1_td, outZ, NZ);

    ln2_kernel<OUTD, false, false><<<ceil_div(ND + NZ, 4), 256, 0, stream>>>(
        outD, g1_drug, b1_drug, outD, ND,
        outZ, g1_dis, b1_dis, outZ, NZ);
}